// Round 5
// baseline (450.618 us; speedup 1.0000x reference)
//
#include <hip/hip_runtime.h>
#include <math.h>

#define PI_F 3.14159265358979323846f

typedef __attribute__((ext_vector_type(8))) short short8;
typedef __attribute__((ext_vector_type(4))) float f32x4;

__device__ __forceinline__ unsigned short f2bf(float f) {
    unsigned int u = __float_as_uint(f);
    unsigned int r = (u + 0x7fffu + ((u >> 16) & 1u)) >> 16;
    return (unsigned short)r;
}
__device__ __forceinline__ float bf2f(unsigned short v) {
    return __uint_as_float((unsigned int)v << 16);
}

// ---------------- encoder: x[16][8192][2] -> u1 bf16 [64][16][8192] ----------------
__global__ __launch_bounds__(256) void enc_kernel(
    const float* __restrict__ x, const float* __restrict__ ew,
    const float* __restrict__ eb, unsigned short* __restrict__ u1)
{
    int idx = blockIdx.x * 256 + threadIdx.x;   // 64*16*2048 threads, 4 t each
    int t4 = idx & 2047;
    int b  = (idx >> 11) & 15;
    int h  = idx >> 15;
    float w0 = ew[2*h], w1 = ew[2*h+1], bb = eb[h];
    const float* xp = x + ((size_t)b*8192 + (size_t)t4*4)*2;
    float4 a = *(const float4*)xp;
    float4 c = *(const float4*)(xp + 4);
    ushort4 o;
    o.x = f2bf(fmaf(w0, a.x, fmaf(w1, a.y, bb)));
    o.y = f2bf(fmaf(w0, a.z, fmaf(w1, a.w, bb)));
    o.z = f2bf(fmaf(w0, c.x, fmaf(w1, c.y, bb)));
    o.w = f2bf(fmaf(w0, c.z, fmaf(w1, c.w, bb)));
    *(ushort4*)(u1 + ((size_t)h*16 + b)*8192 + (size_t)t4*4) = o;
}

// ---------------- conv weight prep: fp32 [O][Cin][3] -> bf16 A-frag [kb][o][kk] ------
__global__ __launch_bounds__(256) void prep_w(
    const float* __restrict__ w0, const float* __restrict__ w1,
    const float* __restrict__ w2, const float* __restrict__ w3,
    const float* __restrict__ w4, const float* __restrict__ w5,
    const float* __restrict__ w6, const float* __restrict__ w7,
    unsigned short* __restrict__ wprep)
{
    int id = blockIdx.y;
    const float* src; int Cin; size_t doff;
    switch (id) {
        case 0: src = w0; Cin = 64;  doff = 0;      break;
        case 1: src = w1; Cin = 64;  doff = 12288;  break;
        case 2: src = w2; Cin = 64;  doff = 24576;  break;
        case 3: src = w3; Cin = 64;  doff = 36864;  break;
        case 4: src = w4; Cin = 256; doff = 49152;  break;
        case 5: src = w5; Cin = 256; doff = 245760; break;
        case 6: src = w6; Cin = 256; doff = 442368; break;
        default: src = w7; Cin = 256; doff = 638976; break;
    }
    int e = blockIdx.x * 256 + threadIdx.x;
    if (e >= Cin * Cin * 3) return;
    int kb  = e / (Cin * 32);
    int rem = e - kb * (Cin * 32);
    int o   = rem >> 5;
    int kk  = rem & 31;
    int cch = kb / 6, t6 = kb % 6, k = t6 >> 1, chalf = t6 & 1;
    int c = cch * 64 + chalf * 32 + kk;
    wprep[doff + e] = f2bf(src[((size_t)o * Cin + c) * 3 + k]);
}

// ---------------- S4 prep: build per-h MFMA A-matrices (coalesced writes) ----------
// TA[h][kb(6)][m(128)][kk(32)]: kb 0..3 Toeplitz K'[m-col], kb 4..5 W[m][j]
// VA[h][kb(4)][row(64)][kk(32)]: V[2n+ri][s] = w^(127-s) Re/Im
// rs[h][128]: prefix sums of K'; Vrs[h][64]: rowsum of V
__global__ __launch_bounds__(128) void prep_s4(
    const float* __restrict__ log_dt, const float* __restrict__ C2,
    const float* __restrict__ Dv,
    unsigned short* __restrict__ TA, unsigned short* __restrict__ VA,
    float* __restrict__ rs, float* __restrict__ Vrs)
{
    int h = blockIdx.x, t = threadIdx.x;
    __shared__ float cn[64];
    __shared__ float sK[128];
    __shared__ unsigned short s_w[128 * 66];   // W staged [m][j], pad 66
    float dt = expf(log_dt[h]);
    if (t < 32) {
        int n = t;
        float e = expf(-0.5f*dt);
        float s_, c_; sincosf(PI_F*dt*n, &s_, &c_);
        float wr = e*c_, wi = e*s_;
        float ar = -0.5f, ai = PI_F*n;
        float den = 1.f/(ar*ar + ai*ai);
        float tr = wr - 1.f, ti = wi;
        float qr = (tr*ar + ti*ai)*den;
        float qi = (ti*ar - tr*ai)*den;
        float c2r = C2[((size_t)h*32+n)*2], c2i = C2[((size_t)h*32+n)*2+1];
        cn[2*n]   = 2.f*(c2r*qr - c2i*qi);
        cn[2*n+1] = 2.f*(c2r*qi + c2i*qr);
        // Vrs = sum_{j=0}^{127} w^j = (1 - w^128)/(1 - w)
        float e128 = expf(-64.f*dt);
        float s2, c2v; sincosf(PI_F*dt*n*128.f, &s2, &c2v);
        float pr = 1.f - e128*c2v, pim = -e128*s2;
        float dr = 1.f - wr, di = -wi;
        float dd = 1.f/(dr*dr + di*di);
        Vrs[(size_t)h*64 + 2*n]   = (pr*dr + pim*di)*dd;
        Vrs[(size_t)h*64 + 2*n+1] = (pim*dr - pr*di)*dd;
    }
    __syncthreads();
    // phase 1: K[t] (each thread one tap)
    {
        float em = expf(-0.5f*dt*t);
        float Kt = 0.f;
        for (int n = 0; n < 32; n++) {
            float s_, c_; sincosf(PI_F*dt*(float)(n*t), &s_, &c_);
            Kt += cn[2*n]*em*c_ - cn[2*n+1]*em*s_;
        }
        sK[t] = Kt + (t == 0 ? Dv[h] : 0.f);
    }
    // phase 2: wave0 (t<64) builds W columns into LDS; wave1 builds V rows direct
    if (t < 64) {
        int n = t >> 1, ri = t & 1;
        float e = expf(-0.5f*dt);
        float s_, c_; sincosf(PI_F*dt*n, &s_, &c_);
        float wr = e*c_, wi = e*s_;
        float crn = cn[2*n], cin = cn[2*n+1];
        float pr = wr, pim = wi;                    // w^(m+1), m=0
        for (int m = 0; m < 128; m++) {
            float re = crn*pr - cin*pim;
            float im = crn*pim + cin*pr;
            s_w[m*66 + t] = f2bf(ri ? -im : re);
            float nr = pr*wr - pim*wi;
            float ni = pr*wi + pim*wr;
            pr = nr; pim = ni;
        }
    } else {
        int r = t - 64; int n = r >> 1, ri = r & 1;
        float e = expf(-0.5f*dt);
        float s_, c_; sincosf(PI_F*dt*n, &s_, &c_);
        float wr = e*c_, wi = e*s_;
        float cr2 = 1.f, ci2 = 0.f;                 // w^0
        for (int kb = 3; kb >= 0; kb--) {
            unsigned short buf[32];
            for (int kk = 31; kk >= 0; kk--) {
                buf[kk] = f2bf(ri ? ci2 : cr2);
                float nr = cr2*wr - ci2*wi;
                float ni = cr2*wi + ci2*wr;
                cr2 = nr; ci2 = ni;
            }
            uint4* dst = (uint4*)&VA[(((size_t)h*4 + kb)*64 + r)*32];
            uint4* src = (uint4*)buf;
            dst[0]=src[0]; dst[1]=src[1]; dst[2]=src[2]; dst[3]=src[3];
        }
    }
    __syncthreads();
    // prefix sum for BN shift
    {
        float acc = 0.f;
        for (int tau = 0; tau <= t; tau++) acc += sK[tau];
        rs[(size_t)h*128 + t] = acc;
    }
    // Toeplitz row t, buffered uint4 stores
    for (int kb = 0; kb < 4; kb++) {
        unsigned short tb[32];
#pragma unroll
        for (int kk = 0; kk < 32; kk++) {
            int col = kb*32 + kk;
            tb[kk] = f2bf((col <= t) ? sK[t - col] : 0.f);
        }
        uint4* dst = (uint4*)&TA[(((size_t)h*6 + kb)*128 + t)*32];
        uint4* src = (uint4*)tb;
        dst[0]=src[0]; dst[1]=src[1]; dst[2]=src[2]; dst[3]=src[3];
    }
    // W copy-out, coalesced: 1024 uint4 over kb'(2) x m(128) x kkg(4)
    for (int i = t; i < 1024; i += 128) {
        int kb = i >> 9;             // 0..1
        int rem = i & 511;
        int m = rem >> 2, kkg = rem & 3;
        *(uint4*)&TA[(((size_t)h*6 + 4 + kb)*128 + m)*32 + kkg*8] =
            *(const uint4*)&s_w[m*66 + kb*32 + kkg*8];
    }
}

// ---------------- slim prep (s4c): V rows + rowsums, coalesced ----------------
__global__ __launch_bounds__(64) void prep_va(
    const float* __restrict__ log_dt,
    unsigned short* __restrict__ VA, float* __restrict__ Vrs)
{
    int h = blockIdx.x, t = threadIdx.x;     // t = row = 2n+ri
    int n = t >> 1, ri = t & 1;
    float dt = expf(log_dt[h]);
    float e = expf(-0.5f*dt);
    float s_, c_; sincosf(PI_F*dt*n, &s_, &c_);
    float wr = e*c_, wi = e*s_;
    float cr2 = 1.f, ci2 = 0.f;              // w^0 -> col 127
    for (int kb = 3; kb >= 0; kb--) {
        unsigned short buf[32];
        for (int kk = 31; kk >= 0; kk--) {
            buf[kk] = f2bf(ri ? ci2 : cr2);
            float nr = cr2*wr - ci2*wi;
            float ni = cr2*wi + ci2*wr;
            cr2 = nr; ci2 = ni;
        }
        uint4* dst = (uint4*)&VA[(((size_t)h*4 + kb)*64 + t)*32];
        uint4* src = (uint4*)buf;
        dst[0]=src[0]; dst[1]=src[1]; dst[2]=src[2]; dst[3]=src[3];
    }
    if (ri == 0) {
        float e128 = expf(-64.f*dt);
        float s2, c2v; sincosf(PI_F*dt*n*128.f, &s2, &c2v);
        float pr = 1.f - e128*c2v, pim = -e128*s2;
        float dr = 1.f - wr, di = -wi;
        float dd = 1.f/(dr*dr + di*di);
        Vrs[(size_t)h*64 + 2*n]   = (pr*dr + pim*di)*dd;
        Vrs[(size_t)h*64 + 2*n+1] = (pim*dr - pr*di)*dd;
    }
}

// ---------------- S4 pass A (GEMM): chunk end-states E = V @ u ----------------
template<int NCH, int LOGNCH>
__global__ __launch_bounds__(64) void s4_gemm_a(
    const unsigned short* __restrict__ u, const unsigned short* __restrict__ VA,
    const float* __restrict__ Vrs, const float* __restrict__ sc,
    const float* __restrict__ sh, float* __restrict__ Bc)
{
    const int L = NCH * 128;
    int h = blockIdx.y;
    int lane = threadIdx.x;
    int nl = lane & 15, g = lane >> 4;
    int col = blockIdx.x * 16 + nl;
    int b = col >> LOGNCH, c = col & (NCH - 1);
    const unsigned short* up = u + ((size_t)h*16 + b)*L + c*128;
    f32x4 acc[4];
#pragma unroll
    for (int mt = 0; mt < 4; mt++) acc[mt] = (f32x4){0.f,0.f,0.f,0.f};
#pragma unroll
    for (int kb = 0; kb < 4; kb++) {
        short8 bf = *(const short8*)(up + kb*32 + g*8);
#pragma unroll
        for (int mt = 0; mt < 4; mt++) {
            short8 af = *(const short8*)(VA + (((size_t)h*4 + kb)*64 + mt*16 + nl)*32 + g*8);
            acc[mt] = __builtin_amdgcn_mfma_f32_16x16x32_bf16(af, bf, acc[mt], 0, 0, 0);
        }
    }
    float scv = sc ? sc[h] : 1.f;
    float shv = sh ? sh[h] : 0.f;
    float* bp = Bc + (((size_t)h*16 + b)*NCH + c)*64;
#pragma unroll
    for (int mt = 0; mt < 4; mt++) {
        int j0 = mt*16 + g*4;
        float4 vr = *(const float4*)(Vrs + (size_t)h*64 + j0);
        float4 o;
        o.x = fmaf(scv, acc[mt][0], shv*vr.x);
        o.y = fmaf(scv, acc[mt][1], shv*vr.y);
        o.z = fmaf(scv, acc[mt][2], shv*vr.z);
        o.w = fmaf(scv, acc[mt][3], shv*vr.w);
        *(float4*)(bp + j0) = o;
    }
}

// ---------------- S4 mid: chunk-level scan (w^128 via 7 squarings) ----------------
__global__ __launch_bounds__(64) void s4_mid(
    const float* __restrict__ log_dt, const float* __restrict__ Bc,
    float* __restrict__ Sinit, float* __restrict__ Sfinal,
    int H, int NCH)
{
    int gid = blockIdx.x * 64 + threadIdx.x;   // H*16*32
    int n = gid & 31;
    int tmp = gid >> 5;
    int b = tmp & 15;
    int h = tmp >> 4;
    float dt = expf(log_dt[h]);
    float e = expf(-0.5f * dt);
    float s_, c_; sincosf(PI_F * dt * n, &s_, &c_);
    float wr = e * c_, wi = e * s_;
#pragma unroll
    for (int i = 0; i < 7; i++) { float r = wr*wr - wi*wi; float im = 2.f*wr*wi; wr = r; wi = im; }
    float Sr = 0.f, Si = 0.f;
    size_t base = (((size_t)h*16 + b)*NCH)*64 + 2*n;
    for (int c = 0; c < NCH; c++) {
        float2 v; v.x = Sr; v.y = Si;
        *(float2*)(Sinit + base + (size_t)c*64) = v;
        float2 bc = *(const float2*)(Bc + base + (size_t)c*64);
        float r  = fmaf(wr, Sr, fmaf(-wi, Si, bc.x));
        float im = fmaf(wi, Sr, fmaf( wr, Si, bc.y));
        Sr = r; Si = im;
    }
    if (Sfinal) {
        float2 v; v.x = Sr; v.y = Si;
        *(float2*)(Sfinal + ((size_t)h*16 + b)*64 + 2*n) = v;
    }
}

// ---------------- S4 pass C (GEMM): y = sc*(T'@u) + sh*rs + W@Sinit ----------------
template<int NCH, int LOGNCH>
__global__ __launch_bounds__(256) void s4_gemm_c(
    const unsigned short* __restrict__ u, const float* __restrict__ Sini,
    const unsigned short* __restrict__ TA, const float* __restrict__ rs,
    const float* __restrict__ sc, const float* __restrict__ sh,
    unsigned short* __restrict__ yout)
{
    const int L = NCH * 128;
    __shared__ unsigned short s_u[64*200];   // 25600 B
    __shared__ unsigned short s_s[64*72];    // 9216 B
    int h = blockIdx.y;
    int tid = threadIdx.x;
    int lane = tid & 63, wid = tid >> 6;
    int nl = lane & 15, g = lane >> 4;
    int col0 = blockIdx.x * 64;
    for (int i = tid; i < 1024; i += 256) {
        int cl = i >> 4, o = i & 15;
        int col = col0 + cl; int b = col >> LOGNCH, c = col & (NCH - 1);
        *(uint4*)&s_u[cl*200 + o*8] =
            *(const uint4*)&u[((size_t)h*16 + b)*L + c*128 + o*8];
    }
    for (int i = tid; i < 1024; i += 256) {
        int cl = i >> 4, o = i & 15;
        int col = col0 + cl; int b = col >> LOGNCH, c = col & (NCH - 1);
        float4 v = *(const float4*)&Sini[(((size_t)h*16 + b)*NCH + c)*64 + o*4];
        ushort4 q; q.x = f2bf(v.x); q.y = f2bf(v.y); q.z = f2bf(v.z); q.w = f2bf(v.w);
        *(ushort4*)&s_s[cl*72 + o*4] = q;
    }
    __syncthreads();
    f32x4 accT[2][4], accW[2][4];
#pragma unroll
    for (int a = 0; a < 2; a++)
#pragma unroll
        for (int j = 0; j < 4; j++) { accT[a][j] = (f32x4){0,0,0,0}; accW[a][j] = (f32x4){0,0,0,0}; }
#pragma unroll
    for (int kb = 0; kb < 4; kb++) {
        short8 bfr[4];
#pragma unroll
        for (int j = 0; j < 4; j++)
            bfr[j] = *(const short8*)&s_u[(j*16 + nl)*200 + kb*32 + g*8];
#pragma unroll
        for (int mt2 = 0; mt2 < 2; mt2++) {
            int mtile = wid*2 + mt2;
            short8 af = *(const short8*)&TA[(((size_t)h*6 + kb)*128 + mtile*16 + nl)*32 + g*8];
#pragma unroll
            for (int j = 0; j < 4; j++)
                accT[mt2][j] = __builtin_amdgcn_mfma_f32_16x16x32_bf16(af, bfr[j], accT[mt2][j], 0, 0, 0);
        }
    }
#pragma unroll
    for (int kw = 0; kw < 2; kw++) {
        short8 bfr[4];
#pragma unroll
        for (int j = 0; j < 4; j++)
            bfr[j] = *(const short8*)&s_s[(j*16 + nl)*72 + kw*32 + g*8];
#pragma unroll
        for (int mt2 = 0; mt2 < 2; mt2++) {
            int mtile = wid*2 + mt2;
            short8 af = *(const short8*)&TA[(((size_t)h*6 + 4 + kw)*128 + mtile*16 + nl)*32 + g*8];
#pragma unroll
            for (int j = 0; j < 4; j++)
                accW[mt2][j] = __builtin_amdgcn_mfma_f32_16x16x32_bf16(af, bfr[j], accW[mt2][j], 0, 0, 0);
        }
    }
    float scv = sc ? sc[h] : 1.f;
    float shv = sh ? sh[h] : 0.f;
#pragma unroll
    for (int mt2 = 0; mt2 < 2; mt2++) {
        int m0 = (wid*2 + mt2)*16 + g*4;
        float4 rsv = *(const float4*)&rs[(size_t)h*128 + m0];
#pragma unroll
        for (int j = 0; j < 4; j++) {
            int col = col0 + j*16 + nl; int b = col >> LOGNCH, c = col & (NCH - 1);
            ushort4 q;
            q.x = f2bf(fmaf(scv, accT[mt2][j][0], shv*rsv.x) + accW[mt2][j][0]);
            q.y = f2bf(fmaf(scv, accT[mt2][j][1], shv*rsv.y) + accW[mt2][j][1]);
            q.z = f2bf(fmaf(scv, accT[mt2][j][2], shv*rsv.z) + accW[mt2][j][2]);
            q.w = f2bf(fmaf(scv, accT[mt2][j][3], shv*rsv.w) + accW[mt2][j][3]);
            *(ushort4*)&yout[((size_t)h*16 + b)*L + c*128 + m0] = q;
        }
    }
}

// ---------------- fused 4-dilation conv block via MFMA (v5) ----------------
// computes all 4 dilated convs (dil = 1,2,4,8) from one LDS staging.
// u [CIN][16][Lin] bf16 -> out [4*CIN][16][Lout] bf16 (out ch = d*CIN + og + local)
// v5 vs v4: v4 was latency-bound (MfmaUtil 10%, VALU 13%, HBM 11%, occ 17%):
// the stage's vmcnt(0) wait sat BEFORE the MFMA phase, stalling every wave
// ~900cy per chunk with only 2 blocks/CU to cover it. Changes:
//  - T14 proper: stage_load (issue only) BEFORE the MFMA phase, stage_write
//    (vmcnt wait + ds_writes) AFTER it, bracketed by two barriers. Load
//    latency hides under 48 MFMAs + LDS reads.  stg regs (<=20) now fit:
//  - TBLK=32 for conv2 too -> 2x18.4KB LDS dbuf -> 4 blocks/CU (16 waves).
//  - launch_bounds(256,4): 128-VGPR cap; acc(32)+stg(20)+addr ~95, no spill.
// Race audit: write buf[(cc+1)&1] at iter cc vs reads of same buf at iter cc-1
// separated by iter cc's post-MFMA barrier; vs iter cc+1 reads by post-write
// barrier. Swizzle unchanged (conflicts measured 0).
template<int CIN, int TBLK>
__global__ __launch_bounds__(256, 4) void conv_mfma4(
    const unsigned short* __restrict__ u, const unsigned short* __restrict__ wp,
    const float* __restrict__ bs0, const float* __restrict__ bs1,
    const float* __restrict__ bs2, const float* __restrict__ bs3,
    unsigned short* __restrict__ out, int Lin, int Lout)
{
    constexpr int F     = TBLK / 16;          // output t-tiles per wave (2)
    constexpr int NPOS  = TBLK * 4 + 16;      // staged input positions (144)
    constexpr int Q     = NPOS / 4;           // q rows per residue plane (36)
    constexpr int NITEM = (NPOS / 8) * 64;    // uint4 load items (1152)
    constexpr int NLD   = (NITEM + 255) / 256;// loads per thread (5)
    constexpr int NCC   = CIN / 64;           // cc0 chunks (4 or 1)
    constexpr int NBUF  = (NCC > 1) ? 2 : 1;  // LDS double-buffer only if chunked
    constexpr int BUFSZ = 4 * Q * 64;         // shorts per buffer (9216)
    __shared__ unsigned short s_in[NBUF * BUFSZ];   // 36864 B / 18432 B

    int tid = threadIdx.x;
    int lane = tid & 63, wid = tid >> 6;
    int nl = lane & 15, g = lane >> 4;
    int t0 = blockIdx.x * TBLK;
    int b  = blockIdx.y;
    int og = blockIdx.z * 64;
    const int P0 = t0 * 4 - 8;

    f32x4 acc[4][F];
#pragma unroll
    for (int d = 0; d < 4; d++)
#pragma unroll
        for (int f = 0; f < F; f++) acc[d][f] = (f32x4){0.f,0.f,0.f,0.f};

    uint4 stg[NLD];

    // issue global loads only (no wait) -- ccbase is the CHANNEL BASE (chunk*64)
    auto stage_load = [&](int ccbase) {
#pragma unroll
        for (int j = 0; j < NLD; j++) {
            int i = tid + 256 * j;
            uint4 v; v.x = 0u; v.y = 0u; v.z = 0u; v.w = 0u;
            if (i < NITEM) {
                int ch = i & 63, po = i >> 6;
                int p = P0 + po * 8;
                const unsigned short* gp = u + ((size_t)(ccbase + ch)*16 + b)*Lin;
                if (p >= 0 && p + 8 <= Lin) {
                    v = *(const uint4*)(gp + p);
                } else {
                    alignas(16) unsigned short t8[8];
#pragma unroll
                    for (int j2 = 0; j2 < 8; j2++) {
                        int pj = p + j2;
                        t8[j2] = ((unsigned)pj < (unsigned)Lin) ? gp[pj] : (unsigned short)0;
                    }
                    v = *(const uint4*)t8;
                }
            }
            stg[j] = v;
        }
    };
    // consume stg -> LDS (the vmcnt wait lands here, AFTER the MFMA phase)
    auto stage_write = [&](int bufidx) {
        unsigned short* sb = s_in + bufidx * BUFSZ;
#pragma unroll
        for (int j = 0; j < NLD; j++) {
            int i = tid + 256 * j;
            if (i < NITEM) {
                int ch = i & 63, po = i >> 6;
                alignas(16) unsigned short t8[8];
                *(uint4*)t8 = stg[j];
#pragma unroll
                for (int jj = 0; jj < 8; jj++) {
                    int pl = po * 8 + jj;
                    int row = (pl & 3) * Q + (pl >> 2);
                    sb[row * 64 + (ch ^ ((row & 7) << 3))] = t8[jj];
                }
            }
        }
    };

    stage_load(0);
    stage_write(0);
    __syncthreads();

#pragma unroll
    for (int cc = 0; cc < NCC; cc++) {
        if (cc + 1 < NCC) stage_load((cc + 1) * 64);   // issue early; hides under MFMAs
        const unsigned short* sb = s_in + (NBUF > 1 ? (cc & 1) * BUFSZ : 0);
#pragma unroll
        for (int k = 0; k < 3; ++k) {
#pragma unroll
            for (int chalf = 0; chalf < 2; ++chalf) {
                int kb = cc * 6 + k * 2 + chalf;
#pragma unroll
                for (int d = 0; d < 4; ++d) {
                    const int DIL = 1 << d;
                    const int off = (k - 1) * DIL + 8;     // 0..16
                    const int r = off & 3, s = off >> 2;
                    short8 afrag = *(const short8*)&wp[(size_t)d*(3*CIN*CIN) +
                        ((size_t)kb*CIN + og + wid*16 + nl)*32 + g*8];
#pragma unroll
                    for (int f = 0; f < F; ++f) {
                        int q = f*16 + nl + s;
                        int row = r * Q + q;
                        short8 bfrag = *(const short8*)&sb[row * 64 +
                            ((((chalf << 2) | g) ^ (row & 7)) << 3)];
                        acc[d][f] = __builtin_amdgcn_mfma_f32_16x16x32_bf16(afrag, bfrag, acc[d][f], 0, 0, 0);
                    }
                }
            }
        }
        if (cc + 1 < NCC) {
            __syncthreads();                 // all waves done reading buf[(cc+1)&1]
            stage_write((cc + 1) & 1);       // vmcnt wait here (post-MFMA)
            __syncthreads();                 // writes visible before next MFMA phase
        }
    }

    const float* bptr[4] = {bs0, bs1, bs2, bs3};
#pragma unroll
    for (int d = 0; d < 4; ++d) {
#pragma unroll
        for (int f = 0; f < F; ++f) {
            int t = t0 + f*16 + nl;
#pragma unroll
            for (int r2 = 0; r2 < 4; ++r2) {
                int o = og + wid*16 + g*4 + r2;
                float v = acc[d][f][r2] + bptr[d][o];
                if (d) v = v >= 0.f ? v : 0.3f*v;
                out[((size_t)(d*CIN + o)*16 + b)*Lout + t] = f2bf(v);
            }
        }
    }
}

// ---------------- BN stats from bf16 [ch][b][t] ----------------
__global__ __launch_bounds__(256) void bn_stats(
    const unsigned short* __restrict__ x, const float* __restrict__ g,
    const float* __restrict__ bb, float* __restrict__ sc, float* __restrict__ sh,
    int n, int gmask)
{
    int ch = blockIdx.x;
    const unsigned short* xp = x + (size_t)ch * n;
    float s1 = 0.f, s2 = 0.f;
    for (int i = threadIdx.x*8; i < n; i += 2048) {
        uint4 raw = *(const uint4*)(xp + i);
        unsigned short us[8]; *(uint4*)us = raw;
#pragma unroll
        for (int j = 0; j < 8; j++) {
            float v = bf2f(us[j]);
            s1 += v; s2 += v*v;
        }
    }
    for (int o = 32; o > 0; o >>= 1) { s1 += __shfl_down(s1, o); s2 += __shfl_down(s2, o); }
    __shared__ float p1[4], p2[4];
    int wid = threadIdx.x >> 6;
    if ((threadIdx.x & 63) == 0) { p1[wid] = s1; p2[wid] = s2; }
    __syncthreads();
    if (threadIdx.x == 0) {
        s1 = p1[0] + p1[1] + p1[2] + p1[3];
        s2 = p2[0] + p2[1] + p2[2] + p2[3];
        float m = s1 / n;
        float var = s2 / n - m*m;
        float rstd = rsqrtf(var + 1e-5f);
        float scale = g[ch & gmask] * rstd;
        sc[ch] = scale;
        sh[ch] = fmaf(-m, scale, bb[ch & gmask]);
    }
}

// ---------------- s4c final-state -> x3[:, :, 511] ----------------
__global__ __launch_bounds__(256) void s4c_last(
    const float* __restrict__ Sfinal, const unsigned short* __restrict__ u3,
    const float* __restrict__ sc, const float* __restrict__ sh,
    const float* __restrict__ log_dt, const float* __restrict__ C2,
    const float* __restrict__ Dv, float* __restrict__ x3last)
{
    int gid = blockIdx.x*256 + threadIdx.x;  // 16*1024
    int h = gid & 1023;
    int b = gid >> 10;
    float dt = expf(log_dt[h]);
    float e = expf(-0.5f * dt);
    const float* sp = Sfinal + ((size_t)h*16 + b)*64;
    float aR = 0.f, aI = 0.f;
#pragma unroll
    for (int n = 0; n < 32; n++) {
        float s_, c_; sincosf(PI_F * dt * n, &s_, &c_);
        float wr = e*c_, wi = e*s_;
        float ar = -0.5f, ai = PI_F * n;
        float den = 1.f / (ar*ar + ai*ai);
        float tr = wr - 1.f, ti = wi;
        float qr = (tr*ar + ti*ai) * den;
        float qi = (ti*ar - tr*ai) * den;
        float c2r = C2[((size_t)h*32 + n)*2], c2i = C2[((size_t)h*32 + n)*2 + 1];
        float crv = c2r*qr - c2i*qi, civ = c2r*qi + c2i*qr;
        aR = fmaf(crv, sp[2*n],   aR);
        aI = fmaf(civ, sp[2*n+1], aI);
    }
    float uv = fmaf(sc[h], bf2f(u3[((size_t)h*16 + b)*512 + 511]), sh[h]);
    x3last[b*1024 + h] = 2.f*(aR - aI) + Dv[h]*uv;
}

// ---------------- decoder head ----------------
__global__ __launch_bounds__(256) void dec_kernel(
    const float* __restrict__ x3last, const float* __restrict__ w1, const float* __restrict__ b1,
    const float* __restrict__ w2, const float* __restrict__ b2, float* __restrict__ out)
{
    __shared__ float xs[1024];
    int b = blockIdx.x, tid = threadIdx.x;
    for (int i = tid; i < 1024; i += 256) xs[i] = x3last[b*1024 + i];
    __syncthreads();
    float z = b1[tid];
    const float* wpt = w1 + (size_t)tid*1024;
    for (int i = 0; i < 1024; i += 4) {
        float4 wv = *(const float4*)(wpt + i);
        z = fmaf(wv.x, xs[i],   z);
        z = fmaf(wv.y, xs[i+1], z);
        z = fmaf(wv.z, xs[i+2], z);
        z = fmaf(wv.w, xs[i+3], z);
    }
    float v = w2[tid] * z;
    for (int o = 32; o > 0; o >>= 1) v += __shfl_down(v, o);
    __shared__ float ps[4];
    if ((tid & 63) == 0) ps[tid >> 6] = v;
    __syncthreads();
    if (tid == 0) out[b] = ps[0] + ps[1] + ps[2] + ps[3] + b2[0];
}

extern "C" void kernel_launch(void* const* d_in, const int* in_sizes, int n_in,
                              void* d_out, int out_size, void* d_ws, size_t ws_size,
                              hipStream_t stream)
{
    const float* x       = (const float*)d_in[0];
    const float* enc_w   = (const float*)d_in[1];
    const float* enc_b   = (const float*)d_in[2];
    const float* s4a_ldt = (const float*)d_in[3];
    const float* s4a_C   = (const float*)d_in[4];
    const float* s4a_D   = (const float*)d_in[5];
    const float* s4b_ldt = (const float*)d_in[6];
    const float* s4b_C   = (const float*)d_in[7];
    const float* s4b_D   = (const float*)d_in[8];
    const float* s4c_ldt = (const float*)d_in[9];
    const float* s4c_C   = (const float*)d_in[10];
    const float* s4c_D   = (const float*)d_in[11];
    const float* b1w[4] = {(const float*)d_in[12], (const float*)d_in[14], (const float*)d_in[16], (const float*)d_in[18]};
    const float* b1b[4] = {(const float*)d_in[13], (const float*)d_in[15], (const float*)d_in[17], (const float*)d_in[19]};
    const float* b2w[4] = {(const float*)d_in[20], (const float*)d_in[22], (const float*)d_in[24], (const float*)d_in[26]};
    const float* b2b[4] = {(const float*)d_in[21], (const float*)d_in[23], (const float*)d_in[25], (const float*)d_in[27]};
    const float* bn1_g  = (const float*)d_in[28];
    const float* bn1_b  = (const float*)d_in[29];
    const float* bn2_g  = (const float*)d_in[30];
    const float* bn2_b  = (const float*)d_in[31];
    const float* dec1_w = (const float*)d_in[32];
    const float* dec1_b = (const float*)d_in[33];
    const float* dec2_w = (const float*)d_in[34];
    const float* dec2_b = (const float*)d_in[35];
    float* out = (float*)d_out;

    char* ws = (char*)d_ws;
    unsigned short* u1    = (unsigned short*)(ws);              // 16.8 MB (also u3)
    unsigned short* u3    = u1;
    unsigned short* ya    = (unsigned short*)(ws + 16777216);   // 16.8 MB (also yb, later VA_c)
    unsigned short* yb    = ya;
    unsigned short* VA_c  = ya;                                 // reuse after conv2
    unsigned short* u2    = (unsigned short*)(ws + 33554432);   // 16.8 MB
    float*          Bc    = (float*)(ws + 50331648);            // 16.8 MB
    float*          Sini  = (float*)(ws + 67108864);            // 16.8 MB
    float*          Sfin  = (float*)(ws + 83886080);            // 4.2 MB
    unsigned short* wprep = (unsigned short*)(ws + 88080384);   // 1.67 MB
    unsigned short* TA_a  = (unsigned short*)(ws + 89751552);   // 3.15 MB
    unsigned short* TA_b  = (unsigned short*)(ws + 92897280);   // 12.6 MB
    unsigned short* VA_a  = (unsigned short*)(ws + 105480192);  // 1.05 MB
    unsigned short* VA_b  = (unsigned short*)(ws + 106528768);  // 4.2 MB
    float*          rs_a  = (float*)(ws + 110723072);           // 32 KB
    float*          rs_b  = (float*)(ws + 110755840);           // 128 KB
    float*          Vrs_a = (float*)(ws + 110886912);           // 16 KB
    float*          Vrs_b = (float*)(ws + 110903296);           // 64 KB
    float*          smallp= (float*)(ws + 110968832);
    float* sc1 = smallp;         // 256
    float* sh1 = smallp + 256;   // 256
    float* sc2 = smallp + 512;   // 1024
    float* sh2 = smallp + 1536;  // 1024
    float* x3l = smallp + 2560;  // 16384
    float*          Vrs_c = (float*)(ws + 111280128);           // 256 KB

    // prep (independent of data path)
    prep_w<<<dim3(768, 8), 256, 0, stream>>>(b1w[0], b1w[1], b1w[2], b1w[3],
                                             b2w[0], b2w[1], b2w[2], b2w[3], wprep);
    prep_s4<<<64, 128, 0, stream>>>(s4a_ldt, s4a_C, s4a_D, TA_a, VA_a, rs_a, Vrs_a);
    prep_s4<<<256, 128, 0, stream>>>(s4b_ldt, s4b_C, s4b_D, TA_b, VA_b, rs_b, Vrs_b);

    // encoder -> u1 bf16
    enc_kernel<<<8192, 256, 0, stream>>>(x, enc_w, enc_b, u1);

    // s4a: H=64, NCH=64 (L=8192)
    s4_gemm_a<64,6><<<dim3(64, 64), 64, 0, stream>>>(u1, VA_a, Vrs_a, nullptr, nullptr, Bc);
    s4_mid<<<512, 64, 0, stream>>>(s4a_ldt, Bc, Sini, nullptr, 64, 64);
    s4_gemm_c<64,6><<<dim3(16, 64), 256, 0, stream>>>(u1, Sini, TA_a, rs_a, nullptr, nullptr, ya);

    // conv block1 (fused 4 dilations): ya [64][16][8192] -> u2 [256][16][2048]
    // TBLK=32, single LDS buffer 18.4 KB, 4 blocks/CU
    conv_mfma4<64,32><<<dim3(64, 16, 1), 256, 0, stream>>>(
        ya, wprep, b1b[0], b1b[1], b1b[2], b1b[3], u2, 8192, 2048);
    bn_stats<<<256, 256, 0, stream>>>(u2, bn1_g, bn1_b, sc1, sh1, 16*2048, 63);

    // s4b: H=256, NCH=16 (L=2048)
    s4_gemm_a<16,4><<<dim3(16, 256), 64, 0, stream>>>(u2, VA_b, Vrs_b, sc1, sh1, Bc);
    s4_mid<<<2048, 64, 0, stream>>>(s4b_ldt, Bc, Sini, nullptr, 256, 16);
    s4_gemm_c<16,4><<<dim3(4, 256), 256, 0, stream>>>(u2, Sini, TA_b, rs_b, sc1, sh1, yb);

    // conv block2 (fused 4 dilations): yb [256][16][2048] -> u3 [1024][16][512]
    // TBLK=32, LDS dbuf 36.9 KB -> 4 blocks/CU, T14 load-early/write-late
    conv_mfma4<256,32><<<dim3(16, 16, 4), 256, 0, stream>>>(
        yb, wprep + 49152, b2b[0], b2b[1], b2b[2], b2b[3], u3, 2048, 512);
    bn_stats<<<1024, 256, 0, stream>>>(u3, bn2_g, bn2_b, sc2, sh2, 16*512, 255);

    // s4c: H=1024, NCH=4 (L=512); only final state needed.
    // yb is dead now -> reuse its 16.8 MB slot for VA_c (exact fit).
    prep_va<<<1024, 64, 0, stream>>>(s4c_ldt, VA_c, Vrs_c);
    s4_gemm_a<4,2><<<dim3(4, 1024), 64, 0, stream>>>(u3, VA_c, Vrs_c, sc2, sh2, Bc);
    s4_mid<<<8192, 64, 0, stream>>>(s4c_ldt, Bc, Sini, Sfin, 1024, 4);
    s4c_last<<<64, 256, 0, stream>>>(Sfin, u3, sc2, sh2, s4c_ldt, s4c_C, s4c_D, x3l);

    // decoder head
    dec_kernel<<<16, 256, 0, stream>>>(x3l, dec1_w, dec1_b, dec2_w, dec2_b, out);
}

// Round 6
// 429.227 us; speedup vs baseline: 1.0498x; 1.0498x over previous
//
#include <hip/hip_runtime.h>
#include <math.h>

#define PI_F 3.14159265358979323846f

typedef __attribute__((ext_vector_type(8))) short short8;
typedef __attribute__((ext_vector_type(4))) float f32x4;

__device__ __forceinline__ unsigned short f2bf(float f) {
    unsigned int u = __float_as_uint(f);
    unsigned int r = (u + 0x7fffu + ((u >> 16) & 1u)) >> 16;
    return (unsigned short)r;
}
__device__ __forceinline__ float bf2f(unsigned short v) {
    return __uint_as_float((unsigned int)v << 16);
}

// ---------------- encoder: x[16][8192][2] -> u1 bf16 [64][16][8192] ----------------
__global__ __launch_bounds__(256) void enc_kernel(
    const float* __restrict__ x, const float* __restrict__ ew,
    const float* __restrict__ eb, unsigned short* __restrict__ u1)
{
    int idx = blockIdx.x * 256 + threadIdx.x;   // 64*16*2048 threads, 4 t each
    int t4 = idx & 2047;
    int b  = (idx >> 11) & 15;
    int h  = idx >> 15;
    float w0 = ew[2*h], w1 = ew[2*h+1], bb = eb[h];
    const float* xp = x + ((size_t)b*8192 + (size_t)t4*4)*2;
    float4 a = *(const float4*)xp;
    float4 c = *(const float4*)(xp + 4);
    ushort4 o;
    o.x = f2bf(fmaf(w0, a.x, fmaf(w1, a.y, bb)));
    o.y = f2bf(fmaf(w0, a.z, fmaf(w1, a.w, bb)));
    o.z = f2bf(fmaf(w0, c.x, fmaf(w1, c.y, bb)));
    o.w = f2bf(fmaf(w0, c.z, fmaf(w1, c.w, bb)));
    *(ushort4*)(u1 + ((size_t)h*16 + b)*8192 + (size_t)t4*4) = o;
}

// ---------------- conv weight prep: fp32 [O][Cin][3] -> bf16 A-frag [kb][o][kk] ------
__global__ __launch_bounds__(256) void prep_w(
    const float* __restrict__ w0, const float* __restrict__ w1,
    const float* __restrict__ w2, const float* __restrict__ w3,
    const float* __restrict__ w4, const float* __restrict__ w5,
    const float* __restrict__ w6, const float* __restrict__ w7,
    unsigned short* __restrict__ wprep)
{
    int id = blockIdx.y;
    const float* src; int Cin; size_t doff;
    switch (id) {
        case 0: src = w0; Cin = 64;  doff = 0;      break;
        case 1: src = w1; Cin = 64;  doff = 12288;  break;
        case 2: src = w2; Cin = 64;  doff = 24576;  break;
        case 3: src = w3; Cin = 64;  doff = 36864;  break;
        case 4: src = w4; Cin = 256; doff = 49152;  break;
        case 5: src = w5; Cin = 256; doff = 245760; break;
        case 6: src = w6; Cin = 256; doff = 442368; break;
        default: src = w7; Cin = 256; doff = 638976; break;
    }
    int e = blockIdx.x * 256 + threadIdx.x;
    if (e >= Cin * Cin * 3) return;
    int kb  = e / (Cin * 32);
    int rem = e - kb * (Cin * 32);
    int o   = rem >> 5;
    int kk  = rem & 31;
    int cch = kb / 6, t6 = kb % 6, k = t6 >> 1, chalf = t6 & 1;
    int c = cch * 64 + chalf * 32 + kk;
    wprep[doff + e] = f2bf(src[((size_t)o * Cin + c) * 3 + k]);
}

// ---------------- S4 prep: build per-h MFMA A-matrices (coalesced writes) ----------
// TA[h][kb(6)][m(128)][kk(32)]: kb 0..3 Toeplitz K'[m-col], kb 4..5 W[m][j]
// VA[h][kb(4)][row(64)][kk(32)]: V[2n+ri][s] = w^(127-s) Re/Im
// rs[h][128]: prefix sums of K'; Vrs[h][64]: rowsum of V
__global__ __launch_bounds__(128) void prep_s4(
    const float* __restrict__ log_dt, const float* __restrict__ C2,
    const float* __restrict__ Dv,
    unsigned short* __restrict__ TA, unsigned short* __restrict__ VA,
    float* __restrict__ rs, float* __restrict__ Vrs)
{
    int h = blockIdx.x, t = threadIdx.x;
    __shared__ float cn[64];
    __shared__ float sK[128];
    __shared__ unsigned short s_w[128 * 66];   // W staged [m][j], pad 66
    float dt = expf(log_dt[h]);
    if (t < 32) {
        int n = t;
        float e = expf(-0.5f*dt);
        float s_, c_; sincosf(PI_F*dt*n, &s_, &c_);
        float wr = e*c_, wi = e*s_;
        float ar = -0.5f, ai = PI_F*n;
        float den = 1.f/(ar*ar + ai*ai);
        float tr = wr - 1.f, ti = wi;
        float qr = (tr*ar + ti*ai)*den;
        float qi = (ti*ar - tr*ai)*den;
        float c2r = C2[((size_t)h*32+n)*2], c2i = C2[((size_t)h*32+n)*2+1];
        cn[2*n]   = 2.f*(c2r*qr - c2i*qi);
        cn[2*n+1] = 2.f*(c2r*qi + c2i*qr);
        // Vrs = sum_{j=0}^{127} w^j = (1 - w^128)/(1 - w)
        float e128 = expf(-64.f*dt);
        float s2, c2v; sincosf(PI_F*dt*n*128.f, &s2, &c2v);
        float pr = 1.f - e128*c2v, pim = -e128*s2;
        float dr = 1.f - wr, di = -wi;
        float dd = 1.f/(dr*dr + di*di);
        Vrs[(size_t)h*64 + 2*n]   = (pr*dr + pim*di)*dd;
        Vrs[(size_t)h*64 + 2*n+1] = (pim*dr - pr*di)*dd;
    }
    __syncthreads();
    // phase 1: K[t] (each thread one tap)
    {
        float em = expf(-0.5f*dt*t);
        float Kt = 0.f;
        for (int n = 0; n < 32; n++) {
            float s_, c_; sincosf(PI_F*dt*(float)(n*t), &s_, &c_);
            Kt += cn[2*n]*em*c_ - cn[2*n+1]*em*s_;
        }
        sK[t] = Kt + (t == 0 ? Dv[h] : 0.f);
    }
    // phase 2: wave0 (t<64) builds W columns into LDS; wave1 builds V rows direct
    if (t < 64) {
        int n = t >> 1, ri = t & 1;
        float e = expf(-0.5f*dt);
        float s_, c_; sincosf(PI_F*dt*n, &s_, &c_);
        float wr = e*c_, wi = e*s_;
        float crn = cn[2*n], cin = cn[2*n+1];
        float pr = wr, pim = wi;                    // w^(m+1), m=0
        for (int m = 0; m < 128; m++) {
            float re = crn*pr - cin*pim;
            float im = crn*pim + cin*pr;
            s_w[m*66 + t] = f2bf(ri ? -im : re);
            float nr = pr*wr - pim*wi;
            float ni = pr*wi + pim*wr;
            pr = nr; pim = ni;
        }
    } else {
        int r = t - 64; int n = r >> 1, ri = r & 1;
        float e = expf(-0.5f*dt);
        float s_, c_; sincosf(PI_F*dt*n, &s_, &c_);
        float wr = e*c_, wi = e*s_;
        float cr2 = 1.f, ci2 = 0.f;                 // w^0
        for (int kb = 3; kb >= 0; kb--) {
            unsigned short buf[32];
            for (int kk = 31; kk >= 0; kk--) {
                buf[kk] = f2bf(ri ? ci2 : cr2);
                float nr = cr2*wr - ci2*wi;
                float ni = cr2*wi + ci2*wr;
                cr2 = nr; ci2 = ni;
            }
            uint4* dst = (uint4*)&VA[(((size_t)h*4 + kb)*64 + r)*32];
            uint4* src = (uint4*)buf;
            dst[0]=src[0]; dst[1]=src[1]; dst[2]=src[2]; dst[3]=src[3];
        }
    }
    __syncthreads();
    // prefix sum for BN shift
    {
        float acc = 0.f;
        for (int tau = 0; tau <= t; tau++) acc += sK[tau];
        rs[(size_t)h*128 + t] = acc;
    }
    // Toeplitz row t, buffered uint4 stores
    for (int kb = 0; kb < 4; kb++) {
        unsigned short tb[32];
#pragma unroll
        for (int kk = 0; kk < 32; kk++) {
            int col = kb*32 + kk;
            tb[kk] = f2bf((col <= t) ? sK[t - col] : 0.f);
        }
        uint4* dst = (uint4*)&TA[(((size_t)h*6 + kb)*128 + t)*32];
        uint4* src = (uint4*)tb;
        dst[0]=src[0]; dst[1]=src[1]; dst[2]=src[2]; dst[3]=src[3];
    }
    // W copy-out, coalesced: 1024 uint4 over kb'(2) x m(128) x kkg(4)
    for (int i = t; i < 1024; i += 128) {
        int kb = i >> 9;             // 0..1
        int rem = i & 511;
        int m = rem >> 2, kkg = rem & 3;
        *(uint4*)&TA[(((size_t)h*6 + 4 + kb)*128 + m)*32 + kkg*8] =
            *(const uint4*)&s_w[m*66 + kb*32 + kkg*8];
    }
}

// ---------------- slim prep (s4c): V rows + rowsums, coalesced ----------------
__global__ __launch_bounds__(64) void prep_va(
    const float* __restrict__ log_dt,
    unsigned short* __restrict__ VA, float* __restrict__ Vrs)
{
    int h = blockIdx.x, t = threadIdx.x;     // t = row = 2n+ri
    int n = t >> 1, ri = t & 1;
    float dt = expf(log_dt[h]);
    float e = expf(-0.5f*dt);
    float s_, c_; sincosf(PI_F*dt*n, &s_, &c_);
    float wr = e*c_, wi = e*s_;
    float cr2 = 1.f, ci2 = 0.f;              // w^0 -> col 127
    for (int kb = 3; kb >= 0; kb--) {
        unsigned short buf[32];
        for (int kk = 31; kk >= 0; kk--) {
            buf[kk] = f2bf(ri ? ci2 : cr2);
            float nr = cr2*wr - ci2*wi;
            float ni = cr2*wi + ci2*wr;
            cr2 = nr; ci2 = ni;
        }
        uint4* dst = (uint4*)&VA[(((size_t)h*4 + kb)*64 + t)*32];
        uint4* src = (uint4*)buf;
        dst[0]=src[0]; dst[1]=src[1]; dst[2]=src[2]; dst[3]=src[3];
    }
    if (ri == 0) {
        float e128 = expf(-64.f*dt);
        float s2, c2v; sincosf(PI_F*dt*n*128.f, &s2, &c2v);
        float pr = 1.f - e128*c2v, pim = -e128*s2;
        float dr = 1.f - wr, di = -wi;
        float dd = 1.f/(dr*dr + di*di);
        Vrs[(size_t)h*64 + 2*n]   = (pr*dr + pim*di)*dd;
        Vrs[(size_t)h*64 + 2*n+1] = (pim*dr - pr*di)*dd;
    }
}

// ---------------- S4 pass A (GEMM): chunk end-states E = V @ u ----------------
template<int NCH, int LOGNCH>
__global__ __launch_bounds__(64) void s4_gemm_a(
    const unsigned short* __restrict__ u, const unsigned short* __restrict__ VA,
    const float* __restrict__ Vrs, const float* __restrict__ sc,
    const float* __restrict__ sh, float* __restrict__ Bc)
{
    const int L = NCH * 128;
    int h = blockIdx.y;
    int lane = threadIdx.x;
    int nl = lane & 15, g = lane >> 4;
    int col = blockIdx.x * 16 + nl;
    int b = col >> LOGNCH, c = col & (NCH - 1);
    const unsigned short* up = u + ((size_t)h*16 + b)*L + c*128;
    f32x4 acc[4];
#pragma unroll
    for (int mt = 0; mt < 4; mt++) acc[mt] = (f32x4){0.f,0.f,0.f,0.f};
#pragma unroll
    for (int kb = 0; kb < 4; kb++) {
        short8 bf = *(const short8*)(up + kb*32 + g*8);
#pragma unroll
        for (int mt = 0; mt < 4; mt++) {
            short8 af = *(const short8*)(VA + (((size_t)h*4 + kb)*64 + mt*16 + nl)*32 + g*8);
            acc[mt] = __builtin_amdgcn_mfma_f32_16x16x32_bf16(af, bf, acc[mt], 0, 0, 0);
        }
    }
    float scv = sc ? sc[h] : 1.f;
    float shv = sh ? sh[h] : 0.f;
    float* bp = Bc + (((size_t)h*16 + b)*NCH + c)*64;
#pragma unroll
    for (int mt = 0; mt < 4; mt++) {
        int j0 = mt*16 + g*4;
        float4 vr = *(const float4*)(Vrs + (size_t)h*64 + j0);
        float4 o;
        o.x = fmaf(scv, acc[mt][0], shv*vr.x);
        o.y = fmaf(scv, acc[mt][1], shv*vr.y);
        o.z = fmaf(scv, acc[mt][2], shv*vr.z);
        o.w = fmaf(scv, acc[mt][3], shv*vr.w);
        *(float4*)(bp + j0) = o;
    }
}

// ---------------- S4 mid: chunk-level scan (w^128 via 7 squarings) ----------------
__global__ __launch_bounds__(64) void s4_mid(
    const float* __restrict__ log_dt, const float* __restrict__ Bc,
    float* __restrict__ Sinit, float* __restrict__ Sfinal,
    int H, int NCH)
{
    int gid = blockIdx.x * 64 + threadIdx.x;   // H*16*32
    int n = gid & 31;
    int tmp = gid >> 5;
    int b = tmp & 15;
    int h = tmp >> 4;
    float dt = expf(log_dt[h]);
    float e = expf(-0.5f * dt);
    float s_, c_; sincosf(PI_F * dt * n, &s_, &c_);
    float wr = e * c_, wi = e * s_;
#pragma unroll
    for (int i = 0; i < 7; i++) { float r = wr*wr - wi*wi; float im = 2.f*wr*wi; wr = r; wi = im; }
    float Sr = 0.f, Si = 0.f;
    size_t base = (((size_t)h*16 + b)*NCH)*64 + 2*n;
    for (int c = 0; c < NCH; c++) {
        float2 v; v.x = Sr; v.y = Si;
        *(float2*)(Sinit + base + (size_t)c*64) = v;
        float2 bc = *(const float2*)(Bc + base + (size_t)c*64);
        float r  = fmaf(wr, Sr, fmaf(-wi, Si, bc.x));
        float im = fmaf(wi, Sr, fmaf( wr, Si, bc.y));
        Sr = r; Si = im;
    }
    if (Sfinal) {
        float2 v; v.x = Sr; v.y = Si;
        *(float2*)(Sfinal + ((size_t)h*16 + b)*64 + 2*n) = v;
    }
}

// ---------------- S4 pass C (GEMM): y = sc*(T'@u) + sh*rs + W@Sinit ----------------
template<int NCH, int LOGNCH>
__global__ __launch_bounds__(256) void s4_gemm_c(
    const unsigned short* __restrict__ u, const float* __restrict__ Sini,
    const unsigned short* __restrict__ TA, const float* __restrict__ rs,
    const float* __restrict__ sc, const float* __restrict__ sh,
    unsigned short* __restrict__ yout)
{
    const int L = NCH * 128;
    __shared__ unsigned short s_u[64*200];   // 25600 B
    __shared__ unsigned short s_s[64*72];    // 9216 B
    int h = blockIdx.y;
    int tid = threadIdx.x;
    int lane = tid & 63, wid = tid >> 6;
    int nl = lane & 15, g = lane >> 4;
    int col0 = blockIdx.x * 64;
    for (int i = tid; i < 1024; i += 256) {
        int cl = i >> 4, o = i & 15;
        int col = col0 + cl; int b = col >> LOGNCH, c = col & (NCH - 1);
        *(uint4*)&s_u[cl*200 + o*8] =
            *(const uint4*)&u[((size_t)h*16 + b)*L + c*128 + o*8];
    }
    for (int i = tid; i < 1024; i += 256) {
        int cl = i >> 4, o = i & 15;
        int col = col0 + cl; int b = col >> LOGNCH, c = col & (NCH - 1);
        float4 v = *(const float4*)&Sini[(((size_t)h*16 + b)*NCH + c)*64 + o*4];
        ushort4 q; q.x = f2bf(v.x); q.y = f2bf(v.y); q.z = f2bf(v.z); q.w = f2bf(v.w);
        *(ushort4*)&s_s[cl*72 + o*4] = q;
    }
    __syncthreads();
    f32x4 accT[2][4], accW[2][4];
#pragma unroll
    for (int a = 0; a < 2; a++)
#pragma unroll
        for (int j = 0; j < 4; j++) { accT[a][j] = (f32x4){0,0,0,0}; accW[a][j] = (f32x4){0,0,0,0}; }
#pragma unroll
    for (int kb = 0; kb < 4; kb++) {
        short8 bfr[4];
#pragma unroll
        for (int j = 0; j < 4; j++)
            bfr[j] = *(const short8*)&s_u[(j*16 + nl)*200 + kb*32 + g*8];
#pragma unroll
        for (int mt2 = 0; mt2 < 2; mt2++) {
            int mtile = wid*2 + mt2;
            short8 af = *(const short8*)&TA[(((size_t)h*6 + kb)*128 + mtile*16 + nl)*32 + g*8];
#pragma unroll
            for (int j = 0; j < 4; j++)
                accT[mt2][j] = __builtin_amdgcn_mfma_f32_16x16x32_bf16(af, bfr[j], accT[mt2][j], 0, 0, 0);
        }
    }
#pragma unroll
    for (int kw = 0; kw < 2; kw++) {
        short8 bfr[4];
#pragma unroll
        for (int j = 0; j < 4; j++)
            bfr[j] = *(const short8*)&s_s[(j*16 + nl)*72 + kw*32 + g*8];
#pragma unroll
        for (int mt2 = 0; mt2 < 2; mt2++) {
            int mtile = wid*2 + mt2;
            short8 af = *(const short8*)&TA[(((size_t)h*6 + 4 + kw)*128 + mtile*16 + nl)*32 + g*8];
#pragma unroll
            for (int j = 0; j < 4; j++)
                accW[mt2][j] = __builtin_amdgcn_mfma_f32_16x16x32_bf16(af, bfr[j], accW[mt2][j], 0, 0, 0);
        }
    }
    float scv = sc ? sc[h] : 1.f;
    float shv = sh ? sh[h] : 0.f;
#pragma unroll
    for (int mt2 = 0; mt2 < 2; mt2++) {
        int m0 = (wid*2 + mt2)*16 + g*4;
        float4 rsv = *(const float4*)&rs[(size_t)h*128 + m0];
#pragma unroll
        for (int j = 0; j < 4; j++) {
            int col = col0 + j*16 + nl; int b = col >> LOGNCH, c = col & (NCH - 1);
            ushort4 q;
            q.x = f2bf(fmaf(scv, accT[mt2][j][0], shv*rsv.x) + accW[mt2][j][0]);
            q.y = f2bf(fmaf(scv, accT[mt2][j][1], shv*rsv.y) + accW[mt2][j][1]);
            q.z = f2bf(fmaf(scv, accT[mt2][j][2], shv*rsv.z) + accW[mt2][j][2]);
            q.w = f2bf(fmaf(scv, accT[mt2][j][3], shv*rsv.w) + accW[mt2][j][3]);
            *(ushort4*)&yout[((size_t)h*16 + b)*L + c*128 + m0] = q;
        }
    }
}

// ---------------- fused 4-dilation conv block via MFMA (v6) ----------------
// computes all 4 dilated convs (dil = 1,2,4,8) from one LDS staging.
// u [CIN][16][Lin] bf16 -> out [4*CIN][16][Lout] bf16 (out ch = d*CIN + og + local)
// v6 = v5 schedule with launch_bounds(256,2). v5's (256,4) made the allocator
// clamp to the 64-VGPR occupancy step -> ~50MB scratch spills (FETCH 72MB,
// WRITE 69MB), dur 86us. (256,2) grants up to 256 VGPRs; needed ~100-120
// (acc 32 + stg 20 + temps) -> no spill, and runtime occupancy is LDS-limited
// at 4 blocks/CU for conv2's 36.9KB dbuf (the 2nd arg is a MINIMUM, not a cap
// on achieved occupancy). T14 split retained: stage_load (issue, no wait)
// before the MFMA phase; stage_write (vmcnt wait + ds_writes) after it.
// Race audit unchanged (two barriers separate buffer reuse). Conflicts: 0.
template<int CIN, int TBLK>
__global__ __launch_bounds__(256, 2) void conv_mfma4(
    const unsigned short* __restrict__ u, const unsigned short* __restrict__ wp,
    const float* __restrict__ bs0, const float* __restrict__ bs1,
    const float* __restrict__ bs2, const float* __restrict__ bs3,
    unsigned short* __restrict__ out, int Lin, int Lout)
{
    constexpr int F     = TBLK / 16;          // output t-tiles per wave (2)
    constexpr int NPOS  = TBLK * 4 + 16;      // staged input positions (144)
    constexpr int Q     = NPOS / 4;           // q rows per residue plane (36)
    constexpr int NITEM = (NPOS / 8) * 64;    // uint4 load items (1152)
    constexpr int NLD   = (NITEM + 255) / 256;// loads per thread (5)
    constexpr int NCC   = CIN / 64;           // cc0 chunks (4 or 1)
    constexpr int NBUF  = (NCC > 1) ? 2 : 1;  // LDS double-buffer only if chunked
    constexpr int BUFSZ = 4 * Q * 64;         // shorts per buffer (9216)
    __shared__ unsigned short s_in[NBUF * BUFSZ];   // 36864 B / 18432 B

    int tid = threadIdx.x;
    int lane = tid & 63, wid = tid >> 6;
    int nl = lane & 15, g = lane >> 4;
    int t0 = blockIdx.x * TBLK;
    int b  = blockIdx.y;
    int og = blockIdx.z * 64;
    const int P0 = t0 * 4 - 8;

    f32x4 acc[4][F];
#pragma unroll
    for (int d = 0; d < 4; d++)
#pragma unroll
        for (int f = 0; f < F; f++) acc[d][f] = (f32x4){0.f,0.f,0.f,0.f};

    uint4 stg[NLD];

    // issue global loads only (no wait) -- ccbase is the CHANNEL BASE (chunk*64)
    auto stage_load = [&](int ccbase) {
#pragma unroll
        for (int j = 0; j < NLD; j++) {
            int i = tid + 256 * j;
            uint4 v; v.x = 0u; v.y = 0u; v.z = 0u; v.w = 0u;
            if (i < NITEM) {
                int ch = i & 63, po = i >> 6;
                int p = P0 + po * 8;
                const unsigned short* gp = u + ((size_t)(ccbase + ch)*16 + b)*Lin;
                if (p >= 0 && p + 8 <= Lin) {
                    v = *(const uint4*)(gp + p);
                } else {
                    alignas(16) unsigned short t8[8];
#pragma unroll
                    for (int j2 = 0; j2 < 8; j2++) {
                        int pj = p + j2;
                        t8[j2] = ((unsigned)pj < (unsigned)Lin) ? gp[pj] : (unsigned short)0;
                    }
                    v = *(const uint4*)t8;
                }
            }
            stg[j] = v;
        }
    };
    // consume stg -> LDS (the vmcnt wait lands here, AFTER the MFMA phase)
    auto stage_write = [&](int bufidx) {
        unsigned short* sb = s_in + bufidx * BUFSZ;
#pragma unroll
        for (int j = 0; j < NLD; j++) {
            int i = tid + 256 * j;
            if (i < NITEM) {
                int ch = i & 63, po = i >> 6;
                alignas(16) unsigned short t8[8];
                *(uint4*)t8 = stg[j];
#pragma unroll
                for (int jj = 0; jj < 8; jj++) {
                    int pl = po * 8 + jj;
                    int row = (pl & 3) * Q + (pl >> 2);
                    sb[row * 64 + (ch ^ ((row & 7) << 3))] = t8[jj];
                }
            }
        }
    };

    stage_load(0);
    stage_write(0);
    __syncthreads();

#pragma unroll
    for (int cc = 0; cc < NCC; cc++) {
        if (cc + 1 < NCC) stage_load((cc + 1) * 64);   // issue early; hides under MFMAs
        const unsigned short* sb = s_in + (NBUF > 1 ? (cc & 1) * BUFSZ : 0);
#pragma unroll
        for (int k = 0; k < 3; ++k) {
#pragma unroll
            for (int chalf = 0; chalf < 2; ++chalf) {
                int kb = cc * 6 + k * 2 + chalf;
#pragma unroll
                for (int d = 0; d < 4; ++d) {
                    const int DIL = 1 << d;
                    const int off = (k - 1) * DIL + 8;     // 0..16
                    const int r = off & 3, s = off >> 2;
                    short8 afrag = *(const short8*)&wp[(size_t)d*(3*CIN*CIN) +
                        ((size_t)kb*CIN + og + wid*16 + nl)*32 + g*8];
#pragma unroll
                    for (int f = 0; f < F; ++f) {
                        int q = f*16 + nl + s;
                        int row = r * Q + q;
                        short8 bfrag = *(const short8*)&sb[row * 64 +
                            ((((chalf << 2) | g) ^ (row & 7)) << 3)];
                        acc[d][f] = __builtin_amdgcn_mfma_f32_16x16x32_bf16(afrag, bfrag, acc[d][f], 0, 0, 0);
                    }
                }
            }
        }
        if (cc + 1 < NCC) {
            __syncthreads();                 // all waves done reading buf[(cc+1)&1]
            stage_write((cc + 1) & 1);       // vmcnt wait here (post-MFMA)
            __syncthreads();                 // writes visible before next MFMA phase
        }
    }

    const float* bptr[4] = {bs0, bs1, bs2, bs3};
#pragma unroll
    for (int d = 0; d < 4; ++d) {
#pragma unroll
        for (int f = 0; f < F; ++f) {
            int t = t0 + f*16 + nl;
#pragma unroll
            for (int r2 = 0; r2 < 4; ++r2) {
                int o = og + wid*16 + g*4 + r2;
                float v = acc[d][f][r2] + bptr[d][o];
                if (d) v = v >= 0.f ? v : 0.3f*v;
                out[((size_t)(d*CIN + o)*16 + b)*Lout + t] = f2bf(v);
            }
        }
    }
}

// ---------------- BN stats from bf16 [ch][b][t] ----------------
__global__ __launch_bounds__(256) void bn_stats(
    const unsigned short* __restrict__ x, const float* __restrict__ g,
    const float* __restrict__ bb, float* __restrict__ sc, float* __restrict__ sh,
    int n, int gmask)
{
    int ch = blockIdx.x;
    const unsigned short* xp = x + (size_t)ch * n;
    float s1 = 0.f, s2 = 0.f;
    for (int i = threadIdx.x*8; i < n; i += 2048) {
        uint4 raw = *(const uint4*)(xp + i);
        unsigned short us[8]; *(uint4*)us = raw;
#pragma unroll
        for (int j = 0; j < 8; j++) {
            float v = bf2f(us[j]);
            s1 += v; s2 += v*v;
        }
    }
    for (int o = 32; o > 0; o >>= 1) { s1 += __shfl_down(s1, o); s2 += __shfl_down(s2, o); }
    __shared__ float p1[4], p2[4];
    int wid = threadIdx.x >> 6;
    if ((threadIdx.x & 63) == 0) { p1[wid] = s1; p2[wid] = s2; }
    __syncthreads();
    if (threadIdx.x == 0) {
        s1 = p1[0] + p1[1] + p1[2] + p1[3];
        s2 = p2[0] + p2[1] + p2[2] + p2[3];
        float m = s1 / n;
        float var = s2 / n - m*m;
        float rstd = rsqrtf(var + 1e-5f);
        float scale = g[ch & gmask] * rstd;
        sc[ch] = scale;
        sh[ch] = fmaf(-m, scale, bb[ch & gmask]);
    }
}

// ---------------- s4c final-state -> x3[:, :, 511] ----------------
__global__ __launch_bounds__(256) void s4c_last(
    const float* __restrict__ Sfinal, const unsigned short* __restrict__ u3,
    const float* __restrict__ sc, const float* __restrict__ sh,
    const float* __restrict__ log_dt, const float* __restrict__ C2,
    const float* __restrict__ Dv, float* __restrict__ x3last)
{
    int gid = blockIdx.x*256 + threadIdx.x;  // 16*1024
    int h = gid & 1023;
    int b = gid >> 10;
    float dt = expf(log_dt[h]);
    float e = expf(-0.5f * dt);
    const float* sp = Sfinal + ((size_t)h*16 + b)*64;
    float aR = 0.f, aI = 0.f;
#pragma unroll
    for (int n = 0; n < 32; n++) {
        float s_, c_; sincosf(PI_F * dt * n, &s_, &c_);
        float wr = e*c_, wi = e*s_;
        float ar = -0.5f, ai = PI_F * n;
        float den = 1.f / (ar*ar + ai*ai);
        float tr = wr - 1.f, ti = wi;
        float qr = (tr*ar + ti*ai) * den;
        float qi = (ti*ar - tr*ai) * den;
        float c2r = C2[((size_t)h*32 + n)*2], c2i = C2[((size_t)h*32 + n)*2 + 1];
        float crv = c2r*qr - c2i*qi, civ = c2r*qi + c2i*qr;
        aR = fmaf(crv, sp[2*n],   aR);
        aI = fmaf(civ, sp[2*n+1], aI);
    }
    float uv = fmaf(sc[h], bf2f(u3[((size_t)h*16 + b)*512 + 511]), sh[h]);
    x3last[b*1024 + h] = 2.f*(aR - aI) + Dv[h]*uv;
}

// ---------------- decoder head ----------------
__global__ __launch_bounds__(256) void dec_kernel(
    const float* __restrict__ x3last, const float* __restrict__ w1, const float* __restrict__ b1,
    const float* __restrict__ w2, const float* __restrict__ b2, float* __restrict__ out)
{
    __shared__ float xs[1024];
    int b = blockIdx.x, tid = threadIdx.x;
    for (int i = tid; i < 1024; i += 256) xs[i] = x3last[b*1024 + i];
    __syncthreads();
    float z = b1[tid];
    const float* wpt = w1 + (size_t)tid*1024;
    for (int i = 0; i < 1024; i += 4) {
        float4 wv = *(const float4*)(wpt + i);
        z = fmaf(wv.x, xs[i],   z);
        z = fmaf(wv.y, xs[i+1], z);
        z = fmaf(wv.z, xs[i+2], z);
        z = fmaf(wv.w, xs[i+3], z);
    }
    float v = w2[tid] * z;
    for (int o = 32; o > 0; o >>= 1) v += __shfl_down(v, o);
    __shared__ float ps[4];
    if ((tid & 63) == 0) ps[tid >> 6] = v;
    __syncthreads();
    if (tid == 0) out[b] = ps[0] + ps[1] + ps[2] + ps[3] + b2[0];
}

extern "C" void kernel_launch(void* const* d_in, const int* in_sizes, int n_in,
                              void* d_out, int out_size, void* d_ws, size_t ws_size,
                              hipStream_t stream)
{
    const float* x       = (const float*)d_in[0];
    const float* enc_w   = (const float*)d_in[1];
    const float* enc_b   = (const float*)d_in[2];
    const float* s4a_ldt = (const float*)d_in[3];
    const float* s4a_C   = (const float*)d_in[4];
    const float* s4a_D   = (const float*)d_in[5];
    const float* s4b_ldt = (const float*)d_in[6];
    const float* s4b_C   = (const float*)d_in[7];
    const float* s4b_D   = (const float*)d_in[8];
    const float* s4c_ldt = (const float*)d_in[9];
    const float* s4c_C   = (const float*)d_in[10];
    const float* s4c_D   = (const float*)d_in[11];
    const float* b1w[4] = {(const float*)d_in[12], (const float*)d_in[14], (const float*)d_in[16], (const float*)d_in[18]};
    const float* b1b[4] = {(const float*)d_in[13], (const float*)d_in[15], (const float*)d_in[17], (const float*)d_in[19]};
    const float* b2w[4] = {(const float*)d_in[20], (const float*)d_in[22], (const float*)d_in[24], (const float*)d_in[26]};
    const float* b2b[4] = {(const float*)d_in[21], (const float*)d_in[23], (const float*)d_in[25], (const float*)d_in[27]};
    const float* bn1_g  = (const float*)d_in[28];
    const float* bn1_b  = (const float*)d_in[29];
    const float* bn2_g  = (const float*)d_in[30];
    const float* bn2_b  = (const float*)d_in[31];
    const float* dec1_w = (const float*)d_in[32];
    const float* dec1_b = (const float*)d_in[33];
    const float* dec2_w = (const float*)d_in[34];
    const float* dec2_b = (const float*)d_in[35];
    float* out = (float*)d_out;

    char* ws = (char*)d_ws;
    unsigned short* u1    = (unsigned short*)(ws);              // 16.8 MB (also u3)
    unsigned short* u3    = u1;
    unsigned short* ya    = (unsigned short*)(ws + 16777216);   // 16.8 MB (also yb, later VA_c)
    unsigned short* yb    = ya;
    unsigned short* VA_c  = ya;                                 // reuse after conv2
    unsigned short* u2    = (unsigned short*)(ws + 33554432);   // 16.8 MB
    float*          Bc    = (float*)(ws + 50331648);            // 16.8 MB
    float*          Sini  = (float*)(ws + 67108864);            // 16.8 MB
    float*          Sfin  = (float*)(ws + 83886080);            // 4.2 MB
    unsigned short* wprep = (unsigned short*)(ws + 88080384);   // 1.67 MB
    unsigned short* TA_a  = (unsigned short*)(ws + 89751552);   // 3.15 MB
    unsigned short* TA_b  = (unsigned short*)(ws + 92897280);   // 12.6 MB
    unsigned short* VA_a  = (unsigned short*)(ws + 105480192);  // 1.05 MB
    unsigned short* VA_b  = (unsigned short*)(ws + 106528768);  // 4.2 MB
    float*          rs_a  = (float*)(ws + 110723072);           // 32 KB
    float*          rs_b  = (float*)(ws + 110755840);           // 128 KB
    float*          Vrs_a = (float*)(ws + 110886912);           // 16 KB
    float*          Vrs_b = (float*)(ws + 110903296);           // 64 KB
    float*          smallp= (float*)(ws + 110968832);
    float* sc1 = smallp;         // 256
    float* sh1 = smallp + 256;   // 256
    float* sc2 = smallp + 512;   // 1024
    float* sh2 = smallp + 1536;  // 1024
    float* x3l = smallp + 2560;  // 16384
    float*          Vrs_c = (float*)(ws + 111280128);           // 256 KB

    // prep (independent of data path)
    prep_w<<<dim3(768, 8), 256, 0, stream>>>(b1w[0], b1w[1], b1w[2], b1w[3],
                                             b2w[0], b2w[1], b2w[2], b2w[3], wprep);
    prep_s4<<<64, 128, 0, stream>>>(s4a_ldt, s4a_C, s4a_D, TA_a, VA_a, rs_a, Vrs_a);
    prep_s4<<<256, 128, 0, stream>>>(s4b_ldt, s4b_C, s4b_D, TA_b, VA_b, rs_b, Vrs_b);

    // encoder -> u1 bf16
    enc_kernel<<<8192, 256, 0, stream>>>(x, enc_w, enc_b, u1);

    // s4a: H=64, NCH=64 (L=8192)
    s4_gemm_a<64,6><<<dim3(64, 64), 64, 0, stream>>>(u1, VA_a, Vrs_a, nullptr, nullptr, Bc);
    s4_mid<<<512, 64, 0, stream>>>(s4a_ldt, Bc, Sini, nullptr, 64, 64);
    s4_gemm_c<64,6><<<dim3(16, 64), 256, 0, stream>>>(u1, Sini, TA_a, rs_a, nullptr, nullptr, ya);

    // conv block1 (fused 4 dilations): ya [64][16][8192] -> u2 [256][16][2048]
    // TBLK=32, single LDS buffer 18.4 KB
    conv_mfma4<64,32><<<dim3(64, 16, 1), 256, 0, stream>>>(
        ya, wprep, b1b[0], b1b[1], b1b[2], b1b[3], u2, 8192, 2048);
    bn_stats<<<256, 256, 0, stream>>>(u2, bn1_g, bn1_b, sc1, sh1, 16*2048, 63);

    // s4b: H=256, NCH=16 (L=2048)
    s4_gemm_a<16,4><<<dim3(16, 256), 64, 0, stream>>>(u2, VA_b, Vrs_b, sc1, sh1, Bc);
    s4_mid<<<2048, 64, 0, stream>>>(s4b_ldt, Bc, Sini, nullptr, 256, 16);
    s4_gemm_c<16,4><<<dim3(4, 256), 256, 0, stream>>>(u2, Sini, TA_b, rs_b, sc1, sh1, yb);

    // conv block2 (fused 4 dilations): yb [256][16][2048] -> u3 [1024][16][512]
    // TBLK=32, LDS dbuf 36.9 KB, T14 load-early/write-late, bounds (256,2)
    conv_mfma4<256,32><<<dim3(16, 16, 4), 256, 0, stream>>>(
        yb, wprep + 49152, b2b[0], b2b[1], b2b[2], b2b[3], u3, 2048, 512);
    bn_stats<<<1024, 256, 0, stream>>>(u3, bn2_g, bn2_b, sc2, sh2, 16*512, 255);

    // s4c: H=1024, NCH=4 (L=512); only final state needed.
    // yb is dead now -> reuse its 16.8 MB slot for VA_c (exact fit).
    prep_va<<<1024, 64, 0, stream>>>(s4c_ldt, VA_c, Vrs_c);
    s4_gemm_a<4,2><<<dim3(4, 1024), 64, 0, stream>>>(u3, VA_c, Vrs_c, sc2, sh2, Bc);
    s4_mid<<<8192, 64, 0, stream>>>(s4c_ldt, Bc, Sini, Sfin, 1024, 4);
    s4c_last<<<64, 256, 0, stream>>>(Sfin, u3, sc2, sh2, s4c_ldt, s4c_C, s4c_D, x3l);

    // decoder head
    dec_kernel<<<16, 256, 0, stream>>>(x3l, dec1_w, dec1_b, dec2_w, dec2_b, out);
}

// Round 8
// 418.896 us; speedup vs baseline: 1.0757x; 1.0247x over previous
//
#include <hip/hip_runtime.h>
#include <math.h>

#define PI_F 3.14159265358979323846f

typedef __attribute__((ext_vector_type(8))) short short8;
typedef __attribute__((ext_vector_type(4))) float f32x4;

__device__ __forceinline__ unsigned short f2bf(float f) {
    unsigned int u = __float_as_uint(f);
    unsigned int r = (u + 0x7fffu + ((u >> 16) & 1u)) >> 16;
    return (unsigned short)r;
}
__device__ __forceinline__ float bf2f(unsigned short v) {
    return __uint_as_float((unsigned int)v << 16);
}

// ---------------- encoder: x[16][8192][2] -> u1 bf16 [64][16][8192] ----------------
__global__ __launch_bounds__(256) void enc_kernel(
    const float* __restrict__ x, const float* __restrict__ ew,
    const float* __restrict__ eb, unsigned short* __restrict__ u1)
{
    int idx = blockIdx.x * 256 + threadIdx.x;   // 64*16*2048 threads, 4 t each
    int t4 = idx & 2047;
    int b  = (idx >> 11) & 15;
    int h  = idx >> 15;
    float w0 = ew[2*h], w1 = ew[2*h+1], bb = eb[h];
    const float* xp = x + ((size_t)b*8192 + (size_t)t4*4)*2;
    float4 a = *(const float4*)xp;
    float4 c = *(const float4*)(xp + 4);
    ushort4 o;
    o.x = f2bf(fmaf(w0, a.x, fmaf(w1, a.y, bb)));
    o.y = f2bf(fmaf(w0, a.z, fmaf(w1, a.w, bb)));
    o.z = f2bf(fmaf(w0, c.x, fmaf(w1, c.y, bb)));
    o.w = f2bf(fmaf(w0, c.z, fmaf(w1, c.w, bb)));
    *(ushort4*)(u1 + ((size_t)h*16 + b)*8192 + (size_t)t4*4) = o;
}

// ---------------- conv weight prep: fp32 [O][Cin][3] -> bf16 A-frag [kb][o][kk] ------
__global__ __launch_bounds__(256) void prep_w(
    const float* __restrict__ w0, const float* __restrict__ w1,
    const float* __restrict__ w2, const float* __restrict__ w3,
    const float* __restrict__ w4, const float* __restrict__ w5,
    const float* __restrict__ w6, const float* __restrict__ w7,
    unsigned short* __restrict__ wprep)
{
    int id = blockIdx.y;
    const float* src; int Cin; size_t doff;
    switch (id) {
        case 0: src = w0; Cin = 64;  doff = 0;      break;
        case 1: src = w1; Cin = 64;  doff = 12288;  break;
        case 2: src = w2; Cin = 64;  doff = 24576;  break;
        case 3: src = w3; Cin = 64;  doff = 36864;  break;
        case 4: src = w4; Cin = 256; doff = 49152;  break;
        case 5: src = w5; Cin = 256; doff = 245760; break;
        case 6: src = w6; Cin = 256; doff = 442368; break;
        default: src = w7; Cin = 256; doff = 638976; break;
    }
    int e = blockIdx.x * 256 + threadIdx.x;
    if (e >= Cin * Cin * 3) return;
    int kb  = e / (Cin * 32);
    int rem = e - kb * (Cin * 32);
    int o   = rem >> 5;
    int kk  = rem & 31;
    int cch = kb / 6, t6 = kb % 6, k = t6 >> 1, chalf = t6 & 1;
    int c = cch * 64 + chalf * 32 + kk;
    wprep[doff + e] = f2bf(src[((size_t)o * Cin + c) * 3 + k]);
}

// ---------------- S4 prep: build per-h MFMA A-matrices (coalesced writes) ----------
// TA[h][kb(6)][m(128)][kk(32)]: kb 0..3 Toeplitz K'[m-col], kb 4..5 W[m][j]
// VA[h][kb(4)][row(64)][kk(32)]: V[2n+ri][s] = w^(127-s) Re/Im
// rs[h][128]: prefix sums of K'; Vrs[h][64]: rowsum of V
__global__ __launch_bounds__(128) void prep_s4(
    const float* __restrict__ log_dt, const float* __restrict__ C2,
    const float* __restrict__ Dv,
    unsigned short* __restrict__ TA, unsigned short* __restrict__ VA,
    float* __restrict__ rs, float* __restrict__ Vrs)
{
    int h = blockIdx.x, t = threadIdx.x;
    __shared__ float cn[64];
    __shared__ float sK[128];
    __shared__ unsigned short s_w[128 * 66];   // W staged [m][j], pad 66
    float dt = expf(log_dt[h]);
    if (t < 32) {
        int n = t;
        float e = expf(-0.5f*dt);
        float s_, c_; sincosf(PI_F*dt*n, &s_, &c_);
        float wr = e*c_, wi = e*s_;
        float ar = -0.5f, ai = PI_F*n;
        float den = 1.f/(ar*ar + ai*ai);
        float tr = wr - 1.f, ti = wi;
        float qr = (tr*ar + ti*ai)*den;
        float qi = (ti*ar - tr*ai)*den;
        float c2r = C2[((size_t)h*32+n)*2], c2i = C2[((size_t)h*32+n)*2+1];
        cn[2*n]   = 2.f*(c2r*qr - c2i*qi);
        cn[2*n+1] = 2.f*(c2r*qi + c2i*qr);
        // Vrs = sum_{j=0}^{127} w^j = (1 - w^128)/(1 - w)
        float e128 = expf(-64.f*dt);
        float s2, c2v; sincosf(PI_F*dt*n*128.f, &s2, &c2v);
        float pr = 1.f - e128*c2v, pim = -e128*s2;
        float dr = 1.f - wr, di = -wi;
        float dd = 1.f/(dr*dr + di*di);
        Vrs[(size_t)h*64 + 2*n]   = (pr*dr + pim*di)*dd;
        Vrs[(size_t)h*64 + 2*n+1] = (pim*dr - pr*di)*dd;
    }
    __syncthreads();
    // phase 1: K[t] (each thread one tap)
    {
        float em = expf(-0.5f*dt*t);
        float Kt = 0.f;
        for (int n = 0; n < 32; n++) {
            float s_, c_; sincosf(PI_F*dt*(float)(n*t), &s_, &c_);
            Kt += cn[2*n]*em*c_ - cn[2*n+1]*em*s_;
        }
        sK[t] = Kt + (t == 0 ? Dv[h] : 0.f);
    }
    // phase 2: wave0 (t<64) builds W columns into LDS; wave1 builds V rows direct
    if (t < 64) {
        int n = t >> 1, ri = t & 1;
        float e = expf(-0.5f*dt);
        float s_, c_; sincosf(PI_F*dt*n, &s_, &c_);
        float wr = e*c_, wi = e*s_;
        float crn = cn[2*n], cin = cn[2*n+1];
        float pr = wr, pim = wi;                    // w^(m+1), m=0
        for (int m = 0; m < 128; m++) {
            float re = crn*pr - cin*pim;
            float im = crn*pim + cin*pr;
            s_w[m*66 + t] = f2bf(ri ? -im : re);
            float nr = pr*wr - pim*wi;
            float ni = pr*wi + pim*wr;
            pr = nr; pim = ni;
        }
    } else {
        int r = t - 64; int n = r >> 1, ri = r & 1;
        float e = expf(-0.5f*dt);
        float s_, c_; sincosf(PI_F*dt*n, &s_, &c_);
        float wr = e*c_, wi = e*s_;
        float cr2 = 1.f, ci2 = 0.f;                 // w^0
        for (int kb = 3; kb >= 0; kb--) {
            unsigned short buf[32];
            for (int kk = 31; kk >= 0; kk--) {
                buf[kk] = f2bf(ri ? ci2 : cr2);
                float nr = cr2*wr - ci2*wi;
                float ni = cr2*wi + ci2*wr;
                cr2 = nr; ci2 = ni;
            }
            uint4* dst = (uint4*)&VA[(((size_t)h*4 + kb)*64 + r)*32];
            uint4* src = (uint4*)buf;
            dst[0]=src[0]; dst[1]=src[1]; dst[2]=src[2]; dst[3]=src[3];
        }
    }
    __syncthreads();
    // prefix sum for BN shift
    {
        float acc = 0.f;
        for (int tau = 0; tau <= t; tau++) acc += sK[tau];
        rs[(size_t)h*128 + t] = acc;
    }
    // Toeplitz row t, buffered uint4 stores
    for (int kb = 0; kb < 4; kb++) {
        unsigned short tb[32];
#pragma unroll
        for (int kk = 0; kk < 32; kk++) {
            int col = kb*32 + kk;
            tb[kk] = f2bf((col <= t) ? sK[t - col] : 0.f);
        }
        uint4* dst = (uint4*)&TA[(((size_t)h*6 + kb)*128 + t)*32];
        uint4* src = (uint4*)tb;
        dst[0]=src[0]; dst[1]=src[1]; dst[2]=src[2]; dst[3]=src[3];
    }
    // W copy-out, coalesced: 1024 uint4 over kb'(2) x m(128) x kkg(4)
    for (int i = t; i < 1024; i += 128) {
        int kb = i >> 9;             // 0..1
        int rem = i & 511;
        int m = rem >> 2, kkg = rem & 3;
        *(uint4*)&TA[(((size_t)h*6 + 4 + kb)*128 + m)*32 + kkg*8] =
            *(const uint4*)&s_w[m*66 + kb*32 + kkg*8];
    }
}

// ---------------- slim prep (s4c): V rows + rowsums, coalesced ----------------
__global__ __launch_bounds__(64) void prep_va(
    const float* __restrict__ log_dt,
    unsigned short* __restrict__ VA, float* __restrict__ Vrs)
{
    int h = blockIdx.x, t = threadIdx.x;     // t = row = 2n+ri
    int n = t >> 1, ri = t & 1;
    float dt = expf(log_dt[h]);
    float e = expf(-0.5f*dt);
    float s_, c_; sincosf(PI_F*dt*n, &s_, &c_);
    float wr = e*c_, wi = e*s_;
    float cr2 = 1.f, ci2 = 0.f;              // w^0 -> col 127
    for (int kb = 3; kb >= 0; kb--) {
        unsigned short buf[32];
        for (int kk = 31; kk >= 0; kk--) {
            buf[kk] = f2bf(ri ? ci2 : cr2);
            float nr = cr2*wr - ci2*wi;
            float ni = cr2*wi + ci2*wr;
            cr2 = nr; ci2 = ni;
        }
        uint4* dst = (uint4*)&VA[(((size_t)h*4 + kb)*64 + t)*32];
        uint4* src = (uint4*)buf;
        dst[0]=src[0]; dst[1]=src[1]; dst[2]=src[2]; dst[3]=src[3];
    }
    if (ri == 0) {
        float e128 = expf(-64.f*dt);
        float s2, c2v; sincosf(PI_F*dt*n*128.f, &s2, &c2v);
        float pr = 1.f - e128*c2v, pim = -e128*s2;
        float dr = 1.f - wr, di = -wi;
        float dd = 1.f/(dr*dr + di*di);
        Vrs[(size_t)h*64 + 2*n]   = (pr*dr + pim*di)*dd;
        Vrs[(size_t)h*64 + 2*n+1] = (pim*dr - pr*di)*dd;
    }
}

// ---------------- S4 pass A (GEMM): chunk end-states E = V @ u ----------------
template<int NCH, int LOGNCH>
__global__ __launch_bounds__(64) void s4_gemm_a(
    const unsigned short* __restrict__ u, const unsigned short* __restrict__ VA,
    const float* __restrict__ Vrs, const float* __restrict__ sc,
    const float* __restrict__ sh, float* __restrict__ Bc)
{
    const int L = NCH * 128;
    int h = blockIdx.y;
    int lane = threadIdx.x;
    int nl = lane & 15, g = lane >> 4;
    int col = blockIdx.x * 16 + nl;
    int b = col >> LOGNCH, c = col & (NCH - 1);
    const unsigned short* up = u + ((size_t)h*16 + b)*L + c*128;
    f32x4 acc[4];
#pragma unroll
    for (int mt = 0; mt < 4; mt++) acc[mt] = (f32x4){0.f,0.f,0.f,0.f};
#pragma unroll
    for (int kb = 0; kb < 4; kb++) {
        short8 bf = *(const short8*)(up + kb*32 + g*8);
#pragma unroll
        for (int mt = 0; mt < 4; mt++) {
            short8 af = *(const short8*)(VA + (((size_t)h*4 + kb)*64 + mt*16 + nl)*32 + g*8);
            acc[mt] = __builtin_amdgcn_mfma_f32_16x16x32_bf16(af, bf, acc[mt], 0, 0, 0);
        }
    }
    float scv = sc ? sc[h] : 1.f;
    float shv = sh ? sh[h] : 0.f;
    float* bp = Bc + (((size_t)h*16 + b)*NCH + c)*64;
#pragma unroll
    for (int mt = 0; mt < 4; mt++) {
        int j0 = mt*16 + g*4;
        float4 vr = *(const float4*)(Vrs + (size_t)h*64 + j0);
        float4 o;
        o.x = fmaf(scv, acc[mt][0], shv*vr.x);
        o.y = fmaf(scv, acc[mt][1], shv*vr.y);
        o.z = fmaf(scv, acc[mt][2], shv*vr.z);
        o.w = fmaf(scv, acc[mt][3], shv*vr.w);
        *(float4*)(bp + j0) = o;
    }
}

// ---------------- S4 mid: chunk-level scan (w^128 via 7 squarings) ----------------
__global__ __launch_bounds__(64) void s4_mid(
    const float* __restrict__ log_dt, const float* __restrict__ Bc,
    float* __restrict__ Sinit, float* __restrict__ Sfinal,
    int H, int NCH)
{
    int gid = blockIdx.x * 64 + threadIdx.x;   // H*16*32
    int n = gid & 31;
    int tmp = gid >> 5;
    int b = tmp & 15;
    int h = tmp >> 4;
    float dt = expf(log_dt[h]);
    float e = expf(-0.5f * dt);
    float s_, c_; sincosf(PI_F * dt * n, &s_, &c_);
    float wr = e * c_, wi = e * s_;
#pragma unroll
    for (int i = 0; i < 7; i++) { float r = wr*wr - wi*wi; float im = 2.f*wr*wi; wr = r; wi = im; }
    float Sr = 0.f, Si = 0.f;
    size_t base = (((size_t)h*16 + b)*NCH)*64 + 2*n;
    for (int c = 0; c < NCH; c++) {
        float2 v; v.x = Sr; v.y = Si;
        *(float2*)(Sinit + base + (size_t)c*64) = v;
        float2 bc = *(const float2*)(Bc + base + (size_t)c*64);
        float r  = fmaf(wr, Sr, fmaf(-wi, Si, bc.x));
        float im = fmaf(wi, Sr, fmaf( wr, Si, bc.y));
        Sr = r; Si = im;
    }
    if (Sfinal) {
        float2 v; v.x = Sr; v.y = Si;
        *(float2*)(Sfinal + ((size_t)h*16 + b)*64 + 2*n) = v;
    }
}

// ---------------- S4 pass C (GEMM): y = sc*(T'@u) + sh*rs + W@Sinit ----------------
template<int NCH, int LOGNCH>
__global__ __launch_bounds__(256) void s4_gemm_c(
    const unsigned short* __restrict__ u, const float* __restrict__ Sini,
    const unsigned short* __restrict__ TA, const float* __restrict__ rs,
    const float* __restrict__ sc, const float* __restrict__ sh,
    unsigned short* __restrict__ yout)
{
    const int L = NCH * 128;
    __shared__ unsigned short s_u[64*200];   // 25600 B
    __shared__ unsigned short s_s[64*72];    // 9216 B
    int h = blockIdx.y;
    int tid = threadIdx.x;
    int lane = tid & 63, wid = tid >> 6;
    int nl = lane & 15, g = lane >> 4;
    int col0 = blockIdx.x * 64;
    for (int i = tid; i < 1024; i += 256) {
        int cl = i >> 4, o = i & 15;
        int col = col0 + cl; int b = col >> LOGNCH, c = col & (NCH - 1);
        *(uint4*)&s_u[cl*200 + o*8] =
            *(const uint4*)&u[((size_t)h*16 + b)*L + c*128 + o*8];
    }
    for (int i = tid; i < 1024; i += 256) {
        int cl = i >> 4, o = i & 15;
        int col = col0 + cl; int b = col >> LOGNCH, c = col & (NCH - 1);
        float4 v = *(const float4*)&Sini[(((size_t)h*16 + b)*NCH + c)*64 + o*4];
        ushort4 q; q.x = f2bf(v.x); q.y = f2bf(v.y); q.z = f2bf(v.z); q.w = f2bf(v.w);
        *(ushort4*)&s_s[cl*72 + o*4] = q;
    }
    __syncthreads();
    f32x4 accT[2][4], accW[2][4];
#pragma unroll
    for (int a = 0; a < 2; a++)
#pragma unroll
        for (int j = 0; j < 4; j++) { accT[a][j] = (f32x4){0,0,0,0}; accW[a][j] = (f32x4){0,0,0,0}; }
#pragma unroll
    for (int kb = 0; kb < 4; kb++) {
        short8 bfr[4];
#pragma unroll
        for (int j = 0; j < 4; j++)
            bfr[j] = *(const short8*)&s_u[(j*16 + nl)*200 + kb*32 + g*8];
#pragma unroll
        for (int mt2 = 0; mt2 < 2; mt2++) {
            int mtile = wid*2 + mt2;
            short8 af = *(const short8*)&TA[(((size_t)h*6 + kb)*128 + mtile*16 + nl)*32 + g*8];
#pragma unroll
            for (int j = 0; j < 4; j++)
                accT[mt2][j] = __builtin_amdgcn_mfma_f32_16x16x32_bf16(af, bfr[j], accT[mt2][j], 0, 0, 0);
        }
    }
#pragma unroll
    for (int kw = 0; kw < 2; kw++) {
        short8 bfr[4];
#pragma unroll
        for (int j = 0; j < 4; j++)
            bfr[j] = *(const short8*)&s_s[(j*16 + nl)*72 + kw*32 + g*8];
#pragma unroll
        for (int mt2 = 0; mt2 < 2; mt2++) {
            int mtile = wid*2 + mt2;
            short8 af = *(const short8*)&TA[(((size_t)h*6 + 4 + kw)*128 + mtile*16 + nl)*32 + g*8];
#pragma unroll
            for (int j = 0; j < 4; j++)
                accW[mt2][j] = __builtin_amdgcn_mfma_f32_16x16x32_bf16(af, bfr[j], accW[mt2][j], 0, 0, 0);
        }
    }
    float scv = sc ? sc[h] : 1.f;
    float shv = sh ? sh[h] : 0.f;
#pragma unroll
    for (int mt2 = 0; mt2 < 2; mt2++) {
        int m0 = (wid*2 + mt2)*16 + g*4;
        float4 rsv = *(const float4*)&rs[(size_t)h*128 + m0];
#pragma unroll
        for (int j = 0; j < 4; j++) {
            int col = col0 + j*16 + nl; int b = col >> LOGNCH, c = col & (NCH - 1);
            ushort4 q;
            q.x = f2bf(fmaf(scv, accT[mt2][j][0], shv*rsv.x) + accW[mt2][j][0]);
            q.y = f2bf(fmaf(scv, accT[mt2][j][1], shv*rsv.y) + accW[mt2][j][1]);
            q.z = f2bf(fmaf(scv, accT[mt2][j][2], shv*rsv.z) + accW[mt2][j][2]);
            q.w = f2bf(fmaf(scv, accT[mt2][j][3], shv*rsv.w) + accW[mt2][j][3]);
            *(ushort4*)&yout[((size_t)h*16 + b)*L + c*128 + m0] = q;
        }
    }
}

// ---------------- fused 4-dilation conv block via MFMA (v7, resubmitted) ----------------
// computes all 4 dilated convs (dil = 1,2,4,8) from one LDS staging.
// u [CIN][16][Lin] bf16 -> out [4*CIN][16][Lout] bf16 (out ch = d*CIN + og + local)
// v7 = v6 template, conv2 back to TBLK=64. History:
//   v4: TBLK=64, stage(wait)-before-MFMA, 2blk/CU  -> 46us, FETCH 20.5MB (L2 good)
//   v6: TBLK=32, T14 split, 4blk/CU                -> 63us, FETCH 38MB (1024 blocks
//       spread og-sharing blocks across XCDs -> input re-fetched from HBM)
// v7 combines the untested pair: TBLK=64 tiling (good L2) + T14 split (stage_load
// issue-only before the MFMA phase, stage_write vmcnt-wait after it). Per chunk a
// wave has 96 MFMAs + 96 ds_read_b128 (~9k cy/CU) to hide ~900cy load latency.
// VGPR: acc 64 + stg 36 + temps ~130 at (256,2) -> no spill expected; tripwire is
// WRITE_SIZE >> 21MB. Race audit: two barriers separate buffer reuse (unchanged).
template<int CIN, int TBLK>
__global__ __launch_bounds__(256, 2) void conv_mfma4(
    const unsigned short* __restrict__ u, const unsigned short* __restrict__ wp,
    const float* __restrict__ bs0, const float* __restrict__ bs1,
    const float* __restrict__ bs2, const float* __restrict__ bs3,
    unsigned short* __restrict__ out, int Lin, int Lout)
{
    constexpr int F     = TBLK / 16;          // output t-tiles per wave (4 or 2)
    constexpr int NPOS  = TBLK * 4 + 16;      // staged input positions (272 or 144)
    constexpr int Q     = NPOS / 4;           // q rows per residue plane (68 or 36)
    constexpr int NITEM = (NPOS / 8) * 64;    // uint4 load items (2176 or 1152)
    constexpr int NLD   = (NITEM + 255) / 256;// loads per thread (9 or 5)
    constexpr int NCC   = CIN / 64;           // cc0 chunks (4 or 1)
    constexpr int NBUF  = (NCC > 1) ? 2 : 1;  // LDS double-buffer only if chunked
    constexpr int BUFSZ = 4 * Q * 64;         // shorts per buffer
    __shared__ unsigned short s_in[NBUF * BUFSZ];   // 69632 B / 18432 B

    int tid = threadIdx.x;
    int lane = tid & 63, wid = tid >> 6;
    int nl = lane & 15, g = lane >> 4;
    int t0 = blockIdx.x * TBLK;
    int b  = blockIdx.y;
    int og = blockIdx.z * 64;
    const int P0 = t0 * 4 - 8;

    f32x4 acc[4][F];
#pragma unroll
    for (int d = 0; d < 4; d++)
#pragma unroll
        for (int f = 0; f < F; f++) acc[d][f] = (f32x4){0.f,0.f,0.f,0.f};

    uint4 stg[NLD];

    // issue global loads only (no wait) -- ccbase is the CHANNEL BASE (chunk*64)
    auto stage_load = [&](int ccbase) {
#pragma unroll
        for (int j = 0; j < NLD; j++) {
            int i = tid + 256 * j;
            uint4 v; v.x = 0u; v.y = 0u; v.z = 0u; v.w = 0u;
            if (i < NITEM) {
                int ch = i & 63, po = i >> 6;
                int p = P0 + po * 8;
                const unsigned short* gp = u + ((size_t)(ccbase + ch)*16 + b)*Lin;
                if (p >= 0 && p + 8 <= Lin) {
                    v = *(const uint4*)(gp + p);
                } else {
                    alignas(16) unsigned short t8[8];
#pragma unroll
                    for (int j2 = 0; j2 < 8; j2++) {
                        int pj = p + j2;
                        t8[j2] = ((unsigned)pj < (unsigned)Lin) ? gp[pj] : (unsigned short)0;
                    }
                    v = *(const uint4*)t8;
                }
            }
            stg[j] = v;
        }
    };
    // consume stg -> LDS (the vmcnt wait lands here, AFTER the MFMA phase)
    auto stage_write = [&](int bufidx) {
        unsigned short* sb = s_in + bufidx * BUFSZ;
#pragma unroll
        for (int j = 0; j < NLD; j++) {
            int i = tid + 256 * j;
            if (i < NITEM) {
                int ch = i & 63, po = i >> 6;
                alignas(16) unsigned short t8[8];
                *(uint4*)t8 = stg[j];
#pragma unroll
                for (int jj = 0; jj < 8; jj++) {
                    int pl = po * 8 + jj;
                    int row = (pl & 3) * Q + (pl >> 2);
                    sb[row * 64 + (ch ^ ((row & 7) << 3))] = t8[jj];
                }
            }
        }
    };

    stage_load(0);
    stage_write(0);
    __syncthreads();

#pragma unroll
    for (int cc = 0; cc < NCC; cc++) {
        if (cc + 1 < NCC) stage_load((cc + 1) * 64);   // issue early; hides under MFMAs
        const unsigned short* sb = s_in + (NBUF > 1 ? (cc & 1) * BUFSZ : 0);
#pragma unroll
        for (int k = 0; k < 3; ++k) {
#pragma unroll
            for (int chalf = 0; chalf < 2; ++chalf) {
                int kb = cc * 6 + k * 2 + chalf;
#pragma unroll
                for (int d = 0; d < 4; ++d) {
                    const int DIL = 1 << d;
                    const int off = (k - 1) * DIL + 8;     // 0..16
                    const int r = off & 3, s = off >> 2;
                    short8 afrag = *(const short8*)&wp[(size_t)d*(3*CIN*CIN) +
                        ((size_t)kb*CIN + og + wid*16 + nl)*32 + g*8];
#pragma unroll
                    for (int f = 0; f < F; ++f) {
                        int q = f*16 + nl + s;
                        int row = r * Q + q;
                        short8 bfrag = *(const short8*)&sb[row * 64 +
                            ((((chalf << 2) | g) ^ (row & 7)) << 3)];
                        acc[d][f] = __builtin_amdgcn_mfma_f32_16x16x32_bf16(afrag, bfrag, acc[d][f], 0, 0, 0);
                    }
                }
            }
        }
        if (cc + 1 < NCC) {
            __syncthreads();                 // all waves done reading buf[(cc+1)&1]
            stage_write((cc + 1) & 1);       // vmcnt wait here (post-MFMA)
            __syncthreads();                 // writes visible before next MFMA phase
        }
    }

    const float* bptr[4] = {bs0, bs1, bs2, bs3};
#pragma unroll
    for (int d = 0; d < 4; ++d) {
#pragma unroll
        for (int f = 0; f < F; ++f) {
            int t = t0 + f*16 + nl;
#pragma unroll
            for (int r2 = 0; r2 < 4; ++r2) {
                int o = og + wid*16 + g*4 + r2;
                float v = acc[d][f][r2] + bptr[d][o];
                if (d) v = v >= 0.f ? v : 0.3f*v;
                out[((size_t)(d*CIN + o)*16 + b)*Lout + t] = f2bf(v);
            }
        }
    }
}

// ---------------- BN stats from bf16 [ch][b][t] ----------------
__global__ __launch_bounds__(256) void bn_stats(
    const unsigned short* __restrict__ x, const float* __restrict__ g,
    const float* __restrict__ bb, float* __restrict__ sc, float* __restrict__ sh,
    int n, int gmask)
{
    int ch = blockIdx.x;
    const unsigned short* xp = x + (size_t)ch * n;
    float s1 = 0.f, s2 = 0.f;
    for (int i = threadIdx.x*8; i < n; i += 2048) {
        uint4 raw = *(const uint4*)(xp + i);
        unsigned short us[8]; *(uint4*)us = raw;
#pragma unroll
        for (int j = 0; j < 8; j++) {
            float v = bf2f(us[j]);
            s1 += v; s2 += v*v;
        }
    }
    for (int o = 32; o > 0; o >>= 1) { s1 += __shfl_down(s1, o); s2 += __shfl_down(s2, o); }
    __shared__ float p1[4], p2[4];
    int wid = threadIdx.x >> 6;
    if ((threadIdx.x & 63) == 0) { p1[wid] = s1; p2[wid] = s2; }
    __syncthreads();
    if (threadIdx.x == 0) {
        s1 = p1[0] + p1[1] + p1[2] + p1[3];
        s2 = p2[0] + p2[1] + p2[2] + p2[3];
        float m = s1 / n;
        float var = s2 / n - m*m;
        float rstd = rsqrtf(var + 1e-5f);
        float scale = g[ch & gmask] * rstd;
        sc[ch] = scale;
        sh[ch] = fmaf(-m, scale, bb[ch & gmask]);
    }
}

// ---------------- s4c final-state -> x3[:, :, 511] ----------------
__global__ __launch_bounds__(256) void s4c_last(
    const float* __restrict__ Sfinal, const unsigned short* __restrict__ u3,
    const float* __restrict__ sc, const float* __restrict__ sh,
    const float* __restrict__ log_dt, const float* __restrict__ C2,
    const float* __restrict__ Dv, float* __restrict__ x3last)
{
    int gid = blockIdx.x*256 + threadIdx.x;  // 16*1024
    int h = gid & 1023;
    int b = gid >> 10;
    float dt = expf(log_dt[h]);
    float e = expf(-0.5f * dt);
    const float* sp = Sfinal + ((size_t)h*16 + b)*64;
    float aR = 0.f, aI = 0.f;
#pragma unroll
    for (int n = 0; n < 32; n++) {
        float s_, c_; sincosf(PI_F * dt * n, &s_, &c_);
        float wr = e*c_, wi = e*s_;
        float ar = -0.5f, ai = PI_F * n;
        float den = 1.f / (ar*ar + ai*ai);
        float tr = wr - 1.f, ti = wi;
        float qr = (tr*ar + ti*ai) * den;
        float qi = (ti*ar - tr*ai) * den;
        float c2r = C2[((size_t)h*32 + n)*2], c2i = C2[((size_t)h*32 + n)*2 + 1];
        float crv = c2r*qr - c2i*qi, civ = c2r*qi + c2i*qr;
        aR = fmaf(crv, sp[2*n],   aR);
        aI = fmaf(civ, sp[2*n+1], aI);
    }
    float uv = fmaf(sc[h], bf2f(u3[((size_t)h*16 + b)*512 + 511]), sh[h]);
    x3last[b*1024 + h] = 2.f*(aR - aI) + Dv[h]*uv;
}

// ---------------- decoder head ----------------
__global__ __launch_bounds__(256) void dec_kernel(
    const float* __restrict__ x3last, const float* __restrict__ w1, const float* __restrict__ b1,
    const float* __restrict__ w2, const float* __restrict__ b2, float* __restrict__ out)
{
    __shared__ float xs[1024];
    int b = blockIdx.x, tid = threadIdx.x;
    for (int i = tid; i < 1024; i += 256) xs[i] = x3last[b*1024 + i];
    __syncthreads();
    float z = b1[tid];
    const float* wpt = w1 + (size_t)tid*1024;
    for (int i = 0; i < 1024; i += 4) {
        float4 wv = *(const float4*)(wpt + i);
        z = fmaf(wv.x, xs[i],   z);
        z = fmaf(wv.y, xs[i+1], z);
        z = fmaf(wv.z, xs[i+2], z);
        z = fmaf(wv.w, xs[i+3], z);
    }
    float v = w2[tid] * z;
    for (int o = 32; o > 0; o >>= 1) v += __shfl_down(v, o);
    __shared__ float ps[4];
    if ((tid & 63) == 0) ps[tid >> 6] = v;
    __syncthreads();
    if (tid == 0) out[b] = ps[0] + ps[1] + ps[2] + ps[3] + b2[0];
}

extern "C" void kernel_launch(void* const* d_in, const int* in_sizes, int n_in,
                              void* d_out, int out_size, void* d_ws, size_t ws_size,
                              hipStream_t stream)
{
    const float* x       = (const float*)d_in[0];
    const float* enc_w   = (const float*)d_in[1];
    const float* enc_b   = (const float*)d_in[2];
    const float* s4a_ldt = (const float*)d_in[3];
    const float* s4a_C   = (const float*)d_in[4];
    const float* s4a_D   = (const float*)d_in[5];
    const float* s4b_ldt = (const float*)d_in[6];
    const float* s4b_C   = (const float*)d_in[7];
    const float* s4b_D   = (const float*)d_in[8];
    const float* s4c_ldt = (const float*)d_in[9];
    const float* s4c_C   = (const float*)d_in[10];
    const float* s4c_D   = (const float*)d_in[11];
    const float* b1w[4] = {(const float*)d_in[12], (const float*)d_in[14], (const float*)d_in[16], (const float*)d_in[18]};
    const float* b1b[4] = {(const float*)d_in[13], (const float*)d_in[15], (const float*)d_in[17], (const float*)d_in[19]};
    const float* b2w[4] = {(const float*)d_in[20], (const float*)d_in[22], (const float*)d_in[24], (const float*)d_in[26]};
    const float* b2b[4] = {(const float*)d_in[21], (const float*)d_in[23], (const float*)d_in[25], (const float*)d_in[27]};
    const float* bn1_g  = (const float*)d_in[28];
    const float* bn1_b  = (const float*)d_in[29];
    const float* bn2_g  = (const float*)d_in[30];
    const float* bn2_b  = (const float*)d_in[31];
    const float* dec1_w = (const float*)d_in[32];
    const float* dec1_b = (const float*)d_in[33];
    const float* dec2_w = (const float*)d_in[34];
    const float* dec2_b = (const float*)d_in[35];
    float* out = (float*)d_out;

    char* ws = (char*)d_ws;
    unsigned short* u1    = (unsigned short*)(ws);              // 16.8 MB (also u3)
    unsigned short* u3    = u1;
    unsigned short* ya    = (unsigned short*)(ws + 16777216);   // 16.8 MB (also yb, later VA_c)
    unsigned short* yb    = ya;
    unsigned short* VA_c  = ya;                                 // reuse after conv2
    unsigned short* u2    = (unsigned short*)(ws + 33554432);   // 16.8 MB
    float*          Bc    = (float*)(ws + 50331648);            // 16.8 MB
    float*          Sini  = (float*)(ws + 67108864);            // 16.8 MB
    float*          Sfin  = (float*)(ws + 83886080);            // 4.2 MB
    unsigned short* wprep = (unsigned short*)(ws + 88080384);   // 1.67 MB
    unsigned short* TA_a  = (unsigned short*)(ws + 89751552);   // 3.15 MB
    unsigned short* TA_b  = (unsigned short*)(ws + 92897280);   // 12.6 MB
    unsigned short* VA_a  = (unsigned short*)(ws + 105480192);  // 1.05 MB
    unsigned short* VA_b  = (unsigned short*)(ws + 106528768);  // 4.2 MB
    float*          rs_a  = (float*)(ws + 110723072);           // 32 KB
    float*          rs_b  = (float*)(ws + 110755840);           // 128 KB
    float*          Vrs_a = (float*)(ws + 110886912);           // 16 KB
    float*          Vrs_b = (float*)(ws + 110903296);           // 64 KB
    float*          smallp= (float*)(ws + 110968832);
    float* sc1 = smallp;         // 256
    float* sh1 = smallp + 256;   // 256
    float* sc2 = smallp + 512;   // 1024
    float* sh2 = smallp + 1536;  // 1024
    float* x3l = smallp + 2560;  // 16384
    float*          Vrs_c = (float*)(ws + 111280128);           // 256 KB

    // prep (independent of data path)
    prep_w<<<dim3(768, 8), 256, 0, stream>>>(b1w[0], b1w[1], b1w[2], b1w[3],
                                             b2w[0], b2w[1], b2w[2], b2w[3], wprep);
    prep_s4<<<64, 128, 0, stream>>>(s4a_ldt, s4a_C, s4a_D, TA_a, VA_a, rs_a, Vrs_a);
    prep_s4<<<256, 128, 0, stream>>>(s4b_ldt, s4b_C, s4b_D, TA_b, VA_b, rs_b, Vrs_b);

    // encoder -> u1 bf16
    enc_kernel<<<8192, 256, 0, stream>>>(x, enc_w, enc_b, u1);

    // s4a: H=64, NCH=64 (L=8192)
    s4_gemm_a<64,6><<<dim3(64, 64), 64, 0, stream>>>(u1, VA_a, Vrs_a, nullptr, nullptr, Bc);
    s4_mid<<<512, 64, 0, stream>>>(s4a_ldt, Bc, Sini, nullptr, 64, 64);
    s4_gemm_c<64,6><<<dim3(16, 64), 256, 0, stream>>>(u1, Sini, TA_a, rs_a, nullptr, nullptr, ya);

    // conv block1 (fused 4 dilations): ya [64][16][8192] -> u2 [256][16][2048]
    // TBLK=32, single LDS buffer 18.4 KB
    conv_mfma4<64,32><<<dim3(64, 16, 1), 256, 0, stream>>>(
        ya, wprep, b1b[0], b1b[1], b1b[2], b1b[3], u2, 8192, 2048);
    bn_stats<<<256, 256, 0, stream>>>(u2, bn1_g, bn1_b, sc1, sh1, 16*2048, 63);

    // s4b: H=256, NCH=16 (L=2048)
    s4_gemm_a<16,4><<<dim3(16, 256), 64, 0, stream>>>(u2, VA_b, Vrs_b, sc1, sh1, Bc);
    s4_mid<<<2048, 64, 0, stream>>>(s4b_ldt, Bc, Sini, nullptr, 256, 16);
    s4_gemm_c<16,4><<<dim3(4, 256), 256, 0, stream>>>(u2, Sini, TA_b, rs_b, sc1, sh1, yb);

    // conv block2 (fused 4 dilations): yb [256][16][2048] -> u3 [1024][16][512]
    // TBLK=64 (v4's L2-friendly tiling), LDS dbuf 69.6 KB, T14 load-early/write-late
    conv_mfma4<256,64><<<dim3(8, 16, 4), 256, 0, stream>>>(
        yb, wprep + 49152, b2b[0], b2b[1], b2b[2], b2b[3], u3, 2048, 512);
    bn_stats<<<1024, 256, 0, stream>>>(u3, bn2_g, bn2_b, sc2, sh2, 16*512, 255);

    // s4c: H=1024, NCH=4 (L=512); only final state needed.
    // yb is dead now -> reuse its 16.8 MB slot for VA_c (exact fit).
    prep_va<<<1024, 64, 0, stream>>>(s4c_ldt, VA_c, Vrs_c);
    s4_gemm_a<4,2><<<dim3(4, 1024), 64, 0, stream>>>(u3, VA_c, Vrs_c, sc2, sh2, Bc);
    s4_mid<<<8192, 64, 0, stream>>>(s4c_ldt, Bc, Sini, Sfin, 1024, 4);
    s4c_last<<<64, 256, 0, stream>>>(Sfin, u3, sc2, sh2, s4c_ldt, s4c_C, s4c_D, x3l);

    // decoder head
    dec_kernel<<<16, 256, 0, stream>>>(x3l, dec1_w, dec1_b, dec2_w, dec2_b, out);
}

// Round 9
// 403.794 us; speedup vs baseline: 1.1160x; 1.0374x over previous
//
#include <hip/hip_runtime.h>
#include <math.h>

#define PI_F 3.14159265358979323846f

typedef __attribute__((ext_vector_type(8))) short short8;
typedef __attribute__((ext_vector_type(4))) float f32x4;

__device__ __forceinline__ unsigned short f2bf(float f) {
    unsigned int u = __float_as_uint(f);
    unsigned int r = (u + 0x7fffu + ((u >> 16) & 1u)) >> 16;
    return (unsigned short)r;
}
__device__ __forceinline__ float bf2f(unsigned short v) {
    return __uint_as_float((unsigned int)v << 16);
}

// ---------------- encoder: x[16][8192][2] -> u1 bf16 [64][16][8192] ----------------
__global__ __launch_bounds__(256) void enc_kernel(
    const float* __restrict__ x, const float* __restrict__ ew,
    const float* __restrict__ eb, unsigned short* __restrict__ u1)
{
    int idx = blockIdx.x * 256 + threadIdx.x;   // 64*16*2048 threads, 4 t each
    int t4 = idx & 2047;
    int b  = (idx >> 11) & 15;
    int h  = idx >> 15;
    float w0 = ew[2*h], w1 = ew[2*h+1], bb = eb[h];
    const float* xp = x + ((size_t)b*8192 + (size_t)t4*4)*2;
    float4 a = *(const float4*)xp;
    float4 c = *(const float4*)(xp + 4);
    ushort4 o;
    o.x = f2bf(fmaf(w0, a.x, fmaf(w1, a.y, bb)));
    o.y = f2bf(fmaf(w0, a.z, fmaf(w1, a.w, bb)));
    o.z = f2bf(fmaf(w0, c.x, fmaf(w1, c.y, bb)));
    o.w = f2bf(fmaf(w0, c.z, fmaf(w1, c.w, bb)));
    *(ushort4*)(u1 + ((size_t)h*16 + b)*8192 + (size_t)t4*4) = o;
}

// ---------------- conv weight prep: fp32 [O][Cin][3] -> bf16 A-frag [kb][o][kk] ------
__global__ __launch_bounds__(256) void prep_w(
    const float* __restrict__ w0, const float* __restrict__ w1,
    const float* __restrict__ w2, const float* __restrict__ w3,
    const float* __restrict__ w4, const float* __restrict__ w5,
    const float* __restrict__ w6, const float* __restrict__ w7,
    unsigned short* __restrict__ wprep)
{
    int id = blockIdx.y;
    const float* src; int Cin; size_t doff;
    switch (id) {
        case 0: src = w0; Cin = 64;  doff = 0;      break;
        case 1: src = w1; Cin = 64;  doff = 12288;  break;
        case 2: src = w2; Cin = 64;  doff = 24576;  break;
        case 3: src = w3; Cin = 64;  doff = 36864;  break;
        case 4: src = w4; Cin = 256; doff = 49152;  break;
        case 5: src = w5; Cin = 256; doff = 245760; break;
        case 6: src = w6; Cin = 256; doff = 442368; break;
        default: src = w7; Cin = 256; doff = 638976; break;
    }
    int e = blockIdx.x * 256 + threadIdx.x;
    if (e >= Cin * Cin * 3) return;
    int kb  = e / (Cin * 32);
    int rem = e - kb * (Cin * 32);
    int o   = rem >> 5;
    int kk  = rem & 31;
    int cch = kb / 6, t6 = kb % 6, k = t6 >> 1, chalf = t6 & 1;
    int c = cch * 64 + chalf * 32 + kk;
    wprep[doff + e] = f2bf(src[((size_t)o * Cin + c) * 3 + k]);
}

// ---------------- S4 prep: build per-h MFMA A-matrices (coalesced writes) ----------
// TA[h][kb(6)][m(128)][kk(32)]: kb 0..3 Toeplitz K'[m-col], kb 4..5 W[m][j]
// VA[h][kb(4)][row(64)][kk(32)]: V[2n+ri][s] = w^(127-s) Re/Im
// rs[h][128]: prefix sums of K'; Vrs[h][64]: rowsum of V
__global__ __launch_bounds__(128) void prep_s4(
    const float* __restrict__ log_dt, const float* __restrict__ C2,
    const float* __restrict__ Dv,
    unsigned short* __restrict__ TA, unsigned short* __restrict__ VA,
    float* __restrict__ rs, float* __restrict__ Vrs)
{
    int h = blockIdx.x, t = threadIdx.x;
    __shared__ float cn[64];
    __shared__ float sK[128];
    __shared__ unsigned short s_w[128 * 66];   // W staged [m][j], pad 66
    float dt = expf(log_dt[h]);
    if (t < 32) {
        int n = t;
        float e = expf(-0.5f*dt);
        float s_, c_; sincosf(PI_F*dt*n, &s_, &c_);
        float wr = e*c_, wi = e*s_;
        float ar = -0.5f, ai = PI_F*n;
        float den = 1.f/(ar*ar + ai*ai);
        float tr = wr - 1.f, ti = wi;
        float qr = (tr*ar + ti*ai)*den;
        float qi = (ti*ar - tr*ai)*den;
        float c2r = C2[((size_t)h*32+n)*2], c2i = C2[((size_t)h*32+n)*2+1];
        cn[2*n]   = 2.f*(c2r*qr - c2i*qi);
        cn[2*n+1] = 2.f*(c2r*qi + c2i*qr);
        // Vrs = sum_{j=0}^{127} w^j = (1 - w^128)/(1 - w)
        float e128 = expf(-64.f*dt);
        float s2, c2v; sincosf(PI_F*dt*n*128.f, &s2, &c2v);
        float pr = 1.f - e128*c2v, pim = -e128*s2;
        float dr = 1.f - wr, di = -wi;
        float dd = 1.f/(dr*dr + di*di);
        Vrs[(size_t)h*64 + 2*n]   = (pr*dr + pim*di)*dd;
        Vrs[(size_t)h*64 + 2*n+1] = (pim*dr - pr*di)*dd;
    }
    __syncthreads();
    // phase 1: K[t] (each thread one tap)
    {
        float em = expf(-0.5f*dt*t);
        float Kt = 0.f;
        for (int n = 0; n < 32; n++) {
            float s_, c_; sincosf(PI_F*dt*(float)(n*t), &s_, &c_);
            Kt += cn[2*n]*em*c_ - cn[2*n+1]*em*s_;
        }
        sK[t] = Kt + (t == 0 ? Dv[h] : 0.f);
    }
    // phase 2: wave0 (t<64) builds W columns into LDS; wave1 builds V rows direct
    if (t < 64) {
        int n = t >> 1, ri = t & 1;
        float e = expf(-0.5f*dt);
        float s_, c_; sincosf(PI_F*dt*n, &s_, &c_);
        float wr = e*c_, wi = e*s_;
        float crn = cn[2*n], cin = cn[2*n+1];
        float pr = wr, pim = wi;                    // w^(m+1), m=0
        for (int m = 0; m < 128; m++) {
            float re = crn*pr - cin*pim;
            float im = crn*pim + cin*pr;
            s_w[m*66 + t] = f2bf(ri ? -im : re);
            float nr = pr*wr - pim*wi;
            float ni = pr*wi + pim*wr;
            pr = nr; pim = ni;
        }
    } else {
        int r = t - 64; int n = r >> 1, ri = r & 1;
        float e = expf(-0.5f*dt);
        float s_, c_; sincosf(PI_F*dt*n, &s_, &c_);
        float wr = e*c_, wi = e*s_;
        float cr2 = 1.f, ci2 = 0.f;                 // w^0
        for (int kb = 3; kb >= 0; kb--) {
            unsigned short buf[32];
            for (int kk = 31; kk >= 0; kk--) {
                buf[kk] = f2bf(ri ? ci2 : cr2);
                float nr = cr2*wr - ci2*wi;
                float ni = cr2*wi + ci2*wr;
                cr2 = nr; ci2 = ni;
            }
            uint4* dst = (uint4*)&VA[(((size_t)h*4 + kb)*64 + r)*32];
            uint4* src = (uint4*)buf;
            dst[0]=src[0]; dst[1]=src[1]; dst[2]=src[2]; dst[3]=src[3];
        }
    }
    __syncthreads();
    // prefix sum for BN shift
    {
        float acc = 0.f;
        for (int tau = 0; tau <= t; tau++) acc += sK[tau];
        rs[(size_t)h*128 + t] = acc;
    }
    // Toeplitz row t, buffered uint4 stores
    for (int kb = 0; kb < 4; kb++) {
        unsigned short tb[32];
#pragma unroll
        for (int kk = 0; kk < 32; kk++) {
            int col = kb*32 + kk;
            tb[kk] = f2bf((col <= t) ? sK[t - col] : 0.f);
        }
        uint4* dst = (uint4*)&TA[(((size_t)h*6 + kb)*128 + t)*32];
        uint4* src = (uint4*)tb;
        dst[0]=src[0]; dst[1]=src[1]; dst[2]=src[2]; dst[3]=src[3];
    }
    // W copy-out, coalesced: 1024 uint4 over kb'(2) x m(128) x kkg(4)
    for (int i = t; i < 1024; i += 128) {
        int kb = i >> 9;             // 0..1
        int rem = i & 511;
        int m = rem >> 2, kkg = rem & 3;
        *(uint4*)&TA[(((size_t)h*6 + 4 + kb)*128 + m)*32 + kkg*8] =
            *(const uint4*)&s_w[m*66 + kb*32 + kkg*8];
    }
}

// ---------------- slim prep (s4c): V rows + rowsums, coalesced ----------------
__global__ __launch_bounds__(64) void prep_va(
    const float* __restrict__ log_dt,
    unsigned short* __restrict__ VA, float* __restrict__ Vrs)
{
    int h = blockIdx.x, t = threadIdx.x;     // t = row = 2n+ri
    int n = t >> 1, ri = t & 1;
    float dt = expf(log_dt[h]);
    float e = expf(-0.5f*dt);
    float s_, c_; sincosf(PI_F*dt*n, &s_, &c_);
    float wr = e*c_, wi = e*s_;
    float cr2 = 1.f, ci2 = 0.f;              // w^0 -> col 127
    for (int kb = 3; kb >= 0; kb--) {
        unsigned short buf[32];
        for (int kk = 31; kk >= 0; kk--) {
            buf[kk] = f2bf(ri ? ci2 : cr2);
            float nr = cr2*wr - ci2*wi;
            float ni = cr2*wi + ci2*wr;
            cr2 = nr; ci2 = ni;
        }
        uint4* dst = (uint4*)&VA[(((size_t)h*4 + kb)*64 + t)*32];
        uint4* src = (uint4*)buf;
        dst[0]=src[0]; dst[1]=src[1]; dst[2]=src[2]; dst[3]=src[3];
    }
    if (ri == 0) {
        float e128 = expf(-64.f*dt);
        float s2, c2v; sincosf(PI_F*dt*n*128.f, &s2, &c2v);
        float pr = 1.f - e128*c2v, pim = -e128*s2;
        float dr = 1.f - wr, di = -wi;
        float dd = 1.f/(dr*dr + di*di);
        Vrs[(size_t)h*64 + 2*n]   = (pr*dr + pim*di)*dd;
        Vrs[(size_t)h*64 + 2*n+1] = (pim*dr - pr*di)*dd;
    }
}

// ---------------- S4 pass A (GEMM): chunk end-states E = V @ u ----------------
template<int NCH, int LOGNCH>
__global__ __launch_bounds__(64) void s4_gemm_a(
    const unsigned short* __restrict__ u, const unsigned short* __restrict__ VA,
    const float* __restrict__ Vrs, const float* __restrict__ sc,
    const float* __restrict__ sh, float* __restrict__ Bc)
{
    const int L = NCH * 128;
    int h = blockIdx.y;
    int lane = threadIdx.x;
    int nl = lane & 15, g = lane >> 4;
    int col = blockIdx.x * 16 + nl;
    int b = col >> LOGNCH, c = col & (NCH - 1);
    const unsigned short* up = u + ((size_t)h*16 + b)*L + c*128;
    f32x4 acc[4];
#pragma unroll
    for (int mt = 0; mt < 4; mt++) acc[mt] = (f32x4){0.f,0.f,0.f,0.f};
#pragma unroll
    for (int kb = 0; kb < 4; kb++) {
        short8 bf = *(const short8*)(up + kb*32 + g*8);
#pragma unroll
        for (int mt = 0; mt < 4; mt++) {
            short8 af = *(const short8*)(VA + (((size_t)h*4 + kb)*64 + mt*16 + nl)*32 + g*8);
            acc[mt] = __builtin_amdgcn_mfma_f32_16x16x32_bf16(af, bf, acc[mt], 0, 0, 0);
        }
    }
    float scv = sc ? sc[h] : 1.f;
    float shv = sh ? sh[h] : 0.f;
    float* bp = Bc + (((size_t)h*16 + b)*NCH + c)*64;
#pragma unroll
    for (int mt = 0; mt < 4; mt++) {
        int j0 = mt*16 + g*4;
        float4 vr = *(const float4*)(Vrs + (size_t)h*64 + j0);
        float4 o;
        o.x = fmaf(scv, acc[mt][0], shv*vr.x);
        o.y = fmaf(scv, acc[mt][1], shv*vr.y);
        o.z = fmaf(scv, acc[mt][2], shv*vr.z);
        o.w = fmaf(scv, acc[mt][3], shv*vr.w);
        *(float4*)(bp + j0) = o;
    }
}

// ---------------- S4 mid: chunk-level scan (w^128 via 7 squarings) ----------------
__global__ __launch_bounds__(64) void s4_mid(
    const float* __restrict__ log_dt, const float* __restrict__ Bc,
    float* __restrict__ Sinit, float* __restrict__ Sfinal,
    int H, int NCH)
{
    int gid = blockIdx.x * 64 + threadIdx.x;   // H*16*32
    int n = gid & 31;
    int tmp = gid >> 5;
    int b = tmp & 15;
    int h = tmp >> 4;
    float dt = expf(log_dt[h]);
    float e = expf(-0.5f * dt);
    float s_, c_; sincosf(PI_F * dt * n, &s_, &c_);
    float wr = e * c_, wi = e * s_;
#pragma unroll
    for (int i = 0; i < 7; i++) { float r = wr*wr - wi*wi; float im = 2.f*wr*wi; wr = r; wi = im; }
    float Sr = 0.f, Si = 0.f;
    size_t base = (((size_t)h*16 + b)*NCH)*64 + 2*n;
    for (int c = 0; c < NCH; c++) {
        float2 v; v.x = Sr; v.y = Si;
        *(float2*)(Sinit + base + (size_t)c*64) = v;
        float2 bc = *(const float2*)(Bc + base + (size_t)c*64);
        float r  = fmaf(wr, Sr, fmaf(-wi, Si, bc.x));
        float im = fmaf(wi, Sr, fmaf( wr, Si, bc.y));
        Sr = r; Si = im;
    }
    if (Sfinal) {
        float2 v; v.x = Sr; v.y = Si;
        *(float2*)(Sfinal + ((size_t)h*16 + b)*64 + 2*n) = v;
    }
}

// ---------------- S4 pass C (GEMM): y = sc*(T'@u) + sh*rs + W@Sinit ----------------
template<int NCH, int LOGNCH>
__global__ __launch_bounds__(256) void s4_gemm_c(
    const unsigned short* __restrict__ u, const float* __restrict__ Sini,
    const unsigned short* __restrict__ TA, const float* __restrict__ rs,
    const float* __restrict__ sc, const float* __restrict__ sh,
    unsigned short* __restrict__ yout)
{
    const int L = NCH * 128;
    __shared__ unsigned short s_u[64*200];   // 25600 B
    __shared__ unsigned short s_s[64*72];    // 9216 B
    int h = blockIdx.y;
    int tid = threadIdx.x;
    int lane = tid & 63, wid = tid >> 6;
    int nl = lane & 15, g = lane >> 4;
    int col0 = blockIdx.x * 64;
    for (int i = tid; i < 1024; i += 256) {
        int cl = i >> 4, o = i & 15;
        int col = col0 + cl; int b = col >> LOGNCH, c = col & (NCH - 1);
        *(uint4*)&s_u[cl*200 + o*8] =
            *(const uint4*)&u[((size_t)h*16 + b)*L + c*128 + o*8];
    }
    for (int i = tid; i < 1024; i += 256) {
        int cl = i >> 4, o = i & 15;
        int col = col0 + cl; int b = col >> LOGNCH, c = col & (NCH - 1);
        float4 v = *(const float4*)&Sini[(((size_t)h*16 + b)*NCH + c)*64 + o*4];
        ushort4 q; q.x = f2bf(v.x); q.y = f2bf(v.y); q.z = f2bf(v.z); q.w = f2bf(v.w);
        *(ushort4*)&s_s[cl*72 + o*4] = q;
    }
    __syncthreads();
    f32x4 accT[2][4], accW[2][4];
#pragma unroll
    for (int a = 0; a < 2; a++)
#pragma unroll
        for (int j = 0; j < 4; j++) { accT[a][j] = (f32x4){0,0,0,0}; accW[a][j] = (f32x4){0,0,0,0}; }
#pragma unroll
    for (int kb = 0; kb < 4; kb++) {
        short8 bfr[4];
#pragma unroll
        for (int j = 0; j < 4; j++)
            bfr[j] = *(const short8*)&s_u[(j*16 + nl)*200 + kb*32 + g*8];
#pragma unroll
        for (int mt2 = 0; mt2 < 2; mt2++) {
            int mtile = wid*2 + mt2;
            short8 af = *(const short8*)&TA[(((size_t)h*6 + kb)*128 + mtile*16 + nl)*32 + g*8];
#pragma unroll
            for (int j = 0; j < 4; j++)
                accT[mt2][j] = __builtin_amdgcn_mfma_f32_16x16x32_bf16(af, bfr[j], accT[mt2][j], 0, 0, 0);
        }
    }
#pragma unroll
    for (int kw = 0; kw < 2; kw++) {
        short8 bfr[4];
#pragma unroll
        for (int j = 0; j < 4; j++)
            bfr[j] = *(const short8*)&s_s[(j*16 + nl)*72 + kw*32 + g*8];
#pragma unroll
        for (int mt2 = 0; mt2 < 2; mt2++) {
            int mtile = wid*2 + mt2;
            short8 af = *(const short8*)&TA[(((size_t)h*6 + 4 + kw)*128 + mtile*16 + nl)*32 + g*8];
#pragma unroll
            for (int j = 0; j < 4; j++)
                accW[mt2][j] = __builtin_amdgcn_mfma_f32_16x16x32_bf16(af, bfr[j], accW[mt2][j], 0, 0, 0);
        }
    }
    float scv = sc ? sc[h] : 1.f;
    float shv = sh ? sh[h] : 0.f;
#pragma unroll
    for (int mt2 = 0; mt2 < 2; mt2++) {
        int m0 = (wid*2 + mt2)*16 + g*4;
        float4 rsv = *(const float4*)&rs[(size_t)h*128 + m0];
#pragma unroll
        for (int j = 0; j < 4; j++) {
            int col = col0 + j*16 + nl; int b = col >> LOGNCH, c = col & (NCH - 1);
            ushort4 q;
            q.x = f2bf(fmaf(scv, accT[mt2][j][0], shv*rsv.x) + accW[mt2][j][0]);
            q.y = f2bf(fmaf(scv, accT[mt2][j][1], shv*rsv.y) + accW[mt2][j][1]);
            q.z = f2bf(fmaf(scv, accT[mt2][j][2], shv*rsv.z) + accW[mt2][j][2]);
            q.w = f2bf(fmaf(scv, accT[mt2][j][3], shv*rsv.w) + accW[mt2][j][3]);
            *(ushort4*)&yout[((size_t)h*16 + b)*L + c*128 + m0] = q;
        }
    }
}

// ---------------- fused 4-dilation conv block via MFMA (v8) ----------------
// computes all 4 dilated convs (dil = 1,2,4,8) from one LDS staging.
// u [CIN][16][Lin] bf16 -> out [4*CIN][16][Lout] bf16
// v8 vs v7: WAVE <-> DILATION remap. v7 had each wave compute M=16 out-ch x 4
// dilations; the B-fragment differs per dilation (r,s shift) -> 1:1
// ds_read_b128 : MFMA (96/chunk/wave, ~15us of LDS pipe). Now each wave owns ONE
// dilation (d = wid, wave-uniform incl. the lrelu branch) and all 64 out-ch
// (4 M-tiles): bfrag depends only on (k,chalf,f) -> loaded once, reused across
// 4 MFMAs. ds_read_b128 per chunk per wave: 96 -> 24 (4x). afrag loads stay 24,
// each reused F times. MFMA count/output mapping exact as before.
// Staging/barriers/swizzle identical to v7 (FETCH 20.5MB verified good).
template<int CIN, int TBLK>
__global__ __launch_bounds__(256, 2) void conv_mfma4(
    const unsigned short* __restrict__ u, const unsigned short* __restrict__ wp,
    const float* __restrict__ bs0, const float* __restrict__ bs1,
    const float* __restrict__ bs2, const float* __restrict__ bs3,
    unsigned short* __restrict__ out, int Lin, int Lout)
{
    constexpr int F     = TBLK / 16;          // output t-tiles per wave (4 or 2)
    constexpr int NPOS  = TBLK * 4 + 16;      // staged input positions (272 or 144)
    constexpr int Q     = NPOS / 4;           // q rows per residue plane (68 or 36)
    constexpr int NITEM = (NPOS / 8) * 64;    // uint4 load items (2176 or 1152)
    constexpr int NLD   = (NITEM + 255) / 256;// loads per thread (9 or 5)
    constexpr int NCC   = CIN / 64;           // cc0 chunks (4 or 1)
    constexpr int NBUF  = (NCC > 1) ? 2 : 1;  // LDS double-buffer only if chunked
    constexpr int BUFSZ = 4 * Q * 64;         // shorts per buffer
    __shared__ unsigned short s_in[NBUF * BUFSZ];   // 69632 B / 18432 B

    int tid = threadIdx.x;
    int lane = tid & 63, wid = tid >> 6;      // wid == dilation index d
    int nl = lane & 15, g = lane >> 4;
    int t0 = blockIdx.x * TBLK;
    int b  = blockIdx.y;
    int og = blockIdx.z * 64;
    const int P0 = t0 * 4 - 8;
    const int DIL = 1 << wid;                 // wave-uniform

    f32x4 acc[4][F];
#pragma unroll
    for (int m = 0; m < 4; m++)
#pragma unroll
        for (int f = 0; f < F; f++) acc[m][f] = (f32x4){0.f,0.f,0.f,0.f};

    uint4 stg[NLD];

    // issue global loads only (no wait) -- ccbase is the CHANNEL BASE (chunk*64)
    auto stage_load = [&](int ccbase) {
#pragma unroll
        for (int j = 0; j < NLD; j++) {
            int i = tid + 256 * j;
            uint4 v; v.x = 0u; v.y = 0u; v.z = 0u; v.w = 0u;
            if (i < NITEM) {
                int ch = i & 63, po = i >> 6;
                int p = P0 + po * 8;
                const unsigned short* gp = u + ((size_t)(ccbase + ch)*16 + b)*Lin;
                if (p >= 0 && p + 8 <= Lin) {
                    v = *(const uint4*)(gp + p);
                } else {
                    alignas(16) unsigned short t8[8];
#pragma unroll
                    for (int j2 = 0; j2 < 8; j2++) {
                        int pj = p + j2;
                        t8[j2] = ((unsigned)pj < (unsigned)Lin) ? gp[pj] : (unsigned short)0;
                    }
                    v = *(const uint4*)t8;
                }
            }
            stg[j] = v;
        }
    };
    // consume stg -> LDS (the vmcnt wait lands here)
    auto stage_write = [&](int bufidx) {
        unsigned short* sb = s_in + bufidx * BUFSZ;
#pragma unroll
        for (int j = 0; j < NLD; j++) {
            int i = tid + 256 * j;
            if (i < NITEM) {
                int ch = i & 63, po = i >> 6;
                alignas(16) unsigned short t8[8];
                *(uint4*)t8 = stg[j];
#pragma unroll
                for (int jj = 0; jj < 8; jj++) {
                    int pl = po * 8 + jj;
                    int row = (pl & 3) * Q + (pl >> 2);
                    sb[row * 64 + (ch ^ ((row & 7) << 3))] = t8[jj];
                }
            }
        }
    };

    stage_load(0);
    stage_write(0);
    __syncthreads();

#pragma unroll
    for (int cc = 0; cc < NCC; cc++) {
        if (cc + 1 < NCC) stage_load((cc + 1) * 64);   // issue early
        const unsigned short* sb = s_in + (NBUF > 1 ? (cc & 1) * BUFSZ : 0);
#pragma unroll
        for (int k = 0; k < 3; ++k) {
            const int off = (k - 1) * DIL + 8;     // 0..16, wave-uniform
            const int r = off & 3, s = off >> 2;
#pragma unroll
            for (int chalf = 0; chalf < 2; ++chalf) {
                int kb = cc * 6 + k * 2 + chalf;
                short8 bfr[F];
#pragma unroll
                for (int f = 0; f < F; ++f) {
                    int q = f*16 + nl + s;
                    int row = r * Q + q;
                    bfr[f] = *(const short8*)&sb[row * 64 +
                        ((((chalf << 2) | g) ^ (row & 7)) << 3)];
                }
#pragma unroll
                for (int m = 0; m < 4; ++m) {
                    short8 afrag = *(const short8*)&wp[(size_t)wid*(3*CIN*CIN) +
                        ((size_t)kb*CIN + og + m*16 + nl)*32 + g*8];
#pragma unroll
                    for (int f = 0; f < F; ++f)
                        acc[m][f] = __builtin_amdgcn_mfma_f32_16x16x32_bf16(afrag, bfr[f], acc[m][f], 0, 0, 0);
                }
            }
        }
        if (cc + 1 < NCC) {
            __syncthreads();                 // all waves done reading buf[(cc+1)&1]
            stage_write((cc + 1) & 1);       // vmcnt wait here (post-MFMA)
            __syncthreads();                 // writes visible before next MFMA phase
        }
    }

    const float* bp = (wid == 0) ? bs0 : (wid == 1) ? bs1 : (wid == 2) ? bs2 : bs3;
#pragma unroll
    for (int m = 0; m < 4; ++m) {
#pragma unroll
        for (int f = 0; f < F; ++f) {
            int t = t0 + f*16 + nl;
#pragma unroll
            for (int r2 = 0; r2 < 4; ++r2) {
                int o = og + m*16 + g*4 + r2;
                float v = acc[m][f][r2] + bp[o];
                if (wid) v = v >= 0.f ? v : 0.3f*v;   // wave-uniform branch
                out[((size_t)(wid*CIN + o)*16 + b)*Lout + t] = f2bf(v);
            }
        }
    }
}

// ---------------- BN stats from bf16 [ch][b][t] ----------------
__global__ __launch_bounds__(256) void bn_stats(
    const unsigned short* __restrict__ x, const float* __restrict__ g,
    const float* __restrict__ bb, float* __restrict__ sc, float* __restrict__ sh,
    int n, int gmask)
{
    int ch = blockIdx.x;
    const unsigned short* xp = x + (size_t)ch * n;
    float s1 = 0.f, s2 = 0.f;
    for (int i = threadIdx.x*8; i < n; i += 2048) {
        uint4 raw = *(const uint4*)(xp + i);
        unsigned short us[8]; *(uint4*)us = raw;
#pragma unroll
        for (int j = 0; j < 8; j++) {
            float v = bf2f(us[j]);
            s1 += v; s2 += v*v;
        }
    }
    for (int o = 32; o > 0; o >>= 1) { s1 += __shfl_down(s1, o); s2 += __shfl_down(s2, o); }
    __shared__ float p1[4], p2[4];
    int wid = threadIdx.x >> 6;
    if ((threadIdx.x & 63) == 0) { p1[wid] = s1; p2[wid] = s2; }
    __syncthreads();
    if (threadIdx.x == 0) {
        s1 = p1[0] + p1[1] + p1[2] + p1[3];
        s2 = p2[0] + p2[1] + p2[2] + p2[3];
        float m = s1 / n;
        float var = s2 / n - m*m;
        float rstd = rsqrtf(var + 1e-5f);
        float scale = g[ch & gmask] * rstd;
        sc[ch] = scale;
        sh[ch] = fmaf(-m, scale, bb[ch & gmask]);
    }
}

// ---------------- s4c final-state -> x3[:, :, 511] ----------------
__global__ __launch_bounds__(256) void s4c_last(
    const float* __restrict__ Sfinal, const unsigned short* __restrict__ u3,
    const float* __restrict__ sc, const float* __restrict__ sh,
    const float* __restrict__ log_dt, const float* __restrict__ C2,
    const float* __restrict__ Dv, float* __restrict__ x3last)
{
    int gid = blockIdx.x*256 + threadIdx.x;  // 16*1024
    int h = gid & 1023;
    int b = gid >> 10;
    float dt = expf(log_dt[h]);
    float e = expf(-0.5f * dt);
    const float* sp = Sfinal + ((size_t)h*16 + b)*64;
    float aR = 0.f, aI = 0.f;
#pragma unroll
    for (int n = 0; n < 32; n++) {
        float s_, c_; sincosf(PI_F * dt * n, &s_, &c_);
        float wr = e*c_, wi = e*s_;
        float ar = -0.5f, ai = PI_F * n;
        float den = 1.f / (ar*ar + ai*ai);
        float tr = wr - 1.f, ti = wi;
        float qr = (tr*ar + ti*ai) * den;
        float qi = (ti*ar - tr*ai) * den;
        float c2r = C2[((size_t)h*32 + n)*2], c2i = C2[((size_t)h*32 + n)*2 + 1];
        float crv = c2r*qr - c2i*qi, civ = c2r*qi + c2i*qr;
        aR = fmaf(crv, sp[2*n],   aR);
        aI = fmaf(civ, sp[2*n+1], aI);
    }
    float uv = fmaf(sc[h], bf2f(u3[((size_t)h*16 + b)*512 + 511]), sh[h]);
    x3last[b*1024 + h] = 2.f*(aR - aI) + Dv[h]*uv;
}

// ---------------- decoder head ----------------
__global__ __launch_bounds__(256) void dec_kernel(
    const float* __restrict__ x3last, const float* __restrict__ w1, const float* __restrict__ b1,
    const float* __restrict__ w2, const float* __restrict__ b2, float* __restrict__ out)
{
    __shared__ float xs[1024];
    int b = blockIdx.x, tid = threadIdx.x;
    for (int i = tid; i < 1024; i += 256) xs[i] = x3last[b*1024 + i];
    __syncthreads();
    float z = b1[tid];
    const float* wpt = w1 + (size_t)tid*1024;
    for (int i = 0; i < 1024; i += 4) {
        float4 wv = *(const float4*)(wpt + i);
        z = fmaf(wv.x, xs[i],   z);
        z = fmaf(wv.y, xs[i+1], z);
        z = fmaf(wv.z, xs[i+2], z);
        z = fmaf(wv.w, xs[i+3], z);
    }
    float v = w2[tid] * z;
    for (int o = 32; o > 0; o >>= 1) v += __shfl_down(v, o);
    __shared__ float ps[4];
    if ((tid & 63) == 0) ps[tid >> 6] = v;
    __syncthreads();
    if (tid == 0) out[b] = ps[0] + ps[1] + ps[2] + ps[3] + b2[0];
}

extern "C" void kernel_launch(void* const* d_in, const int* in_sizes, int n_in,
                              void* d_out, int out_size, void* d_ws, size_t ws_size,
                              hipStream_t stream)
{
    const float* x       = (const float*)d_in[0];
    const float* enc_w   = (const float*)d_in[1];
    const float* enc_b   = (const float*)d_in[2];
    const float* s4a_ldt = (const float*)d_in[3];
    const float* s4a_C   = (const float*)d_in[4];
    const float* s4a_D   = (const float*)d_in[5];
    const float* s4b_ldt = (const float*)d_in[6];
    const float* s4b_C   = (const float*)d_in[7];
    const float* s4b_D   = (const float*)d_in[8];
    const float* s4c_ldt = (const float*)d_in[9];
    const float* s4c_C   = (const float*)d_in[10];
    const float* s4c_D   = (const float*)d_in[11];
    const float* b1w[4] = {(const float*)d_in[12], (const float*)d_in[14], (const float*)d_in[16], (const float*)d_in[18]};
    const float* b1b[4] = {(const float*)d_in[13], (const float*)d_in[15], (const float*)d_in[17], (const float*)d_in[19]};
    const float* b2w[4] = {(const float*)d_in[20], (const float*)d_in[22], (const float*)d_in[24], (const float*)d_in[26]};
    const float* b2b[4] = {(const float*)d_in[21], (const float*)d_in[23], (const float*)d_in[25], (const float*)d_in[27]};
    const float* bn1_g  = (const float*)d_in[28];
    const float* bn1_b  = (const float*)d_in[29];
    const float* bn2_g  = (const float*)d_in[30];
    const float* bn2_b  = (const float*)d_in[31];
    const float* dec1_w = (const float*)d_in[32];
    const float* dec1_b = (const float*)d_in[33];
    const float* dec2_w = (const float*)d_in[34];
    const float* dec2_b = (const float*)d_in[35];
    float* out = (float*)d_out;

    char* ws = (char*)d_ws;
    unsigned short* u1    = (unsigned short*)(ws);              // 16.8 MB (also u3)
    unsigned short* u3    = u1;
    unsigned short* ya    = (unsigned short*)(ws + 16777216);   // 16.8 MB (also yb, later VA_c)
    unsigned short* yb    = ya;
    unsigned short* VA_c  = ya;                                 // reuse after conv2
    unsigned short* u2    = (unsigned short*)(ws + 33554432);   // 16.8 MB
    float*          Bc    = (float*)(ws + 50331648);            // 16.8 MB
    float*          Sini  = (float*)(ws + 67108864);            // 16.8 MB
    float*          Sfin  = (float*)(ws + 83886080);            // 4.2 MB
    unsigned short* wprep = (unsigned short*)(ws + 88080384);   // 1.67 MB
    unsigned short* TA_a  = (unsigned short*)(ws + 89751552);   // 3.15 MB
    unsigned short* TA_b  = (unsigned short*)(ws + 92897280);   // 12.6 MB
    unsigned short* VA_a  = (unsigned short*)(ws + 105480192);  // 1.05 MB
    unsigned short* VA_b  = (unsigned short*)(ws + 106528768);  // 4.2 MB
    float*          rs_a  = (float*)(ws + 110723072);           // 32 KB
    float*          rs_b  = (float*)(ws + 110755840);           // 128 KB
    float*          Vrs_a = (float*)(ws + 110886912);           // 16 KB
    float*          Vrs_b = (float*)(ws + 110903296);           // 64 KB
    float*          smallp= (float*)(ws + 110968832);
    float* sc1 = smallp;         // 256
    float* sh1 = smallp + 256;   // 256
    float* sc2 = smallp + 512;   // 1024
    float* sh2 = smallp + 1536;  // 1024
    float* x3l = smallp + 2560;  // 16384
    float*          Vrs_c = (float*)(ws + 111280128);           // 256 KB

    // prep (independent of data path)
    prep_w<<<dim3(768, 8), 256, 0, stream>>>(b1w[0], b1w[1], b1w[2], b1w[3],
                                             b2w[0], b2w[1], b2w[2], b2w[3], wprep);
    prep_s4<<<64, 128, 0, stream>>>(s4a_ldt, s4a_C, s4a_D, TA_a, VA_a, rs_a, Vrs_a);
    prep_s4<<<256, 128, 0, stream>>>(s4b_ldt, s4b_C, s4b_D, TA_b, VA_b, rs_b, Vrs_b);

    // encoder -> u1 bf16
    enc_kernel<<<8192, 256, 0, stream>>>(x, enc_w, enc_b, u1);

    // s4a: H=64, NCH=64 (L=8192)
    s4_gemm_a<64,6><<<dim3(64, 64), 64, 0, stream>>>(u1, VA_a, Vrs_a, nullptr, nullptr, Bc);
    s4_mid<<<512, 64, 0, stream>>>(s4a_ldt, Bc, Sini, nullptr, 64, 64);
    s4_gemm_c<64,6><<<dim3(16, 64), 256, 0, stream>>>(u1, Sini, TA_a, rs_a, nullptr, nullptr, ya);

    // conv block1 (fused 4 dilations): ya [64][16][8192] -> u2 [256][16][2048]
    // TBLK=32, single LDS buffer 18.4 KB, wave<->dilation remap
    conv_mfma4<64,32><<<dim3(64, 16, 1), 256, 0, stream>>>(
        ya, wprep, b1b[0], b1b[1], b1b[2], b1b[3], u2, 8192, 2048);
    bn_stats<<<256, 256, 0, stream>>>(u2, bn1_g, bn1_b, sc1, sh1, 16*2048, 63);

    // s4b: H=256, NCH=16 (L=2048)
    s4_gemm_a<16,4><<<dim3(16, 256), 64, 0, stream>>>(u2, VA_b, Vrs_b, sc1, sh1, Bc);
    s4_mid<<<2048, 64, 0, stream>>>(s4b_ldt, Bc, Sini, nullptr, 256, 16);
    s4_gemm_c<16,4><<<dim3(4, 256), 256, 0, stream>>>(u2, Sini, TA_b, rs_b, sc1, sh1, yb);

    // conv block2 (fused 4 dilations): yb [256][16][2048] -> u3 [1024][16][512]
    // TBLK=64, LDS dbuf 69.6 KB, wave<->dilation remap (4x fewer ds_reads)
    conv_mfma4<256,64><<<dim3(8, 16, 4), 256, 0, stream>>>(
        yb, wprep + 49152, b2b[0], b2b[1], b2b[2], b2b[3], u3, 2048, 512);
    bn_stats<<<1024, 256, 0, stream>>>(u3, bn2_g, bn2_b, sc2, sh2, 16*512, 255);

    // s4c: H=1024, NCH=4 (L=512); only final state needed.
    // yb is dead now -> reuse its 16.8 MB slot for VA_c (exact fit).
    prep_va<<<1024, 64, 0, stream>>>(s4c_ldt, VA_c, Vrs_c);
    s4_gemm_a<4,2><<<dim3(4, 1024), 64, 0, stream>>>(u3, VA_c, Vrs_c, sc2, sh2, Bc);
    s4_mid<<<8192, 64, 0, stream>>>(s4c_ldt, Bc, Sini, Sfin, 1024, 4);
    s4c_last<<<64, 256, 0, stream>>>(Sfin, u3, sc2, sh2, s4c_ldt, s4c_C, s4c_D, x3l);

    // decoder head
    dec_kernel<<<16, 256, 0, stream>>>(x3l, dec1_w, dec1_b, dec2_w, dec2_b, out);
}

// Round 10
// 374.734 us; speedup vs baseline: 1.2025x; 1.0775x over previous
//
#include <hip/hip_runtime.h>
#include <math.h>

#define PI_F 3.14159265358979323846f

typedef __attribute__((ext_vector_type(8))) short short8;
typedef __attribute__((ext_vector_type(4))) float f32x4;

__device__ __forceinline__ unsigned short f2bf(float f) {
    unsigned int u = __float_as_uint(f);
    unsigned int r = (u + 0x7fffu + ((u >> 16) & 1u)) >> 16;
    return (unsigned short)r;
}
__device__ __forceinline__ float bf2f(unsigned short v) {
    return __uint_as_float((unsigned int)v << 16);
}

// ---------------- encoder: x[16][8192][2] -> u1 bf16 [64][16][8192] ----------------
__global__ __launch_bounds__(256) void enc_kernel(
    const float* __restrict__ x, const float* __restrict__ ew,
    const float* __restrict__ eb, unsigned short* __restrict__ u1)
{
    int idx = blockIdx.x * 256 + threadIdx.x;   // 64*16*2048 threads, 4 t each
    int t4 = idx & 2047;
    int b  = (idx >> 11) & 15;
    int h  = idx >> 15;
    float w0 = ew[2*h], w1 = ew[2*h+1], bb = eb[h];
    const float* xp = x + ((size_t)b*8192 + (size_t)t4*4)*2;
    float4 a = *(const float4*)xp;
    float4 c = *(const float4*)(xp + 4);
    ushort4 o;
    o.x = f2bf(fmaf(w0, a.x, fmaf(w1, a.y, bb)));
    o.y = f2bf(fmaf(w0, a.z, fmaf(w1, a.w, bb)));
    o.z = f2bf(fmaf(w0, c.x, fmaf(w1, c.y, bb)));
    o.w = f2bf(fmaf(w0, c.z, fmaf(w1, c.w, bb)));
    *(ushort4*)(u1 + ((size_t)h*16 + b)*8192 + (size_t)t4*4) = o;
}

// ---------------- conv weight prep: fp32 [O][Cin][3] -> bf16 A-frag [kb][o][kk] ------
__global__ __launch_bounds__(256) void prep_w(
    const float* __restrict__ w0, const float* __restrict__ w1,
    const float* __restrict__ w2, const float* __restrict__ w3,
    const float* __restrict__ w4, const float* __restrict__ w5,
    const float* __restrict__ w6, const float* __restrict__ w7,
    unsigned short* __restrict__ wprep)
{
    int id = blockIdx.y;
    const float* src; int Cin; size_t doff;
    switch (id) {
        case 0: src = w0; Cin = 64;  doff = 0;      break;
        case 1: src = w1; Cin = 64;  doff = 12288;  break;
        case 2: src = w2; Cin = 64;  doff = 24576;  break;
        case 3: src = w3; Cin = 64;  doff = 36864;  break;
        case 4: src = w4; Cin = 256; doff = 49152;  break;
        case 5: src = w5; Cin = 256; doff = 245760; break;
        case 6: src = w6; Cin = 256; doff = 442368; break;
        default: src = w7; Cin = 256; doff = 638976; break;
    }
    int e = blockIdx.x * 256 + threadIdx.x;
    if (e >= Cin * Cin * 3) return;
    int kb  = e / (Cin * 32);
    int rem = e - kb * (Cin * 32);
    int o   = rem >> 5;
    int kk  = rem & 31;
    int cch = kb / 6, t6 = kb % 6, k = t6 >> 1, chalf = t6 & 1;
    int c = cch * 64 + chalf * 32 + kk;
    wprep[doff + e] = f2bf(src[((size_t)o * Cin + c) * 3 + k]);
}

// ---------------- S4 prep: build per-h MFMA A-matrices (coalesced writes) ----------
// TA[h][kb(6)][m(128)][kk(32)]: kb 0..3 Toeplitz K'[m-col], kb 4..5 W[m][j]
// VA[h][kb(4)][row(64)][kk(32)]: V[2n+ri][s] = w^(127-s) Re/Im
// rs[h][128]: prefix sums of K'; Vrs[h][64]: rowsum of V
__global__ __launch_bounds__(128) void prep_s4(
    const float* __restrict__ log_dt, const float* __restrict__ C2,
    const float* __restrict__ Dv,
    unsigned short* __restrict__ TA, unsigned short* __restrict__ VA,
    float* __restrict__ rs, float* __restrict__ Vrs)
{
    int h = blockIdx.x, t = threadIdx.x;
    __shared__ float cn[64];
    __shared__ float sK[128];
    __shared__ unsigned short s_w[128 * 66];   // W staged [m][j], pad 66
    float dt = expf(log_dt[h]);
    if (t < 32) {
        int n = t;
        float e = expf(-0.5f*dt);
        float s_, c_; sincosf(PI_F*dt*n, &s_, &c_);
        float wr = e*c_, wi = e*s_;
        float ar = -0.5f, ai = PI_F*n;
        float den = 1.f/(ar*ar + ai*ai);
        float tr = wr - 1.f, ti = wi;
        float qr = (tr*ar + ti*ai)*den;
        float qi = (ti*ar - tr*ai)*den;
        float c2r = C2[((size_t)h*32+n)*2], c2i = C2[((size_t)h*32+n)*2+1];
        cn[2*n]   = 2.f*(c2r*qr - c2i*qi);
        cn[2*n+1] = 2.f*(c2r*qi + c2i*qr);
        // Vrs = sum_{j=0}^{127} w^j = (1 - w^128)/(1 - w)
        float e128 = expf(-64.f*dt);
        float s2, c2v; sincosf(PI_F*dt*n*128.f, &s2, &c2v);
        float pr = 1.f - e128*c2v, pim = -e128*s2;
        float dr = 1.f - wr, di = -wi;
        float dd = 1.f/(dr*dr + di*di);
        Vrs[(size_t)h*64 + 2*n]   = (pr*dr + pim*di)*dd;
        Vrs[(size_t)h*64 + 2*n+1] = (pim*dr - pr*di)*dd;
    }
    __syncthreads();
    // phase 1: K[t] (each thread one tap)
    {
        float em = expf(-0.5f*dt*t);
        float Kt = 0.f;
        for (int n = 0; n < 32; n++) {
            float s_, c_; sincosf(PI_F*dt*(float)(n*t), &s_, &c_);
            Kt += cn[2*n]*em*c_ - cn[2*n+1]*em*s_;
        }
        sK[t] = Kt + (t == 0 ? Dv[h] : 0.f);
    }
    // phase 2: wave0 (t<64) builds W columns into LDS; wave1 builds V rows direct
    if (t < 64) {
        int n = t >> 1, ri = t & 1;
        float e = expf(-0.5f*dt);
        float s_, c_; sincosf(PI_F*dt*n, &s_, &c_);
        float wr = e*c_, wi = e*s_;
        float crn = cn[2*n], cin = cn[2*n+1];
        float pr = wr, pim = wi;                    // w^(m+1), m=0
        for (int m = 0; m < 128; m++) {
            float re = crn*pr - cin*pim;
            float im = crn*pim + cin*pr;
            s_w[m*66 + t] = f2bf(ri ? -im : re);
            float nr = pr*wr - pim*wi;
            float ni = pr*wi + pim*wr;
            pr = nr; pim = ni;
        }
    } else {
        int r = t - 64; int n = r >> 1, ri = r & 1;
        float e = expf(-0.5f*dt);
        float s_, c_; sincosf(PI_F*dt*n, &s_, &c_);
        float wr = e*c_, wi = e*s_;
        float cr2 = 1.f, ci2 = 0.f;                 // w^0
        for (int kb = 3; kb >= 0; kb--) {
            unsigned short buf[32];
            for (int kk = 31; kk >= 0; kk--) {
                buf[kk] = f2bf(ri ? ci2 : cr2);
                float nr = cr2*wr - ci2*wi;
                float ni = cr2*wi + ci2*wr;
                cr2 = nr; ci2 = ni;
            }
            uint4* dst = (uint4*)&VA[(((size_t)h*4 + kb)*64 + r)*32];
            uint4* src = (uint4*)buf;
            dst[0]=src[0]; dst[1]=src[1]; dst[2]=src[2]; dst[3]=src[3];
        }
    }
    __syncthreads();
    // prefix sum for BN shift
    {
        float acc = 0.f;
        for (int tau = 0; tau <= t; tau++) acc += sK[tau];
        rs[(size_t)h*128 + t] = acc;
    }
    // Toeplitz row t, buffered uint4 stores
    for (int kb = 0; kb < 4; kb++) {
        unsigned short tb[32];
#pragma unroll
        for (int kk = 0; kk < 32; kk++) {
            int col = kb*32 + kk;
            tb[kk] = f2bf((col <= t) ? sK[t - col] : 0.f);
        }
        uint4* dst = (uint4*)&TA[(((size_t)h*6 + kb)*128 + t)*32];
        uint4* src = (uint4*)tb;
        dst[0]=src[0]; dst[1]=src[1]; dst[2]=src[2]; dst[3]=src[3];
    }
    // W copy-out, coalesced: 1024 uint4 over kb'(2) x m(128) x kkg(4)
    for (int i = t; i < 1024; i += 128) {
        int kb = i >> 9;             // 0..1
        int rem = i & 511;
        int m = rem >> 2, kkg = rem & 3;
        *(uint4*)&TA[(((size_t)h*6 + 4 + kb)*128 + m)*32 + kkg*8] =
            *(const uint4*)&s_w[m*66 + kb*32 + kkg*8];
    }
}

// ---------------- slim prep (s4c): V rows + rowsums, coalesced ----------------
__global__ __launch_bounds__(64) void prep_va(
    const float* __restrict__ log_dt,
    unsigned short* __restrict__ VA, float* __restrict__ Vrs)
{
    int h = blockIdx.x, t = threadIdx.x;     // t = row = 2n+ri
    int n = t >> 1, ri = t & 1;
    float dt = expf(log_dt[h]);
    float e = expf(-0.5f*dt);
    float s_, c_; sincosf(PI_F*dt*n, &s_, &c_);
    float wr = e*c_, wi = e*s_;
    float cr2 = 1.f, ci2 = 0.f;              // w^0 -> col 127
    for (int kb = 3; kb >= 0; kb--) {
        unsigned short buf[32];
        for (int kk = 31; kk >= 0; kk--) {
            buf[kk] = f2bf(ri ? ci2 : cr2);
            float nr = cr2*wr - ci2*wi;
            float ni = cr2*wi + ci2*wr;
            cr2 = nr; ci2 = ni;
        }
        uint4* dst = (uint4*)&VA[(((size_t)h*4 + kb)*64 + t)*32];
        uint4* src = (uint4*)buf;
        dst[0]=src[0]; dst[1]=src[1]; dst[2]=src[2]; dst[3]=src[3];
    }
    if (ri == 0) {
        float e128 = expf(-64.f*dt);
        float s2, c2v; sincosf(PI_F*dt*n*128.f, &s2, &c2v);
        float pr = 1.f - e128*c2v, pim = -e128*s2;
        float dr = 1.f - wr, di = -wi;
        float dd = 1.f/(dr*dr + di*di);
        Vrs[(size_t)h*64 + 2*n]   = (pr*dr + pim*di)*dd;
        Vrs[(size_t)h*64 + 2*n+1] = (pim*dr - pr*di)*dd;
    }
}

// ---------------- S4 pass A (GEMM): chunk end-states E = V @ u ----------------
template<int NCH, int LOGNCH>
__global__ __launch_bounds__(64) void s4_gemm_a(
    const unsigned short* __restrict__ u, const unsigned short* __restrict__ VA,
    const float* __restrict__ Vrs, const float* __restrict__ sc,
    const float* __restrict__ sh, float* __restrict__ Bc)
{
    const int L = NCH * 128;
    int h = blockIdx.y;
    int lane = threadIdx.x;
    int nl = lane & 15, g = lane >> 4;
    int col = blockIdx.x * 16 + nl;
    int b = col >> LOGNCH, c = col & (NCH - 1);
    const unsigned short* up = u + ((size_t)h*16 + b)*L + c*128;
    f32x4 acc[4];
#pragma unroll
    for (int mt = 0; mt < 4; mt++) acc[mt] = (f32x4){0.f,0.f,0.f,0.f};
#pragma unroll
    for (int kb = 0; kb < 4; kb++) {
        short8 bf = *(const short8*)(up + kb*32 + g*8);
#pragma unroll
        for (int mt = 0; mt < 4; mt++) {
            short8 af = *(const short8*)(VA + (((size_t)h*4 + kb)*64 + mt*16 + nl)*32 + g*8);
            acc[mt] = __builtin_amdgcn_mfma_f32_16x16x32_bf16(af, bf, acc[mt], 0, 0, 0);
        }
    }
    float scv = sc ? sc[h] : 1.f;
    float shv = sh ? sh[h] : 0.f;
    float* bp = Bc + (((size_t)h*16 + b)*NCH + c)*64;
#pragma unroll
    for (int mt = 0; mt < 4; mt++) {
        int j0 = mt*16 + g*4;
        float4 vr = *(const float4*)(Vrs + (size_t)h*64 + j0);
        float4 o;
        o.x = fmaf(scv, acc[mt][0], shv*vr.x);
        o.y = fmaf(scv, acc[mt][1], shv*vr.y);
        o.z = fmaf(scv, acc[mt][2], shv*vr.z);
        o.w = fmaf(scv, acc[mt][3], shv*vr.w);
        *(float4*)(bp + j0) = o;
    }
}

// ---------------- S4 mid: chunk-level scan (w^128 via 7 squarings) ----------------
// v9: Sinit written as bf16 (gemm_c converted it to bf16 anyway -> identical values,
// half the traffic).
__global__ __launch_bounds__(64) void s4_mid(
    const float* __restrict__ log_dt, const float* __restrict__ Bc,
    unsigned short* __restrict__ Sinit,
    int H, int NCH)
{
    int gid = blockIdx.x * 64 + threadIdx.x;   // H*16*32
    int n = gid & 31;
    int tmp = gid >> 5;
    int b = tmp & 15;
    int h = tmp >> 4;
    float dt = expf(log_dt[h]);
    float e = expf(-0.5f * dt);
    float s_, c_; sincosf(PI_F * dt * n, &s_, &c_);
    float wr = e * c_, wi = e * s_;
#pragma unroll
    for (int i = 0; i < 7; i++) { float r = wr*wr - wi*wi; float im = 2.f*wr*wi; wr = r; wi = im; }
    float Sr = 0.f, Si = 0.f;
    size_t base = (((size_t)h*16 + b)*NCH)*64 + 2*n;
    for (int c = 0; c < NCH; c++) {
        ushort2 v; v.x = f2bf(Sr); v.y = f2bf(Si);
        *(ushort2*)(Sinit + base + (size_t)c*64) = v;
        float2 bc = *(const float2*)(Bc + base + (size_t)c*64);
        float r  = fmaf(wr, Sr, fmaf(-wi, Si, bc.x));
        float im = fmaf(wi, Sr, fmaf( wr, Si, bc.y));
        Sr = r; Si = im;
    }
}

// ---------------- S4 pass C (GEMM): y = sc*(T'@u) + sh*rs + W@Sinit ----------------
template<int NCH, int LOGNCH>
__global__ __launch_bounds__(256) void s4_gemm_c(
    const unsigned short* __restrict__ u, const unsigned short* __restrict__ Sini,
    const unsigned short* __restrict__ TA, const float* __restrict__ rs,
    const float* __restrict__ sc, const float* __restrict__ sh,
    unsigned short* __restrict__ yout)
{
    const int L = NCH * 128;
    __shared__ unsigned short s_u[64*200];   // 25600 B
    __shared__ unsigned short s_s[64*72];    // 9216 B
    int h = blockIdx.y;
    int tid = threadIdx.x;
    int lane = tid & 63, wid = tid >> 6;
    int nl = lane & 15, g = lane >> 4;
    int col0 = blockIdx.x * 64;
    for (int i = tid; i < 1024; i += 256) {
        int cl = i >> 4, o = i & 15;
        int col = col0 + cl; int b = col >> LOGNCH, c = col & (NCH - 1);
        *(uint4*)&s_u[cl*200 + o*8] =
            *(const uint4*)&u[((size_t)h*16 + b)*L + c*128 + o*8];
    }
    for (int i = tid; i < 1024; i += 256) {
        int cl = i >> 4, o = i & 15;
        int col = col0 + cl; int b = col >> LOGNCH, c = col & (NCH - 1);
        *(ushort4*)&s_s[cl*72 + o*4] =
            *(const ushort4*)&Sini[(((size_t)h*16 + b)*NCH + c)*64 + o*4];
    }
    __syncthreads();
    f32x4 accT[2][4], accW[2][4];
#pragma unroll
    for (int a = 0; a < 2; a++)
#pragma unroll
        for (int j = 0; j < 4; j++) { accT[a][j] = (f32x4){0,0,0,0}; accW[a][j] = (f32x4){0,0,0,0}; }
#pragma unroll
    for (int kb = 0; kb < 4; kb++) {
        short8 bfr[4];
#pragma unroll
        for (int j = 0; j < 4; j++)
            bfr[j] = *(const short8*)&s_u[(j*16 + nl)*200 + kb*32 + g*8];
#pragma unroll
        for (int mt2 = 0; mt2 < 2; mt2++) {
            int mtile = wid*2 + mt2;
            short8 af = *(const short8*)&TA[(((size_t)h*6 + kb)*128 + mtile*16 + nl)*32 + g*8];
#pragma unroll
            for (int j = 0; j < 4; j++)
                accT[mt2][j] = __builtin_amdgcn_mfma_f32_16x16x32_bf16(af, bfr[j], accT[mt2][j], 0, 0, 0);
        }
    }
#pragma unroll
    for (int kw = 0; kw < 2; kw++) {
        short8 bfr[4];
#pragma unroll
        for (int j = 0; j < 4; j++)
            bfr[j] = *(const short8*)&s_s[(j*16 + nl)*72 + kw*32 + g*8];
#pragma unroll
        for (int mt2 = 0; mt2 < 2; mt2++) {
            int mtile = wid*2 + mt2;
            short8 af = *(const short8*)&TA[(((size_t)h*6 + 4 + kw)*128 + mtile*16 + nl)*32 + g*8];
#pragma unroll
            for (int j = 0; j < 4; j++)
                accW[mt2][j] = __builtin_amdgcn_mfma_f32_16x16x32_bf16(af, bfr[j], accW[mt2][j], 0, 0, 0);
        }
    }
    float scv = sc ? sc[h] : 1.f;
    float shv = sh ? sh[h] : 0.f;
#pragma unroll
    for (int mt2 = 0; mt2 < 2; mt2++) {
        int m0 = (wid*2 + mt2)*16 + g*4;
        float4 rsv = *(const float4*)&rs[(size_t)h*128 + m0];
#pragma unroll
        for (int j = 0; j < 4; j++) {
            int col = col0 + j*16 + nl; int b = col >> LOGNCH, c = col & (NCH - 1);
            ushort4 q;
            q.x = f2bf(fmaf(scv, accT[mt2][j][0], shv*rsv.x) + accW[mt2][j][0]);
            q.y = f2bf(fmaf(scv, accT[mt2][j][1], shv*rsv.y) + accW[mt2][j][1]);
            q.z = f2bf(fmaf(scv, accT[mt2][j][2], shv*rsv.z) + accW[mt2][j][2]);
            q.w = f2bf(fmaf(scv, accT[mt2][j][3], shv*rsv.w) + accW[mt2][j][3]);
            *(ushort4*)&yout[((size_t)h*16 + b)*L + c*128 + m0] = q;
        }
    }
}

// ---------------- fused 4-dilation conv block via MFMA (v8, unchanged) ----------------
template<int CIN, int TBLK>
__global__ __launch_bounds__(256, 2) void conv_mfma4(
    const unsigned short* __restrict__ u, const unsigned short* __restrict__ wp,
    const float* __restrict__ bs0, const float* __restrict__ bs1,
    const float* __restrict__ bs2, const float* __restrict__ bs3,
    unsigned short* __restrict__ out, int Lin, int Lout)
{
    constexpr int F     = TBLK / 16;
    constexpr int NPOS  = TBLK * 4 + 16;
    constexpr int Q     = NPOS / 4;
    constexpr int NITEM = (NPOS / 8) * 64;
    constexpr int NLD   = (NITEM + 255) / 256;
    constexpr int NCC   = CIN / 64;
    constexpr int NBUF  = (NCC > 1) ? 2 : 1;
    constexpr int BUFSZ = 4 * Q * 64;
    __shared__ unsigned short s_in[NBUF * BUFSZ];

    int tid = threadIdx.x;
    int lane = tid & 63, wid = tid >> 6;      // wid == dilation index d
    int nl = lane & 15, g = lane >> 4;
    int t0 = blockIdx.x * TBLK;
    int b  = blockIdx.y;
    int og = blockIdx.z * 64;
    const int P0 = t0 * 4 - 8;
    const int DIL = 1 << wid;                 // wave-uniform

    f32x4 acc[4][F];
#pragma unroll
    for (int m = 0; m < 4; m++)
#pragma unroll
        for (int f = 0; f < F; f++) acc[m][f] = (f32x4){0.f,0.f,0.f,0.f};

    uint4 stg[NLD];

    auto stage_load = [&](int ccbase) {
#pragma unroll
        for (int j = 0; j < NLD; j++) {
            int i = tid + 256 * j;
            uint4 v; v.x = 0u; v.y = 0u; v.z = 0u; v.w = 0u;
            if (i < NITEM) {
                int ch = i & 63, po = i >> 6;
                int p = P0 + po * 8;
                const unsigned short* gp = u + ((size_t)(ccbase + ch)*16 + b)*Lin;
                if (p >= 0 && p + 8 <= Lin) {
                    v = *(const uint4*)(gp + p);
                } else {
                    alignas(16) unsigned short t8[8];
#pragma unroll
                    for (int j2 = 0; j2 < 8; j2++) {
                        int pj = p + j2;
                        t8[j2] = ((unsigned)pj < (unsigned)Lin) ? gp[pj] : (unsigned short)0;
                    }
                    v = *(const uint4*)t8;
                }
            }
            stg[j] = v;
        }
    };
    auto stage_write = [&](int bufidx) {
        unsigned short* sb = s_in + bufidx * BUFSZ;
#pragma unroll
        for (int j = 0; j < NLD; j++) {
            int i = tid + 256 * j;
            if (i < NITEM) {
                int ch = i & 63, po = i >> 6;
                alignas(16) unsigned short t8[8];
                *(uint4*)t8 = stg[j];
#pragma unroll
                for (int jj = 0; jj < 8; jj++) {
                    int pl = po * 8 + jj;
                    int row = (pl & 3) * Q + (pl >> 2);
                    sb[row * 64 + (ch ^ ((row & 7) << 3))] = t8[jj];
                }
            }
        }
    };

    stage_load(0);
    stage_write(0);
    __syncthreads();

#pragma unroll
    for (int cc = 0; cc < NCC; cc++) {
        if (cc + 1 < NCC) stage_load((cc + 1) * 64);
        const unsigned short* sb = s_in + (NBUF > 1 ? (cc & 1) * BUFSZ : 0);
#pragma unroll
        for (int k = 0; k < 3; ++k) {
            const int off = (k - 1) * DIL + 8;
            const int r = off & 3, s = off >> 2;
#pragma unroll
            for (int chalf = 0; chalf < 2; ++chalf) {
                int kb = cc * 6 + k * 2 + chalf;
                short8 bfr[F];
#pragma unroll
                for (int f = 0; f < F; ++f) {
                    int q = f*16 + nl + s;
                    int row = r * Q + q;
                    bfr[f] = *(const short8*)&sb[row * 64 +
                        ((((chalf << 2) | g) ^ (row & 7)) << 3)];
                }
#pragma unroll
                for (int m = 0; m < 4; ++m) {
                    short8 afrag = *(const short8*)&wp[(size_t)wid*(3*CIN*CIN) +
                        ((size_t)kb*CIN + og + m*16 + nl)*32 + g*8];
#pragma unroll
                    for (int f = 0; f < F; ++f)
                        acc[m][f] = __builtin_amdgcn_mfma_f32_16x16x32_bf16(afrag, bfr[f], acc[m][f], 0, 0, 0);
                }
            }
        }
        if (cc + 1 < NCC) {
            __syncthreads();
            stage_write((cc + 1) & 1);
            __syncthreads();
        }
    }

    const float* bp = (wid == 0) ? bs0 : (wid == 1) ? bs1 : (wid == 2) ? bs2 : bs3;
#pragma unroll
    for (int m = 0; m < 4; ++m) {
#pragma unroll
        for (int f = 0; f < F; ++f) {
            int t = t0 + f*16 + nl;
#pragma unroll
            for (int r2 = 0; r2 < 4; ++r2) {
                int o = og + m*16 + g*4 + r2;
                float v = acc[m][f][r2] + bp[o];
                if (wid) v = v >= 0.f ? v : 0.3f*v;
                out[((size_t)(wid*CIN + o)*16 + b)*Lout + t] = f2bf(v);
            }
        }
    }
}

// ---------------- BN stats from bf16 [ch][b][t] ----------------
__global__ __launch_bounds__(256) void bn_stats(
    const unsigned short* __restrict__ x, const float* __restrict__ g,
    const float* __restrict__ bb, float* __restrict__ sc, float* __restrict__ sh,
    int n, int gmask)
{
    int ch = blockIdx.x;
    const unsigned short* xp = x + (size_t)ch * n;
    float s1 = 0.f, s2 = 0.f;
    for (int i = threadIdx.x*8; i < n; i += 2048) {
        uint4 raw = *(const uint4*)(xp + i);
        unsigned short us[8]; *(uint4*)us = raw;
#pragma unroll
        for (int j = 0; j < 8; j++) {
            float v = bf2f(us[j]);
            s1 += v; s2 += v*v;
        }
    }
    for (int o = 32; o > 0; o >>= 1) { s1 += __shfl_down(s1, o); s2 += __shfl_down(s2, o); }
    __shared__ float p1[4], p2[4];
    int wid = threadIdx.x >> 6;
    if ((threadIdx.x & 63) == 0) { p1[wid] = s1; p2[wid] = s2; }
    __syncthreads();
    if (threadIdx.x == 0) {
        s1 = p1[0] + p1[1] + p1[2] + p1[3];
        s2 = p2[0] + p2[1] + p2[2] + p2[3];
        float m = s1 / n;
        float var = s2 / n - m*m;
        float rstd = rsqrtf(var + 1e-5f);
        float scale = g[ch & gmask] * rstd;
        sc[ch] = scale;
        sh[ch] = fmaf(-m, scale, bb[ch & gmask]);
    }
}

// ---------------- s4c fused: E-GEMM + W^128 scan + C-reduction -> x3last ----------
// Replaces s4_gemm_a<4,2> + s4_mid(c) + s4c_last: one 64-thread block per h.
// Phase 1 (verbatim gemm_a math): E[col][j] = sc*(V@u)[j][col] + sh*Vrs[j],
//   col = b*4+c, into LDS (row pad 68 to avoid 16-way write conflicts).
// Phase 2 (verbatim mid math): per (n,b): S = 0; for c: S = W128*S + E.
// Phase 3 (verbatim s4c_last math): out[b] = 2*sum_n(crv*Re - civ*Im) + Dv*uv.
__global__ __launch_bounds__(64) void s4c_all(
    const unsigned short* __restrict__ u, const unsigned short* __restrict__ VA,
    const float* __restrict__ Vrs, const float* __restrict__ sc,
    const float* __restrict__ sh, const float* __restrict__ log_dt,
    const float* __restrict__ C2, const float* __restrict__ Dv,
    float* __restrict__ x3last)
{
    __shared__ float sE[64 * 68];    // [col][j], pad 68 -> 17.4 KB
    __shared__ float red[16 * 33];   // [b][n], pad 33
    int h = blockIdx.x;
    int lane = threadIdx.x;
    int nl = lane & 15, g = lane >> 4;
    float scv = sc[h], shv = sh[h];

    // phase 1: 4 col-groups x 16 MFMA = all 64 (b,c) columns for this h
    for (int cg = 0; cg < 4; cg++) {
        int col = cg*16 + nl;
        int b = col >> 2, c = col & 3;
        const unsigned short* up = u + ((size_t)h*16 + b)*512 + c*128;
        f32x4 acc[4];
#pragma unroll
        for (int mt = 0; mt < 4; mt++) acc[mt] = (f32x4){0.f,0.f,0.f,0.f};
#pragma unroll
        for (int kb = 0; kb < 4; kb++) {
            short8 bf = *(const short8*)(up + kb*32 + g*8);
#pragma unroll
            for (int mt = 0; mt < 4; mt++) {
                short8 af = *(const short8*)(VA + (((size_t)h*4 + kb)*64 + mt*16 + nl)*32 + g*8);
                acc[mt] = __builtin_amdgcn_mfma_f32_16x16x32_bf16(af, bf, acc[mt], 0, 0, 0);
            }
        }
#pragma unroll
        for (int mt = 0; mt < 4; mt++) {
            int j0 = mt*16 + g*4;
            float4 vr = *(const float4*)(Vrs + (size_t)h*64 + j0);
            sE[col*68 + j0 + 0] = fmaf(scv, acc[mt][0], shv*vr.x);
            sE[col*68 + j0 + 1] = fmaf(scv, acc[mt][1], shv*vr.y);
            sE[col*68 + j0 + 2] = fmaf(scv, acc[mt][2], shv*vr.z);
            sE[col*68 + j0 + 3] = fmaf(scv, acc[mt][3], shv*vr.w);
        }
    }
    __syncthreads();

    // phase 2+3 partials: lane = (n, bh); each handles 8 b's
    int n = lane >> 1, bh = lane & 1;
    float dt = expf(log_dt[h]);
    float e = expf(-0.5f * dt);
    float s_, c_; sincosf(PI_F * dt * n, &s_, &c_);
    float wr = e*c_, wi = e*s_;
    // C coefficients (s4c_last math)
    float ar = -0.5f, ai = PI_F * n;
    float den = 1.f / (ar*ar + ai*ai);
    float tr = wr - 1.f, ti = wi;
    float qr = (tr*ar + ti*ai) * den;
    float qi = (ti*ar - tr*ai) * den;
    float c2r = C2[((size_t)h*32 + n)*2], c2i = C2[((size_t)h*32 + n)*2 + 1];
    float crv = c2r*qr - c2i*qi, civ = c2r*qi + c2i*qr;
    // W^128 via 7 squarings
    float Wr = wr, Wi = wi;
#pragma unroll
    for (int i = 0; i < 7; i++) { float r = Wr*Wr - Wi*Wi; float im = 2.f*Wr*Wi; Wr = r; Wi = im; }
#pragma unroll
    for (int b2 = 0; b2 < 8; b2++) {
        int b = bh*8 + b2;
        float Sr = 0.f, Si = 0.f;
#pragma unroll
        for (int c = 0; c < 4; c++) {
            int col = b*4 + c;
            float er = sE[col*68 + 2*n], ei = sE[col*68 + 2*n + 1];
            float r  = fmaf(Wr, Sr, fmaf(-Wi, Si, er));
            float im = fmaf(Wi, Sr, fmaf( Wr, Si, ei));
            Sr = r; Si = im;
        }
        red[b*33 + n] = crv*Sr - civ*Si;
    }
    __syncthreads();
    if (lane < 16) {
        int b = lane;
        float s = 0.f;
        for (int n2 = 0; n2 < 32; n2++) s += red[b*33 + n2];
        float uv = fmaf(scv, bf2f(u[((size_t)h*16 + b)*512 + 511]), shv);
        x3last[b*1024 + h] = 2.f*s + Dv[h]*uv;
    }
}

// ---------------- decoder head ----------------
__global__ __launch_bounds__(256) void dec_kernel(
    const float* __restrict__ x3last, const float* __restrict__ w1, const float* __restrict__ b1,
    const float* __restrict__ w2, const float* __restrict__ b2, float* __restrict__ out)
{
    __shared__ float xs[1024];
    int b = blockIdx.x, tid = threadIdx.x;
    for (int i = tid; i < 1024; i += 256) xs[i] = x3last[b*1024 + i];
    __syncthreads();
    float z = b1[tid];
    const float* wpt = w1 + (size_t)tid*1024;
    for (int i = 0; i < 1024; i += 4) {
        float4 wv = *(const float4*)(wpt + i);
        z = fmaf(wv.x, xs[i],   z);
        z = fmaf(wv.y, xs[i+1], z);
        z = fmaf(wv.z, xs[i+2], z);
        z = fmaf(wv.w, xs[i+3], z);
    }
    float v = w2[tid] * z;
    for (int o = 32; o > 0; o >>= 1) v += __shfl_down(v, o);
    __shared__ float ps[4];
    if ((tid & 63) == 0) ps[tid >> 6] = v;
    __syncthreads();
    if (tid == 0) out[b] = ps[0] + ps[1] + ps[2] + ps[3] + b2[0];
}

extern "C" void kernel_launch(void* const* d_in, const int* in_sizes, int n_in,
                              void* d_out, int out_size, void* d_ws, size_t ws_size,
                              hipStream_t stream)
{
    const float* x       = (const float*)d_in[0];
    const float* enc_w   = (const float*)d_in[1];
    const float* enc_b   = (const float*)d_in[2];
    const float* s4a_ldt = (const float*)d_in[3];
    const float* s4a_C   = (const float*)d_in[4];
    const float* s4a_D   = (const float*)d_in[5];
    const float* s4b_ldt = (const float*)d_in[6];
    const float* s4b_C   = (const float*)d_in[7];
    const float* s4b_D   = (const float*)d_in[8];
    const float* s4c_ldt = (const float*)d_in[9];
    const float* s4c_C   = (const float*)d_in[10];
    const float* s4c_D   = (const float*)d_in[11];
    const float* b1w[4] = {(const float*)d_in[12], (const float*)d_in[14], (const float*)d_in[16], (const float*)d_in[18]};
    const float* b1b[4] = {(const float*)d_in[13], (const float*)d_in[15], (const float*)d_in[17], (const float*)d_in[19]};
    const float* b2w[4] = {(const float*)d_in[20], (const float*)d_in[22], (const float*)d_in[24], (const float*)d_in[26]};
    const float* b2b[4] = {(const float*)d_in[21], (const float*)d_in[23], (const float*)d_in[25], (const float*)d_in[27]};
    const float* bn1_g  = (const float*)d_in[28];
    const float* bn1_b  = (const float*)d_in[29];
    const float* bn2_g  = (const float*)d_in[30];
    const float* bn2_b  = (const float*)d_in[31];
    const float* dec1_w = (const float*)d_in[32];
    const float* dec1_b = (const float*)d_in[33];
    const float* dec2_w = (const float*)d_in[34];
    const float* dec2_b = (const float*)d_in[35];
    float* out = (float*)d_out;

    char* ws = (char*)d_ws;
    unsigned short* u1    = (unsigned short*)(ws);              // 16.8 MB (also u3)
    unsigned short* u3    = u1;
    unsigned short* ya    = (unsigned short*)(ws + 16777216);   // 16.8 MB (also yb, later VA_c)
    unsigned short* yb    = ya;
    unsigned short* VA_c  = ya;                                 // reuse after conv2
    unsigned short* u2    = (unsigned short*)(ws + 33554432);   // 16.8 MB
    float*          Bc    = (float*)(ws + 50331648);            // 16.8 MB
    unsigned short* Sini  = (unsigned short*)(ws + 67108864);   // 8.4 MB (bf16 now)
    unsigned short* wprep = (unsigned short*)(ws + 88080384);   // 1.67 MB
    unsigned short* TA_a  = (unsigned short*)(ws + 89751552);   // 3.15 MB
    unsigned short* TA_b  = (unsigned short*)(ws + 92897280);   // 12.6 MB
    unsigned short* VA_a  = (unsigned short*)(ws + 105480192);  // 1.05 MB
    unsigned short* VA_b  = (unsigned short*)(ws + 106528768);  // 4.2 MB
    float*          rs_a  = (float*)(ws + 110723072);           // 32 KB
    float*          rs_b  = (float*)(ws + 110755840);           // 128 KB
    float*          Vrs_a = (float*)(ws + 110886912);           // 16 KB
    float*          Vrs_b = (float*)(ws + 110903296);           // 64 KB
    float*          smallp= (float*)(ws + 110968832);
    float* sc1 = smallp;         // 256
    float* sh1 = smallp + 256;   // 256
    float* sc2 = smallp + 512;   // 1024
    float* sh2 = smallp + 1536;  // 1024
    float* x3l = smallp + 2560;  // 16384
    float*          Vrs_c = (float*)(ws + 111280128);           // 256 KB

    // prep (independent of data path)
    prep_w<<<dim3(768, 8), 256, 0, stream>>>(b1w[0], b1w[1], b1w[2], b1w[3],
                                             b2w[0], b2w[1], b2w[2], b2w[3], wprep);
    prep_s4<<<64, 128, 0, stream>>>(s4a_ldt, s4a_C, s4a_D, TA_a, VA_a, rs_a, Vrs_a);
    prep_s4<<<256, 128, 0, stream>>>(s4b_ldt, s4b_C, s4b_D, TA_b, VA_b, rs_b, Vrs_b);

    // encoder -> u1 bf16
    enc_kernel<<<8192, 256, 0, stream>>>(x, enc_w, enc_b, u1);

    // s4a: H=64, NCH=64 (L=8192)
    s4_gemm_a<64,6><<<dim3(64, 64), 64, 0, stream>>>(u1, VA_a, Vrs_a, nullptr, nullptr, Bc);
    s4_mid<<<512, 64, 0, stream>>>(s4a_ldt, Bc, Sini, 64, 64);
    s4_gemm_c<64,6><<<dim3(16, 64), 256, 0, stream>>>(u1, Sini, TA_a, rs_a, nullptr, nullptr, ya);

    // conv block1 (fused 4 dilations): ya [64][16][8192] -> u2 [256][16][2048]
    conv_mfma4<64,32><<<dim3(64, 16, 1), 256, 0, stream>>>(
        ya, wprep, b1b[0], b1b[1], b1b[2], b1b[3], u2, 8192, 2048);
    bn_stats<<<256, 256, 0, stream>>>(u2, bn1_g, bn1_b, sc1, sh1, 16*2048, 63);

    // s4b: H=256, NCH=16 (L=2048)
    s4_gemm_a<16,4><<<dim3(16, 256), 64, 0, stream>>>(u2, VA_b, Vrs_b, sc1, sh1, Bc);
    s4_mid<<<2048, 64, 0, stream>>>(s4b_ldt, Bc, Sini, 256, 16);
    s4_gemm_c<16,4><<<dim3(4, 256), 256, 0, stream>>>(u2, Sini, TA_b, rs_b, sc1, sh1, yb);

    // conv block2 (fused 4 dilations): yb [256][16][2048] -> u3 [1024][16][512]
    conv_mfma4<256,64><<<dim3(8, 16, 4), 256, 0, stream>>>(
        yb, wprep + 49152, b2b[0], b2b[1], b2b[2], b2b[3], u3, 2048, 512);
    bn_stats<<<1024, 256, 0, stream>>>(u3, bn2_g, bn2_b, sc2, sh2, 16*512, 255);

    // s4c fused: prep_va (VA_c reuses dead yb slot) + single fused kernel
    prep_va<<<1024, 64, 0, stream>>>(s4c_ldt, VA_c, Vrs_c);
    s4c_all<<<1024, 64, 0, stream>>>(u3, VA_c, Vrs_c, sc2, sh2, s4c_ldt, s4c_C, s4c_D, x3l);

    // decoder head
    dec_kernel<<<16, 256, 0, stream>>>(x3l, dec1_w, dec1_b, dec2_w, dec2_b, out);
}

// Round 11
// 342.230 us; speedup vs baseline: 1.3167x; 1.0950x over previous
//
#include <hip/hip_runtime.h>
#include <math.h>

#define PI_F 3.14159265358979323846f

typedef __attribute__((ext_vector_type(8))) short short8;
typedef __attribute__((ext_vector_type(4))) float f32x4;

__device__ __forceinline__ unsigned short f2bf(float f) {
    unsigned int u = __float_as_uint(f);
    unsigned int r = (u + 0x7fffu + ((u >> 16) & 1u)) >> 16;
    return (unsigned short)r;
}
__device__ __forceinline__ float bf2f(unsigned short v) {
    return __uint_as_float((unsigned int)v << 16);
}

// ---------------- encoder: x[16][8192][2] -> u1 bf16 [64][16][8192] ----------------
__global__ __launch_bounds__(256) void enc_kernel(
    const float* __restrict__ x, const float* __restrict__ ew,
    const float* __restrict__ eb, unsigned short* __restrict__ u1)
{
    int idx = blockIdx.x * 256 + threadIdx.x;   // 64*16*2048 threads, 4 t each
    int t4 = idx & 2047;
    int b  = (idx >> 11) & 15;
    int h  = idx >> 15;
    float w0 = ew[2*h], w1 = ew[2*h+1], bb = eb[h];
    const float* xp = x + ((size_t)b*8192 + (size_t)t4*4)*2;
    float4 a = *(const float4*)xp;
    float4 c = *(const float4*)(xp + 4);
    ushort4 o;
    o.x = f2bf(fmaf(w0, a.x, fmaf(w1, a.y, bb)));
    o.y = f2bf(fmaf(w0, a.z, fmaf(w1, a.w, bb)));
    o.z = f2bf(fmaf(w0, c.x, fmaf(w1, c.y, bb)));
    o.w = f2bf(fmaf(w0, c.z, fmaf(w1, c.w, bb)));
    *(ushort4*)(u1 + ((size_t)h*16 + b)*8192 + (size_t)t4*4) = o;
}

// ---------------- conv weight prep: fp32 [O][Cin][3] -> bf16 A-frag [kb][o][kk] ------
__global__ __launch_bounds__(256) void prep_w(
    const float* __restrict__ w0, const float* __restrict__ w1,
    const float* __restrict__ w2, const float* __restrict__ w3,
    const float* __restrict__ w4, const float* __restrict__ w5,
    const float* __restrict__ w6, const float* __restrict__ w7,
    unsigned short* __restrict__ wprep)
{
    int id = blockIdx.y;
    const float* src; int Cin; size_t doff;
    switch (id) {
        case 0: src = w0; Cin = 64;  doff = 0;      break;
        case 1: src = w1; Cin = 64;  doff = 12288;  break;
        case 2: src = w2; Cin = 64;  doff = 24576;  break;
        case 3: src = w3; Cin = 64;  doff = 36864;  break;
        case 4: src = w4; Cin = 256; doff = 49152;  break;
        case 5: src = w5; Cin = 256; doff = 245760; break;
        case 6: src = w6; Cin = 256; doff = 442368; break;
        default: src = w7; Cin = 256; doff = 638976; break;
    }
    int e = blockIdx.x * 256 + threadIdx.x;
    if (e >= Cin * Cin * 3) return;
    int kb  = e / (Cin * 32);
    int rem = e - kb * (Cin * 32);
    int o   = rem >> 5;
    int kk  = rem & 31;
    int cch = kb / 6, t6 = kb % 6, k = t6 >> 1, chalf = t6 & 1;
    int c = cch * 64 + chalf * 32 + kk;
    wprep[doff + e] = f2bf(src[((size_t)o * Cin + c) * 3 + k]);
}

// ---------------- S4 prep: build per-h MFMA A-matrices (coalesced writes) ----------
// TA[h][kb(6)][m(128)][kk(32)]: kb 0..3 Toeplitz K'[m-col], kb 4..5 W[m][j]
// VA[h][kb(4)][row(64)][kk(32)]: V[2n+ri][s] = w^(127-s) Re/Im
// rs[h][128]: prefix sums of K'; Vrs[h][64]: rowsum of V
__global__ __launch_bounds__(128) void prep_s4(
    const float* __restrict__ log_dt, const float* __restrict__ C2,
    const float* __restrict__ Dv,
    unsigned short* __restrict__ TA, unsigned short* __restrict__ VA,
    float* __restrict__ rs, float* __restrict__ Vrs)
{
    int h = blockIdx.x, t = threadIdx.x;
    __shared__ float cn[64];
    __shared__ float sK[128];
    __shared__ unsigned short s_w[128 * 66];   // W staged [m][j], pad 66
    float dt = expf(log_dt[h]);
    if (t < 32) {
        int n = t;
        float e = expf(-0.5f*dt);
        float s_, c_; sincosf(PI_F*dt*n, &s_, &c_);
        float wr = e*c_, wi = e*s_;
        float ar = -0.5f, ai = PI_F*n;
        float den = 1.f/(ar*ar + ai*ai);
        float tr = wr - 1.f, ti = wi;
        float qr = (tr*ar + ti*ai)*den;
        float qi = (ti*ar - tr*ai)*den;
        float c2r = C2[((size_t)h*32+n)*2], c2i = C2[((size_t)h*32+n)*2+1];
        cn[2*n]   = 2.f*(c2r*qr - c2i*qi);
        cn[2*n+1] = 2.f*(c2r*qi + c2i*qr);
        // Vrs = sum_{j=0}^{127} w^j = (1 - w^128)/(1 - w)
        float e128 = expf(-64.f*dt);
        float s2, c2v; sincosf(PI_F*dt*n*128.f, &s2, &c2v);
        float pr = 1.f - e128*c2v, pim = -e128*s2;
        float dr = 1.f - wr, di = -wi;
        float dd = 1.f/(dr*dr + di*di);
        Vrs[(size_t)h*64 + 2*n]   = (pr*dr + pim*di)*dd;
        Vrs[(size_t)h*64 + 2*n+1] = (pim*dr - pr*di)*dd;
    }
    __syncthreads();
    // phase 1: K[t] (each thread one tap)
    {
        float em = expf(-0.5f*dt*t);
        float Kt = 0.f;
        for (int n = 0; n < 32; n++) {
            float s_, c_; sincosf(PI_F*dt*(float)(n*t), &s_, &c_);
            Kt += cn[2*n]*em*c_ - cn[2*n+1]*em*s_;
        }
        sK[t] = Kt + (t == 0 ? Dv[h] : 0.f);
    }
    // phase 2: wave0 (t<64) builds W columns into LDS; wave1 builds V rows direct
    if (t < 64) {
        int n = t >> 1, ri = t & 1;
        float e = expf(-0.5f*dt);
        float s_, c_; sincosf(PI_F*dt*n, &s_, &c_);
        float wr = e*c_, wi = e*s_;
        float crn = cn[2*n], cin = cn[2*n+1];
        float pr = wr, pim = wi;                    // w^(m+1), m=0
        for (int m = 0; m < 128; m++) {
            float re = crn*pr - cin*pim;
            float im = crn*pim + cin*pr;
            s_w[m*66 + t] = f2bf(ri ? -im : re);
            float nr = pr*wr - pim*wi;
            float ni = pr*wi + pim*wr;
            pr = nr; pim = ni;
        }
    } else {
        int r = t - 64; int n = r >> 1, ri = r & 1;
        float e = expf(-0.5f*dt);
        float s_, c_; sincosf(PI_F*dt*n, &s_, &c_);
        float wr = e*c_, wi = e*s_;
        float cr2 = 1.f, ci2 = 0.f;                 // w^0
        for (int kb = 3; kb >= 0; kb--) {
            unsigned short buf[32];
            for (int kk = 31; kk >= 0; kk--) {
                buf[kk] = f2bf(ri ? ci2 : cr2);
                float nr = cr2*wr - ci2*wi;
                float ni = cr2*wi + ci2*wr;
                cr2 = nr; ci2 = ni;
            }
            uint4* dst = (uint4*)&VA[(((size_t)h*4 + kb)*64 + r)*32];
            uint4* src = (uint4*)buf;
            dst[0]=src[0]; dst[1]=src[1]; dst[2]=src[2]; dst[3]=src[3];
        }
    }
    __syncthreads();
    // prefix sum for BN shift
    {
        float acc = 0.f;
        for (int tau = 0; tau <= t; tau++) acc += sK[tau];
        rs[(size_t)h*128 + t] = acc;
    }
    // Toeplitz row t, buffered uint4 stores
    for (int kb = 0; kb < 4; kb++) {
        unsigned short tb[32];
#pragma unroll
        for (int kk = 0; kk < 32; kk++) {
            int col = kb*32 + kk;
            tb[kk] = f2bf((col <= t) ? sK[t - col] : 0.f);
        }
        uint4* dst = (uint4*)&TA[(((size_t)h*6 + kb)*128 + t)*32];
        uint4* src = (uint4*)tb;
        dst[0]=src[0]; dst[1]=src[1]; dst[2]=src[2]; dst[3]=src[3];
    }
    // W copy-out, coalesced: 1024 uint4 over kb'(2) x m(128) x kkg(4)
    for (int i = t; i < 1024; i += 128) {
        int kb = i >> 9;             // 0..1
        int rem = i & 511;
        int m = rem >> 2, kkg = rem & 3;
        *(uint4*)&TA[(((size_t)h*6 + 4 + kb)*128 + m)*32 + kkg*8] =
            *(const uint4*)&s_w[m*66 + kb*32 + kkg*8];
    }
}

// ---------------- S4 fused A+mid: E-GEMM + chunk scan -> Sini bf16 ----------------
// One 64-thread block per (b,h). Replaces s4_gemm_a + s4_mid: Bc never touches HBM.
// Phase 1 (gemm_a math): E[c][j] = sc*(V@u)[j][c] + sh*Vrs[j] into LDS sE (pad 68).
// Phase 2 (mid math): lane n scans c serially; Sini (pre-update state) overwrites
//   E in place (lane n owns words 2n,2n+1 -> no cross-lane hazard).
// Phase 3: coalesced bf16 copy-out of Sini.
template<int NCH, int LOGNCH>
__global__ __launch_bounds__(64) void s4ab_fused(
    const unsigned short* __restrict__ u, const unsigned short* __restrict__ VA,
    const float* __restrict__ Vrs, const float* __restrict__ sc,
    const float* __restrict__ sh, const float* __restrict__ log_dt,
    unsigned short* __restrict__ Sini)
{
    const int L = NCH * 128;
    __shared__ float sE[NCH * 68];
    int b = blockIdx.x, h = blockIdx.y;
    int lane = threadIdx.x;
    int nl = lane & 15, g = lane >> 4;
    float scv = sc ? sc[h] : 1.f;
    float shv = sh ? sh[h] : 0.f;

#pragma unroll
    for (int cg = 0; cg < NCH/16; cg++) {
        int c = cg*16 + nl;
        const unsigned short* up = u + ((size_t)h*16 + b)*L + c*128;
        f32x4 acc[4];
#pragma unroll
        for (int mt = 0; mt < 4; mt++) acc[mt] = (f32x4){0.f,0.f,0.f,0.f};
#pragma unroll
        for (int kb = 0; kb < 4; kb++) {
            short8 bf = *(const short8*)(up + kb*32 + g*8);
#pragma unroll
            for (int mt = 0; mt < 4; mt++) {
                short8 af = *(const short8*)(VA + (((size_t)h*4 + kb)*64 + mt*16 + nl)*32 + g*8);
                acc[mt] = __builtin_amdgcn_mfma_f32_16x16x32_bf16(af, bf, acc[mt], 0, 0, 0);
            }
        }
#pragma unroll
        for (int mt = 0; mt < 4; mt++) {
            int j0 = mt*16 + g*4;
            float4 vr = *(const float4*)(Vrs + (size_t)h*64 + j0);
            sE[c*68 + j0 + 0] = fmaf(scv, acc[mt][0], shv*vr.x);
            sE[c*68 + j0 + 1] = fmaf(scv, acc[mt][1], shv*vr.y);
            sE[c*68 + j0 + 2] = fmaf(scv, acc[mt][2], shv*vr.z);
            sE[c*68 + j0 + 3] = fmaf(scv, acc[mt][3], shv*vr.w);
        }
    }
    __syncthreads();
    if (lane < 32) {
        int n = lane;
        float dt = expf(log_dt[h]);
        float e = expf(-0.5f * dt);
        float s_, c_; sincosf(PI_F * dt * n, &s_, &c_);
        float Wr = e*c_, Wi = e*s_;
#pragma unroll
        for (int i = 0; i < 7; i++) { float r = Wr*Wr - Wi*Wi; float im = 2.f*Wr*Wi; Wr = r; Wi = im; }
        float Sr = 0.f, Si = 0.f;
        for (int c2 = 0; c2 < NCH; c2++) {
            float* ep = &sE[c2*68 + 2*n];
            float er = ep[0], ei = ep[1];
            ep[0] = Sr; ep[1] = Si;          // Sini = state BEFORE chunk c2
            float r  = fmaf(Wr, Sr, fmaf(-Wi, Si, er));
            float im = fmaf(Wi, Sr, fmaf( Wr, Si, ei));
            Sr = r; Si = im;
        }
    }
    __syncthreads();
    unsigned short* sp = Sini + ((size_t)h*16 + b)*NCH*64;
    for (int i = lane*4; i < NCH*64; i += 256) {
        int c2 = i >> 6, j = i & 63;
        ushort4 q;
        q.x = f2bf(sE[c2*68 + j]);
        q.y = f2bf(sE[c2*68 + j+1]);
        q.z = f2bf(sE[c2*68 + j+2]);
        q.w = f2bf(sE[c2*68 + j+3]);
        *(ushort4*)&sp[i] = q;
    }
}

// ---------------- S4 pass C (GEMM): y = sc*(T'@u) + sh*rs + W@Sinit ----------------
template<int NCH, int LOGNCH>
__global__ __launch_bounds__(256) void s4_gemm_c(
    const unsigned short* __restrict__ u, const unsigned short* __restrict__ Sini,
    const unsigned short* __restrict__ TA, const float* __restrict__ rs,
    const float* __restrict__ sc, const float* __restrict__ sh,
    unsigned short* __restrict__ yout)
{
    const int L = NCH * 128;
    __shared__ unsigned short s_u[64*200];   // 25600 B
    __shared__ unsigned short s_s[64*72];    // 9216 B
    int h = blockIdx.y;
    int tid = threadIdx.x;
    int lane = tid & 63, wid = tid >> 6;
    int nl = lane & 15, g = lane >> 4;
    int col0 = blockIdx.x * 64;
    for (int i = tid; i < 1024; i += 256) {
        int cl = i >> 4, o = i & 15;
        int col = col0 + cl; int b = col >> LOGNCH, c = col & (NCH - 1);
        *(uint4*)&s_u[cl*200 + o*8] =
            *(const uint4*)&u[((size_t)h*16 + b)*L + c*128 + o*8];
    }
    for (int i = tid; i < 1024; i += 256) {
        int cl = i >> 4, o = i & 15;
        int col = col0 + cl; int b = col >> LOGNCH, c = col & (NCH - 1);
        *(ushort4*)&s_s[cl*72 + o*4] =
            *(const ushort4*)&Sini[(((size_t)h*16 + b)*NCH + c)*64 + o*4];
    }
    __syncthreads();
    f32x4 accT[2][4], accW[2][4];
#pragma unroll
    for (int a = 0; a < 2; a++)
#pragma unroll
        for (int j = 0; j < 4; j++) { accT[a][j] = (f32x4){0,0,0,0}; accW[a][j] = (f32x4){0,0,0,0}; }
#pragma unroll
    for (int kb = 0; kb < 4; kb++) {
        short8 bfr[4];
#pragma unroll
        for (int j = 0; j < 4; j++)
            bfr[j] = *(const short8*)&s_u[(j*16 + nl)*200 + kb*32 + g*8];
#pragma unroll
        for (int mt2 = 0; mt2 < 2; mt2++) {
            int mtile = wid*2 + mt2;
            short8 af = *(const short8*)&TA[(((size_t)h*6 + kb)*128 + mtile*16 + nl)*32 + g*8];
#pragma unroll
            for (int j = 0; j < 4; j++)
                accT[mt2][j] = __builtin_amdgcn_mfma_f32_16x16x32_bf16(af, bfr[j], accT[mt2][j], 0, 0, 0);
        }
    }
#pragma unroll
    for (int kw = 0; kw < 2; kw++) {
        short8 bfr[4];
#pragma unroll
        for (int j = 0; j < 4; j++)
            bfr[j] = *(const short8*)&s_s[(j*16 + nl)*72 + kw*32 + g*8];
#pragma unroll
        for (int mt2 = 0; mt2 < 2; mt2++) {
            int mtile = wid*2 + mt2;
            short8 af = *(const short8*)&TA[(((size_t)h*6 + 4 + kw)*128 + mtile*16 + nl)*32 + g*8];
#pragma unroll
            for (int j = 0; j < 4; j++)
                accW[mt2][j] = __builtin_amdgcn_mfma_f32_16x16x32_bf16(af, bfr[j], accW[mt2][j], 0, 0, 0);
        }
    }
    float scv = sc ? sc[h] : 1.f;
    float shv = sh ? sh[h] : 0.f;
#pragma unroll
    for (int mt2 = 0; mt2 < 2; mt2++) {
        int m0 = (wid*2 + mt2)*16 + g*4;
        float4 rsv = *(const float4*)&rs[(size_t)h*128 + m0];
#pragma unroll
        for (int j = 0; j < 4; j++) {
            int col = col0 + j*16 + nl; int b = col >> LOGNCH, c = col & (NCH - 1);
            ushort4 q;
            q.x = f2bf(fmaf(scv, accT[mt2][j][0], shv*rsv.x) + accW[mt2][j][0]);
            q.y = f2bf(fmaf(scv, accT[mt2][j][1], shv*rsv.y) + accW[mt2][j][1]);
            q.z = f2bf(fmaf(scv, accT[mt2][j][2], shv*rsv.z) + accW[mt2][j][2]);
            q.w = f2bf(fmaf(scv, accT[mt2][j][3], shv*rsv.w) + accW[mt2][j][3]);
            *(ushort4*)&yout[((size_t)h*16 + b)*L + c*128 + m0] = q;
        }
    }
}

// ---------------- fused 4-dilation conv block via MFMA (v8, unchanged) ----------------
template<int CIN, int TBLK>
__global__ __launch_bounds__(256, 2) void conv_mfma4(
    const unsigned short* __restrict__ u, const unsigned short* __restrict__ wp,
    const float* __restrict__ bs0, const float* __restrict__ bs1,
    const float* __restrict__ bs2, const float* __restrict__ bs3,
    unsigned short* __restrict__ out, int Lin, int Lout)
{
    constexpr int F     = TBLK / 16;
    constexpr int NPOS  = TBLK * 4 + 16;
    constexpr int Q     = NPOS / 4;
    constexpr int NITEM = (NPOS / 8) * 64;
    constexpr int NLD   = (NITEM + 255) / 256;
    constexpr int NCC   = CIN / 64;
    constexpr int NBUF  = (NCC > 1) ? 2 : 1;
    constexpr int BUFSZ = 4 * Q * 64;
    __shared__ unsigned short s_in[NBUF * BUFSZ];

    int tid = threadIdx.x;
    int lane = tid & 63, wid = tid >> 6;      // wid == dilation index d
    int nl = lane & 15, g = lane >> 4;
    int t0 = blockIdx.x * TBLK;
    int b  = blockIdx.y;
    int og = blockIdx.z * 64;
    const int P0 = t0 * 4 - 8;
    const int DIL = 1 << wid;                 // wave-uniform

    f32x4 acc[4][F];
#pragma unroll
    for (int m = 0; m < 4; m++)
#pragma unroll
        for (int f = 0; f < F; f++) acc[m][f] = (f32x4){0.f,0.f,0.f,0.f};

    uint4 stg[NLD];

    auto stage_load = [&](int ccbase) {
#pragma unroll
        for (int j = 0; j < NLD; j++) {
            int i = tid + 256 * j;
            uint4 v; v.x = 0u; v.y = 0u; v.z = 0u; v.w = 0u;
            if (i < NITEM) {
                int ch = i & 63, po = i >> 6;
                int p = P0 + po * 8;
                const unsigned short* gp = u + ((size_t)(ccbase + ch)*16 + b)*Lin;
                if (p >= 0 && p + 8 <= Lin) {
                    v = *(const uint4*)(gp + p);
                } else {
                    alignas(16) unsigned short t8[8];
#pragma unroll
                    for (int j2 = 0; j2 < 8; j2++) {
                        int pj = p + j2;
                        t8[j2] = ((unsigned)pj < (unsigned)Lin) ? gp[pj] : (unsigned short)0;
                    }
                    v = *(const uint4*)t8;
                }
            }
            stg[j] = v;
        }
    };
    auto stage_write = [&](int bufidx) {
        unsigned short* sb = s_in + bufidx * BUFSZ;
#pragma unroll
        for (int j = 0; j < NLD; j++) {
            int i = tid + 256 * j;
            if (i < NITEM) {
                int ch = i & 63, po = i >> 6;
                alignas(16) unsigned short t8[8];
                *(uint4*)t8 = stg[j];
#pragma unroll
                for (int jj = 0; jj < 8; jj++) {
                    int pl = po * 8 + jj;
                    int row = (pl & 3) * Q + (pl >> 2);
                    sb[row * 64 + (ch ^ ((row & 7) << 3))] = t8[jj];
                }
            }
        }
    };

    stage_load(0);
    stage_write(0);
    __syncthreads();

#pragma unroll
    for (int cc = 0; cc < NCC; cc++) {
        if (cc + 1 < NCC) stage_load((cc + 1) * 64);
        const unsigned short* sb = s_in + (NBUF > 1 ? (cc & 1) * BUFSZ : 0);
#pragma unroll
        for (int k = 0; k < 3; ++k) {
            const int off = (k - 1) * DIL + 8;
            const int r = off & 3, s = off >> 2;
#pragma unroll
            for (int chalf = 0; chalf < 2; ++chalf) {
                int kb = cc * 6 + k * 2 + chalf;
                short8 bfr[F];
#pragma unroll
                for (int f = 0; f < F; ++f) {
                    int q = f*16 + nl + s;
                    int row = r * Q + q;
                    bfr[f] = *(const short8*)&sb[row * 64 +
                        ((((chalf << 2) | g) ^ (row & 7)) << 3)];
                }
#pragma unroll
                for (int m = 0; m < 4; ++m) {
                    short8 afrag = *(const short8*)&wp[(size_t)wid*(3*CIN*CIN) +
                        ((size_t)kb*CIN + og + m*16 + nl)*32 + g*8];
#pragma unroll
                    for (int f = 0; f < F; ++f)
                        acc[m][f] = __builtin_amdgcn_mfma_f32_16x16x32_bf16(afrag, bfr[f], acc[m][f], 0, 0, 0);
                }
            }
        }
        if (cc + 1 < NCC) {
            __syncthreads();
            stage_write((cc + 1) & 1);
            __syncthreads();
        }
    }

    const float* bp = (wid == 0) ? bs0 : (wid == 1) ? bs1 : (wid == 2) ? bs2 : bs3;
#pragma unroll
    for (int m = 0; m < 4; ++m) {
#pragma unroll
        for (int f = 0; f < F; ++f) {
            int t = t0 + f*16 + nl;
#pragma unroll
            for (int r2 = 0; r2 < 4; ++r2) {
                int o = og + m*16 + g*4 + r2;
                float v = acc[m][f][r2] + bp[o];
                if (wid) v = v >= 0.f ? v : 0.3f*v;
                out[((size_t)(wid*CIN + o)*16 + b)*Lout + t] = f2bf(v);
            }
        }
    }
}

// ---------------- BN stats from bf16 [ch][b][t] ----------------
__global__ __launch_bounds__(256) void bn_stats(
    const unsigned short* __restrict__ x, const float* __restrict__ g,
    const float* __restrict__ bb, float* __restrict__ sc, float* __restrict__ sh,
    int n, int gmask)
{
    int ch = blockIdx.x;
    const unsigned short* xp = x + (size_t)ch * n;
    float s1 = 0.f, s2 = 0.f;
    for (int i = threadIdx.x*8; i < n; i += 2048) {
        uint4 raw = *(const uint4*)(xp + i);
        unsigned short us[8]; *(uint4*)us = raw;
#pragma unroll
        for (int j = 0; j < 8; j++) {
            float v = bf2f(us[j]);
            s1 += v; s2 += v*v;
        }
    }
    for (int o = 32; o > 0; o >>= 1) { s1 += __shfl_down(s1, o); s2 += __shfl_down(s2, o); }
    __shared__ float p1[4], p2[4];
    int wid = threadIdx.x >> 6;
    if ((threadIdx.x & 63) == 0) { p1[wid] = s1; p2[wid] = s2; }
    __syncthreads();
    if (threadIdx.x == 0) {
        s1 = p1[0] + p1[1] + p1[2] + p1[3];
        s2 = p2[0] + p2[1] + p2[2] + p2[3];
        float m = s1 / n;
        float var = s2 / n - m*m;
        float rstd = rsqrtf(var + 1e-5f);
        float scale = g[ch & gmask] * rstd;
        sc[ch] = scale;
        sh[ch] = fmaf(-m, scale, bb[ch & gmask]);
    }
}

// ---------------- s4c fused v2: in-LDS V build + E-GEMM + scan + C-reduction -------
// Replaces prep_va + gemm_a + mid + last: one 64-thread block per h.
// Build: V rows (prep_va recurrence) into LDS, chunk-swizzled (chunk ^ ((row>>1)&3))
//   so the MFMA ds_read_b128 at 64B row stride is 2-way, not 8-way; Vrs in LDS.
// Then phases 1-3 as before (verbatim math).
__global__ __launch_bounds__(64) void s4c_all(
    const unsigned short* __restrict__ u,
    const float* __restrict__ sc, const float* __restrict__ sh,
    const float* __restrict__ log_dt, const float* __restrict__ C2,
    const float* __restrict__ Dv, float* __restrict__ x3last)
{
    __shared__ float sE[64 * 68];              // 17408 B
    __shared__ float red[16 * 33];             // 2112 B
    __shared__ unsigned short sVA[4 * 64 * 32];// 16384 B
    __shared__ alignas(16) float sVrs[64];     // 256 B
    int h = blockIdx.x;
    int lane = threadIdx.x;
    int nl = lane & 15, g = lane >> 4;
    float scv = sc[h], shv = sh[h];
    float dt = expf(log_dt[h]);

    // build V rows + Vrs (prep_va math, LDS dest, chunk-swizzled)
    {
        int t = lane, n = t >> 1, ri = t & 1;
        float e = expf(-0.5f*dt);
        float s_, c_; sincosf(PI_F*dt*n, &s_, &c_);
        float wr = e*c_, wi = e*s_;
        float cr2 = 1.f, ci2 = 0.f;              // w^0 -> col 127
        int key = (t >> 1) & 3;
        for (int kb = 3; kb >= 0; kb--) {
            alignas(16) unsigned short buf[32];
            for (int kk = 31; kk >= 0; kk--) {
                buf[kk] = f2bf(ri ? ci2 : cr2);
                float nr = cr2*wr - ci2*wi;
                float ni = cr2*wi + ci2*wr;
                cr2 = nr; ci2 = ni;
            }
            uint4* dst = (uint4*)&sVA[(kb*64 + t)*32];
            uint4* src4 = (uint4*)buf;
#pragma unroll
            for (int cc = 0; cc < 4; cc++) dst[cc ^ key] = src4[cc];
        }
        if (ri == 0) {
            float e128 = expf(-64.f*dt);
            float s2, c2v; sincosf(PI_F*dt*n*128.f, &s2, &c2v);
            float pr = 1.f - e128*c2v, pim = -e128*s2;
            float dr = 1.f - wr, di = -wi;
            float dd = 1.f/(dr*dr + di*di);
            sVrs[2*n]   = (pr*dr + pim*di)*dd;
            sVrs[2*n+1] = (pim*dr - pr*di)*dd;
        }
    }
    __syncthreads();

    // phase 1: 4 col-groups x 16 MFMA = all 64 (b,c) columns for this h
    int rkey = (nl >> 1) & 3;
    for (int cg = 0; cg < 4; cg++) {
        int col = cg*16 + nl;
        int b = col >> 2, c = col & 3;
        const unsigned short* up = u + ((size_t)h*16 + b)*512 + c*128;
        f32x4 acc[4];
#pragma unroll
        for (int mt = 0; mt < 4; mt++) acc[mt] = (f32x4){0.f,0.f,0.f,0.f};
#pragma unroll
        for (int kb = 0; kb < 4; kb++) {
            short8 bf = *(const short8*)(up + kb*32 + g*8);
#pragma unroll
            for (int mt = 0; mt < 4; mt++) {
                short8 af = *(const short8*)&sVA[(kb*64 + mt*16 + nl)*32 + ((g ^ rkey) << 3)];
                acc[mt] = __builtin_amdgcn_mfma_f32_16x16x32_bf16(af, bf, acc[mt], 0, 0, 0);
            }
        }
#pragma unroll
        for (int mt = 0; mt < 4; mt++) {
            int j0 = mt*16 + g*4;
            float4 vr = *(const float4*)&sVrs[j0];
            sE[col*68 + j0 + 0] = fmaf(scv, acc[mt][0], shv*vr.x);
            sE[col*68 + j0 + 1] = fmaf(scv, acc[mt][1], shv*vr.y);
            sE[col*68 + j0 + 2] = fmaf(scv, acc[mt][2], shv*vr.z);
            sE[col*68 + j0 + 3] = fmaf(scv, acc[mt][3], shv*vr.w);
        }
    }
    __syncthreads();

    // phase 2+3 partials: lane = (n, bh); each handles 8 b's
    int n = lane >> 1, bh = lane & 1;
    float e = expf(-0.5f * dt);
    float s_, c_; sincosf(PI_F * dt * n, &s_, &c_);
    float wr = e*c_, wi = e*s_;
    float ar = -0.5f, ai = PI_F * n;
    float den = 1.f / (ar*ar + ai*ai);
    float tr = wr - 1.f, ti = wi;
    float qr = (tr*ar + ti*ai) * den;
    float qi = (ti*ar - tr*ai) * den;
    float c2r = C2[((size_t)h*32 + n)*2], c2i = C2[((size_t)h*32 + n)*2 + 1];
    float crv = c2r*qr - c2i*qi, civ = c2r*qi + c2i*qr;
    float Wr = wr, Wi = wi;
#pragma unroll
    for (int i = 0; i < 7; i++) { float r = Wr*Wr - Wi*Wi; float im = 2.f*Wr*Wi; Wr = r; Wi = im; }
#pragma unroll
    for (int b2 = 0; b2 < 8; b2++) {
        int b = bh*8 + b2;
        float Sr = 0.f, Si = 0.f;
#pragma unroll
        for (int c = 0; c < 4; c++) {
            int col = b*4 + c;
            float er = sE[col*68 + 2*n], ei = sE[col*68 + 2*n + 1];
            float r  = fmaf(Wr, Sr, fmaf(-Wi, Si, er));
            float im = fmaf(Wi, Sr, fmaf( Wr, Si, ei));
            Sr = r; Si = im;
        }
        red[b*33 + n] = crv*Sr - civ*Si;
    }
    __syncthreads();
    if (lane < 16) {
        int b = lane;
        float s = 0.f;
        for (int n2 = 0; n2 < 32; n2++) s += red[b*33 + n2];
        float uv = fmaf(scv, bf2f(u[((size_t)h*16 + b)*512 + 511]), shv);
        x3last[b*1024 + h] = 2.f*s + Dv[h]*uv;
    }
}

// ---------------- decoder head ----------------
__global__ __launch_bounds__(256) void dec_kernel(
    const float* __restrict__ x3last, const float* __restrict__ w1, const float* __restrict__ b1,
    const float* __restrict__ w2, const float* __restrict__ b2, float* __restrict__ out)
{
    __shared__ float xs[1024];
    int b = blockIdx.x, tid = threadIdx.x;
    for (int i = tid; i < 1024; i += 256) xs[i] = x3last[b*1024 + i];
    __syncthreads();
    float z = b1[tid];
    const float* wpt = w1 + (size_t)tid*1024;
    for (int i = 0; i < 1024; i += 4) {
        float4 wv = *(const float4*)(wpt + i);
        z = fmaf(wv.x, xs[i],   z);
        z = fmaf(wv.y, xs[i+1], z);
        z = fmaf(wv.z, xs[i+2], z);
        z = fmaf(wv.w, xs[i+3], z);
    }
    float v = w2[tid] * z;
    for (int o = 32; o > 0; o >>= 1) v += __shfl_down(v, o);
    __shared__ float ps[4];
    if ((tid & 63) == 0) ps[tid >> 6] = v;
    __syncthreads();
    if (tid == 0) out[b] = ps[0] + ps[1] + ps[2] + ps[3] + b2[0];
}

extern "C" void kernel_launch(void* const* d_in, const int* in_sizes, int n_in,
                              void* d_out, int out_size, void* d_ws, size_t ws_size,
                              hipStream_t stream)
{
    const float* x       = (const float*)d_in[0];
    const float* enc_w   = (const float*)d_in[1];
    const float* enc_b   = (const float*)d_in[2];
    const float* s4a_ldt = (const float*)d_in[3];
    const float* s4a_C   = (const float*)d_in[4];
    const float* s4a_D   = (const float*)d_in[5];
    const float* s4b_ldt = (const float*)d_in[6];
    const float* s4b_C   = (const float*)d_in[7];
    const float* s4b_D   = (const float*)d_in[8];
    const float* s4c_ldt = (const float*)d_in[9];
    const float* s4c_C   = (const float*)d_in[10];
    const float* s4c_D   = (const float*)d_in[11];
    const float* b1w[4] = {(const float*)d_in[12], (const float*)d_in[14], (const float*)d_in[16], (const float*)d_in[18]};
    const float* b1b[4] = {(const float*)d_in[13], (const float*)d_in[15], (const float*)d_in[17], (const float*)d_in[19]};
    const float* b2w[4] = {(const float*)d_in[20], (const float*)d_in[22], (const float*)d_in[24], (const float*)d_in[26]};
    const float* b2b[4] = {(const float*)d_in[21], (const float*)d_in[23], (const float*)d_in[25], (const float*)d_in[27]};
    const float* bn1_g  = (const float*)d_in[28];
    const float* bn1_b  = (const float*)d_in[29];
    const float* bn2_g  = (const float*)d_in[30];
    const float* bn2_b  = (const float*)d_in[31];
    const float* dec1_w = (const float*)d_in[32];
    const float* dec1_b = (const float*)d_in[33];
    const float* dec2_w = (const float*)d_in[34];
    const float* dec2_b = (const float*)d_in[35];
    float* out = (float*)d_out;

    char* ws = (char*)d_ws;
    unsigned short* u1    = (unsigned short*)(ws);              // 16.8 MB (also u3)
    unsigned short* u3    = u1;
    unsigned short* ya    = (unsigned short*)(ws + 16777216);   // 16.8 MB (also yb)
    unsigned short* yb    = ya;
    unsigned short* u2    = (unsigned short*)(ws + 33554432);   // 16.8 MB
    unsigned short* Sini  = (unsigned short*)(ws + 67108864);   // 8.4 MB (bf16)
    unsigned short* wprep = (unsigned short*)(ws + 88080384);   // 1.67 MB
    unsigned short* TA_a  = (unsigned short*)(ws + 89751552);   // 3.15 MB
    unsigned short* TA_b  = (unsigned short*)(ws + 92897280);   // 12.6 MB
    unsigned short* VA_a  = (unsigned short*)(ws + 105480192);  // 1.05 MB
    unsigned short* VA_b  = (unsigned short*)(ws + 106528768);  // 4.2 MB
    float*          rs_a  = (float*)(ws + 110723072);           // 32 KB
    float*          rs_b  = (float*)(ws + 110755840);           // 128 KB
    float*          Vrs_a = (float*)(ws + 110886912);           // 16 KB
    float*          Vrs_b = (float*)(ws + 110903296);           // 64 KB
    float*          smallp= (float*)(ws + 110968832);
    float* sc1 = smallp;         // 256
    float* sh1 = smallp + 256;   // 256
    float* sc2 = smallp + 512;   // 1024
    float* sh2 = smallp + 1536;  // 1024
    float* x3l = smallp + 2560;  // 16384

    // prep (independent of data path)
    prep_w<<<dim3(768, 8), 256, 0, stream>>>(b1w[0], b1w[1], b1w[2], b1w[3],
                                             b2w[0], b2w[1], b2w[2], b2w[3], wprep);
    prep_s4<<<64, 128, 0, stream>>>(s4a_ldt, s4a_C, s4a_D, TA_a, VA_a, rs_a, Vrs_a);
    prep_s4<<<256, 128, 0, stream>>>(s4b_ldt, s4b_C, s4b_D, TA_b, VA_b, rs_b, Vrs_b);

    // encoder -> u1 bf16
    enc_kernel<<<8192, 256, 0, stream>>>(x, enc_w, enc_b, u1);

    // s4a: H=64, NCH=64 (L=8192) -- fused gemm_a+mid (Bc eliminated)
    s4ab_fused<64,6><<<dim3(16, 64), 64, 0, stream>>>(u1, VA_a, Vrs_a, nullptr, nullptr, s4a_ldt, Sini);
    s4_gemm_c<64,6><<<dim3(16, 64), 256, 0, stream>>>(u1, Sini, TA_a, rs_a, nullptr, nullptr, ya);

    // conv block1 (fused 4 dilations): ya [64][16][8192] -> u2 [256][16][2048]
    conv_mfma4<64,32><<<dim3(64, 16, 1), 256, 0, stream>>>(
        ya, wprep, b1b[0], b1b[1], b1b[2], b1b[3], u2, 8192, 2048);
    bn_stats<<<256, 256, 0, stream>>>(u2, bn1_g, bn1_b, sc1, sh1, 16*2048, 63);

    // s4b: H=256, NCH=16 (L=2048) -- fused gemm_a+mid
    s4ab_fused<16,4><<<dim3(16, 256), 64, 0, stream>>>(u2, VA_b, Vrs_b, sc1, sh1, s4b_ldt, Sini);
    s4_gemm_c<16,4><<<dim3(4, 256), 256, 0, stream>>>(u2, Sini, TA_b, rs_b, sc1, sh1, yb);

    // conv block2 (fused 4 dilations): yb [256][16][2048] -> u3 [1024][16][512]
    conv_mfma4<256,64><<<dim3(8, 16, 4), 256, 0, stream>>>(
        yb, wprep + 49152, b2b[0], b2b[1], b2b[2], b2b[3], u3, 2048, 512);
    bn_stats<<<1024, 256, 0, stream>>>(u3, bn2_g, bn2_b, sc2, sh2, 16*512, 255);

    // s4c fused v2: in-LDS V build (prep_va eliminated) + GEMM + scan + reduction
    s4c_all<<<1024, 64, 0, stream>>>(u3, sc2, sh2, s4c_ldt, s4c_C, s4c_D, x3l);

    // decoder head
    dec_kernel<<<16, 256, 0, stream>>>(x3l, dec1_w, dec1_b, dec2_w, dec2_b, out);
}

// Round 12
// 325.674 us; speedup vs baseline: 1.3836x; 1.0508x over previous
//
#include <hip/hip_runtime.h>
#include <math.h>

#define PI_F 3.14159265358979323846f

typedef __attribute__((ext_vector_type(8))) short short8;
typedef __attribute__((ext_vector_type(4))) float f32x4;

__device__ __forceinline__ unsigned short f2bf(float f) {
    unsigned int u = __float_as_uint(f);
    unsigned int r = (u + 0x7fffu + ((u >> 16) & 1u)) >> 16;
    return (unsigned short)r;
}
__device__ __forceinline__ float bf2f(unsigned short v) {
    return __uint_as_float((unsigned int)v << 16);
}

// ---------------- encoder: x[16][8192][2] -> u1 bf16 [64][16][8192] ----------------
__global__ __launch_bounds__(256) void enc_kernel(
    const float* __restrict__ x, const float* __restrict__ ew,
    const float* __restrict__ eb, unsigned short* __restrict__ u1)
{
    int idx = blockIdx.x * 256 + threadIdx.x;   // 64*16*2048 threads, 4 t each
    int t4 = idx & 2047;
    int b  = (idx >> 11) & 15;
    int h  = idx >> 15;
    float w0 = ew[2*h], w1 = ew[2*h+1], bb = eb[h];
    const float* xp = x + ((size_t)b*8192 + (size_t)t4*4)*2;
    float4 a = *(const float4*)xp;
    float4 c = *(const float4*)(xp + 4);
    ushort4 o;
    o.x = f2bf(fmaf(w0, a.x, fmaf(w1, a.y, bb)));
    o.y = f2bf(fmaf(w0, a.z, fmaf(w1, a.w, bb)));
    o.z = f2bf(fmaf(w0, c.x, fmaf(w1, c.y, bb)));
    o.w = f2bf(fmaf(w0, c.z, fmaf(w1, c.w, bb)));
    *(ushort4*)(u1 + ((size_t)h*16 + b)*8192 + (size_t)t4*4) = o;
}

// ---------------- conv weight prep: fp32 [O][Cin][3] -> bf16 A-frag [kb][o][kk] ------
__global__ __launch_bounds__(256) void prep_w(
    const float* __restrict__ w0, const float* __restrict__ w1,
    const float* __restrict__ w2, const float* __restrict__ w3,
    const float* __restrict__ w4, const float* __restrict__ w5,
    const float* __restrict__ w6, const float* __restrict__ w7,
    unsigned short* __restrict__ wprep)
{
    int id = blockIdx.y;
    const float* src; int Cin; size_t doff;
    switch (id) {
        case 0: src = w0; Cin = 64;  doff = 0;      break;
        case 1: src = w1; Cin = 64;  doff = 12288;  break;
        case 2: src = w2; Cin = 64;  doff = 24576;  break;
        case 3: src = w3; Cin = 64;  doff = 36864;  break;
        case 4: src = w4; Cin = 256; doff = 49152;  break;
        case 5: src = w5; Cin = 256; doff = 245760; break;
        case 6: src = w6; Cin = 256; doff = 442368; break;
        default: src = w7; Cin = 256; doff = 638976; break;
    }
    int e = blockIdx.x * 256 + threadIdx.x;
    if (e >= Cin * Cin * 3) return;
    int kb  = e / (Cin * 32);
    int rem = e - kb * (Cin * 32);
    int o   = rem >> 5;
    int kk  = rem & 31;
    int cch = kb / 6, t6 = kb % 6, k = t6 >> 1, chalf = t6 & 1;
    int c = cch * 64 + chalf * 32 + kk;
    wprep[doff + e] = f2bf(src[((size_t)o * Cin + c) * 3 + k]);
}

// ---------------- S4 prep: build per-h MFMA A-matrices (coalesced writes) ----------
// TA[h][kb(6)][m(128)][kk(32)]: kb 0..3 Toeplitz K'[m-col], kb 4..5 W[m][j]
// VA[h][kb(4)][row(64)][kk(32)]: V[2n+ri][s] = w^(127-s) Re/Im
// rs[h][128]: prefix sums of K'; Vrs[h][64]: rowsum of V
__global__ __launch_bounds__(128) void prep_s4(
    const float* __restrict__ log_dt, const float* __restrict__ C2,
    const float* __restrict__ Dv,
    unsigned short* __restrict__ TA, unsigned short* __restrict__ VA,
    float* __restrict__ rs, float* __restrict__ Vrs)
{
    int h = blockIdx.x, t = threadIdx.x;
    __shared__ float cn[64];
    __shared__ float sK[128];
    __shared__ unsigned short s_w[128 * 66];   // W staged [m][j], pad 66
    float dt = expf(log_dt[h]);
    if (t < 32) {
        int n = t;
        float e = expf(-0.5f*dt);
        float s_, c_; sincosf(PI_F*dt*n, &s_, &c_);
        float wr = e*c_, wi = e*s_;
        float ar = -0.5f, ai = PI_F*n;
        float den = 1.f/(ar*ar + ai*ai);
        float tr = wr - 1.f, ti = wi;
        float qr = (tr*ar + ti*ai)*den;
        float qi = (ti*ar - tr*ai)*den;
        float c2r = C2[((size_t)h*32+n)*2], c2i = C2[((size_t)h*32+n)*2+1];
        cn[2*n]   = 2.f*(c2r*qr - c2i*qi);
        cn[2*n+1] = 2.f*(c2r*qi + c2i*qr);
        // Vrs = sum_{j=0}^{127} w^j = (1 - w^128)/(1 - w)
        float e128 = expf(-64.f*dt);
        float s2, c2v; sincosf(PI_F*dt*n*128.f, &s2, &c2v);
        float pr = 1.f - e128*c2v, pim = -e128*s2;
        float dr = 1.f - wr, di = -wi;
        float dd = 1.f/(dr*dr + di*di);
        Vrs[(size_t)h*64 + 2*n]   = (pr*dr + pim*di)*dd;
        Vrs[(size_t)h*64 + 2*n+1] = (pim*dr - pr*di)*dd;
    }
    __syncthreads();
    // phase 1: K[t] (each thread one tap)
    {
        float em = expf(-0.5f*dt*t);
        float Kt = 0.f;
        for (int n = 0; n < 32; n++) {
            float s_, c_; sincosf(PI_F*dt*(float)(n*t), &s_, &c_);
            Kt += cn[2*n]*em*c_ - cn[2*n+1]*em*s_;
        }
        sK[t] = Kt + (t == 0 ? Dv[h] : 0.f);
    }
    // phase 2: wave0 (t<64) builds W columns into LDS; wave1 builds V rows direct
    if (t < 64) {
        int n = t >> 1, ri = t & 1;
        float e = expf(-0.5f*dt);
        float s_, c_; sincosf(PI_F*dt*n, &s_, &c_);
        float wr = e*c_, wi = e*s_;
        float crn = cn[2*n], cin = cn[2*n+1];
        float pr = wr, pim = wi;                    // w^(m+1), m=0
        for (int m = 0; m < 128; m++) {
            float re = crn*pr - cin*pim;
            float im = crn*pim + cin*pr;
            s_w[m*66 + t] = f2bf(ri ? -im : re);
            float nr = pr*wr - pim*wi;
            float ni = pr*wi + pim*wr;
            pr = nr; pim = ni;
        }
    } else {
        int r = t - 64; int n = r >> 1, ri = r & 1;
        float e = expf(-0.5f*dt);
        float s_, c_; sincosf(PI_F*dt*n, &s_, &c_);
        float wr = e*c_, wi = e*s_;
        float cr2 = 1.f, ci2 = 0.f;                 // w^0
        for (int kb = 3; kb >= 0; kb--) {
            unsigned short buf[32];
            for (int kk = 31; kk >= 0; kk--) {
                buf[kk] = f2bf(ri ? ci2 : cr2);
                float nr = cr2*wr - ci2*wi;
                float ni = cr2*wi + ci2*wr;
                cr2 = nr; ci2 = ni;
            }
            uint4* dst = (uint4*)&VA[(((size_t)h*4 + kb)*64 + r)*32];
            uint4* src = (uint4*)buf;
            dst[0]=src[0]; dst[1]=src[1]; dst[2]=src[2]; dst[3]=src[3];
        }
    }
    __syncthreads();
    // prefix sum for BN shift
    {
        float acc = 0.f;
        for (int tau = 0; tau <= t; tau++) acc += sK[tau];
        rs[(size_t)h*128 + t] = acc;
    }
    // Toeplitz row t, buffered uint4 stores
    for (int kb = 0; kb < 4; kb++) {
        unsigned short tb[32];
#pragma unroll
        for (int kk = 0; kk < 32; kk++) {
            int col = kb*32 + kk;
            tb[kk] = f2bf((col <= t) ? sK[t - col] : 0.f);
        }
        uint4* dst = (uint4*)&TA[(((size_t)h*6 + kb)*128 + t)*32];
        uint4* src = (uint4*)tb;
        dst[0]=src[0]; dst[1]=src[1]; dst[2]=src[2]; dst[3]=src[3];
    }
    // W copy-out, coalesced: 1024 uint4 over kb'(2) x m(128) x kkg(4)
    for (int i = t; i < 1024; i += 128) {
        int kb = i >> 9;             // 0..1
        int rem = i & 511;
        int m = rem >> 2, kkg = rem & 3;
        *(uint4*)&TA[(((size_t)h*6 + 4 + kb)*128 + m)*32 + kkg*8] =
            *(const uint4*)&s_w[m*66 + kb*32 + kkg*8];
    }
}

// ---------------- S4 layer fused: V-GEMM + scan + T/W-GEMM in one kernel ----------
// Replaces s4ab_fused + s4_gemm_c. A block's 64 staged cols are exactly the chunk
// set its scan needs (layer a: 1 b x 64 chunks; layer b: 4 b x 16 chunks), and the
// V-GEMM B-operand is the SAME staged u -> read u once.
// Phases: stage u -> V-GEMM (wave wid: cols wid*16+nl; B-frag from s_u, 2-way
// conflict) -> in-place W^128 scan over sE (lane (bl,n) owns words 2n,2n+1 of its
// own cols) -> convert E->bf16 s_s (same f2bf as before -> identical Sini values)
// -> T-GEMM + W-GEMM + epilogue (verbatim).
template<int NCH, int LOGNCH>
__global__ __launch_bounds__(256) void s4_layer_fused(
    const unsigned short* __restrict__ u, const unsigned short* __restrict__ VA,
    const float* __restrict__ Vrs, const unsigned short* __restrict__ TA,
    const float* __restrict__ rs, const float* __restrict__ sc,
    const float* __restrict__ sh, const float* __restrict__ log_dt,
    unsigned short* __restrict__ yout)
{
    const int L = NCH * 128;
    __shared__ unsigned short s_u[64*200];   // 25600 B
    __shared__ unsigned short s_s[64*72];    // 9216 B
    __shared__ float sE[64*68];              // 17408 B  (total 52224 B)
    int h = blockIdx.y;
    int tid = threadIdx.x;
    int lane = tid & 63, wid = tid >> 6;
    int nl = lane & 15, g = lane >> 4;
    int col0 = blockIdx.x * 64;
    float scv = sc ? sc[h] : 1.f;
    float shv = sh ? sh[h] : 0.f;

    // stage u (once; serves both V-GEMM and T-GEMM)
    for (int i = tid; i < 1024; i += 256) {
        int cl = i >> 4, o = i & 15;
        int col = col0 + cl; int b = col >> LOGNCH, c = col & (NCH - 1);
        *(uint4*)&s_u[cl*200 + o*8] =
            *(const uint4*)&u[((size_t)h*16 + b)*L + c*128 + o*8];
    }
    __syncthreads();

    // V-GEMM: wave wid computes E for cols cl = wid*16 + nl (gemm_a math)
    {
        int cl = wid*16 + nl;
        f32x4 acc[4];
#pragma unroll
        for (int mt = 0; mt < 4; mt++) acc[mt] = (f32x4){0.f,0.f,0.f,0.f};
#pragma unroll
        for (int kb = 0; kb < 4; kb++) {
            short8 bf = *(const short8*)&s_u[cl*200 + kb*32 + g*8];
#pragma unroll
            for (int mt = 0; mt < 4; mt++) {
                short8 af = *(const short8*)(VA + (((size_t)h*4 + kb)*64 + mt*16 + nl)*32 + g*8);
                acc[mt] = __builtin_amdgcn_mfma_f32_16x16x32_bf16(af, bf, acc[mt], 0, 0, 0);
            }
        }
#pragma unroll
        for (int mt = 0; mt < 4; mt++) {
            int j0 = mt*16 + g*4;
            float4 vr = *(const float4*)(Vrs + (size_t)h*64 + j0);
            sE[cl*68 + j0 + 0] = fmaf(scv, acc[mt][0], shv*vr.x);
            sE[cl*68 + j0 + 1] = fmaf(scv, acc[mt][1], shv*vr.y);
            sE[cl*68 + j0 + 2] = fmaf(scv, acc[mt][2], shv*vr.z);
            sE[cl*68 + j0 + 3] = fmaf(scv, acc[mt][3], shv*vr.w);
        }
    }
    __syncthreads();

    // chunk scan (mid math): NB = b's per block; lane (bl,n) scans its b's chunks
    constexpr int NB = 64 / NCH;   // 1 (layer a) or 4 (layer b)
    if (tid < NB * 32) {
        int bl = tid >> 5, n = tid & 31;
        float dt = expf(log_dt[h]);
        float e = expf(-0.5f * dt);
        float s_, c_; sincosf(PI_F * dt * n, &s_, &c_);
        float Wr = e*c_, Wi = e*s_;
#pragma unroll
        for (int i = 0; i < 7; i++) { float r = Wr*Wr - Wi*Wi; float im = 2.f*Wr*Wi; Wr = r; Wi = im; }
        float Sr = 0.f, Si = 0.f;
        for (int c2 = 0; c2 < NCH; c2++) {
            float* ep = &sE[(bl*NCH + c2)*68 + 2*n];
            float er = ep[0], ei = ep[1];
            ep[0] = Sr; ep[1] = Si;          // Sini = state BEFORE chunk c2
            float r  = fmaf(Wr, Sr, fmaf(-Wi, Si, er));
            float im = fmaf(Wi, Sr, fmaf( Wr, Si, ei));
            Sr = r; Si = im;
        }
    }
    __syncthreads();

    // convert Sini (fp32 in sE) -> bf16 s_s (same f2bf as the old DRAM path)
    for (int i = tid*4; i < 4096; i += 1024) {
        int cl = i >> 6, j = i & 63;
        ushort4 q;
        q.x = f2bf(sE[cl*68 + j]);
        q.y = f2bf(sE[cl*68 + j+1]);
        q.z = f2bf(sE[cl*68 + j+2]);
        q.w = f2bf(sE[cl*68 + j+3]);
        *(ushort4*)&s_s[cl*72 + j] = q;
    }
    __syncthreads();

    // T-GEMM + W-GEMM + epilogue (verbatim from s4_gemm_c)
    f32x4 accT[2][4], accW[2][4];
#pragma unroll
    for (int a = 0; a < 2; a++)
#pragma unroll
        for (int j = 0; j < 4; j++) { accT[a][j] = (f32x4){0,0,0,0}; accW[a][j] = (f32x4){0,0,0,0}; }
#pragma unroll
    for (int kb = 0; kb < 4; kb++) {
        short8 bfr[4];
#pragma unroll
        for (int j = 0; j < 4; j++)
            bfr[j] = *(const short8*)&s_u[(j*16 + nl)*200 + kb*32 + g*8];
#pragma unroll
        for (int mt2 = 0; mt2 < 2; mt2++) {
            int mtile = wid*2 + mt2;
            short8 af = *(const short8*)&TA[(((size_t)h*6 + kb)*128 + mtile*16 + nl)*32 + g*8];
#pragma unroll
            for (int j = 0; j < 4; j++)
                accT[mt2][j] = __builtin_amdgcn_mfma_f32_16x16x32_bf16(af, bfr[j], accT[mt2][j], 0, 0, 0);
        }
    }
#pragma unroll
    for (int kw = 0; kw < 2; kw++) {
        short8 bfr[4];
#pragma unroll
        for (int j = 0; j < 4; j++)
            bfr[j] = *(const short8*)&s_s[(j*16 + nl)*72 + kw*32 + g*8];
#pragma unroll
        for (int mt2 = 0; mt2 < 2; mt2++) {
            int mtile = wid*2 + mt2;
            short8 af = *(const short8*)&TA[(((size_t)h*6 + 4 + kw)*128 + mtile*16 + nl)*32 + g*8];
#pragma unroll
            for (int j = 0; j < 4; j++)
                accW[mt2][j] = __builtin_amdgcn_mfma_f32_16x16x32_bf16(af, bfr[j], accW[mt2][j], 0, 0, 0);
        }
    }
#pragma unroll
    for (int mt2 = 0; mt2 < 2; mt2++) {
        int m0 = (wid*2 + mt2)*16 + g*4;
        float4 rsv = *(const float4*)&rs[(size_t)h*128 + m0];
#pragma unroll
        for (int j = 0; j < 4; j++) {
            int col = col0 + j*16 + nl; int b = col >> LOGNCH, c = col & (NCH - 1);
            ushort4 q;
            q.x = f2bf(fmaf(scv, accT[mt2][j][0], shv*rsv.x) + accW[mt2][j][0]);
            q.y = f2bf(fmaf(scv, accT[mt2][j][1], shv*rsv.y) + accW[mt2][j][1]);
            q.z = f2bf(fmaf(scv, accT[mt2][j][2], shv*rsv.z) + accW[mt2][j][2]);
            q.w = f2bf(fmaf(scv, accT[mt2][j][3], shv*rsv.w) + accW[mt2][j][3]);
            *(ushort4*)&yout[((size_t)h*16 + b)*L + c*128 + m0] = q;
        }
    }
}

// ---------------- fused 4-dilation conv block via MFMA (v8, unchanged) ----------------
template<int CIN, int TBLK>
__global__ __launch_bounds__(256, 2) void conv_mfma4(
    const unsigned short* __restrict__ u, const unsigned short* __restrict__ wp,
    const float* __restrict__ bs0, const float* __restrict__ bs1,
    const float* __restrict__ bs2, const float* __restrict__ bs3,
    unsigned short* __restrict__ out, int Lin, int Lout)
{
    constexpr int F     = TBLK / 16;
    constexpr int NPOS  = TBLK * 4 + 16;
    constexpr int Q     = NPOS / 4;
    constexpr int NITEM = (NPOS / 8) * 64;
    constexpr int NLD   = (NITEM + 255) / 256;
    constexpr int NCC   = CIN / 64;
    constexpr int NBUF  = (NCC > 1) ? 2 : 1;
    constexpr int BUFSZ = 4 * Q * 64;
    __shared__ unsigned short s_in[NBUF * BUFSZ];

    int tid = threadIdx.x;
    int lane = tid & 63, wid = tid >> 6;      // wid == dilation index d
    int nl = lane & 15, g = lane >> 4;
    int t0 = blockIdx.x * TBLK;
    int b  = blockIdx.y;
    int og = blockIdx.z * 64;
    const int P0 = t0 * 4 - 8;
    const int DIL = 1 << wid;                 // wave-uniform

    f32x4 acc[4][F];
#pragma unroll
    for (int m = 0; m < 4; m++)
#pragma unroll
        for (int f = 0; f < F; f++) acc[m][f] = (f32x4){0.f,0.f,0.f,0.f};

    uint4 stg[NLD];

    auto stage_load = [&](int ccbase) {
#pragma unroll
        for (int j = 0; j < NLD; j++) {
            int i = tid + 256 * j;
            uint4 v; v.x = 0u; v.y = 0u; v.z = 0u; v.w = 0u;
            if (i < NITEM) {
                int ch = i & 63, po = i >> 6;
                int p = P0 + po * 8;
                const unsigned short* gp = u + ((size_t)(ccbase + ch)*16 + b)*Lin;
                if (p >= 0 && p + 8 <= Lin) {
                    v = *(const uint4*)(gp + p);
                } else {
                    alignas(16) unsigned short t8[8];
#pragma unroll
                    for (int j2 = 0; j2 < 8; j2++) {
                        int pj = p + j2;
                        t8[j2] = ((unsigned)pj < (unsigned)Lin) ? gp[pj] : (unsigned short)0;
                    }
                    v = *(const uint4*)t8;
                }
            }
            stg[j] = v;
        }
    };
    auto stage_write = [&](int bufidx) {
        unsigned short* sb = s_in + bufidx * BUFSZ;
#pragma unroll
        for (int j = 0; j < NLD; j++) {
            int i = tid + 256 * j;
            if (i < NITEM) {
                int ch = i & 63, po = i >> 6;
                alignas(16) unsigned short t8[8];
                *(uint4*)t8 = stg[j];
#pragma unroll
                for (int jj = 0; jj < 8; jj++) {
                    int pl = po * 8 + jj;
                    int row = (pl & 3) * Q + (pl >> 2);
                    sb[row * 64 + (ch ^ ((row & 7) << 3))] = t8[jj];
                }
            }
        }
    };

    stage_load(0);
    stage_write(0);
    __syncthreads();

#pragma unroll
    for (int cc = 0; cc < NCC; cc++) {
        if (cc + 1 < NCC) stage_load((cc + 1) * 64);
        const unsigned short* sb = s_in + (NBUF > 1 ? (cc & 1) * BUFSZ : 0);
#pragma unroll
        for (int k = 0; k < 3; ++k) {
            const int off = (k - 1) * DIL + 8;
            const int r = off & 3, s = off >> 2;
#pragma unroll
            for (int chalf = 0; chalf < 2; ++chalf) {
                int kb = cc * 6 + k * 2 + chalf;
                short8 bfr[F];
#pragma unroll
                for (int f = 0; f < F; ++f) {
                    int q = f*16 + nl + s;
                    int row = r * Q + q;
                    bfr[f] = *(const short8*)&sb[row * 64 +
                        ((((chalf << 2) | g) ^ (row & 7)) << 3)];
                }
#pragma unroll
                for (int m = 0; m < 4; ++m) {
                    short8 afrag = *(const short8*)&wp[(size_t)wid*(3*CIN*CIN) +
                        ((size_t)kb*CIN + og + m*16 + nl)*32 + g*8];
#pragma unroll
                    for (int f = 0; f < F; ++f)
                        acc[m][f] = __builtin_amdgcn_mfma_f32_16x16x32_bf16(afrag, bfr[f], acc[m][f], 0, 0, 0);
                }
            }
        }
        if (cc + 1 < NCC) {
            __syncthreads();
            stage_write((cc + 1) & 1);
            __syncthreads();
        }
    }

    const float* bp = (wid == 0) ? bs0 : (wid == 1) ? bs1 : (wid == 2) ? bs2 : bs3;
#pragma unroll
    for (int m = 0; m < 4; ++m) {
#pragma unroll
        for (int f = 0; f < F; ++f) {
            int t = t0 + f*16 + nl;
#pragma unroll
            for (int r2 = 0; r2 < 4; ++r2) {
                int o = og + m*16 + g*4 + r2;
                float v = acc[m][f][r2] + bp[o];
                if (wid) v = v >= 0.f ? v : 0.3f*v;
                out[((size_t)(wid*CIN + o)*16 + b)*Lout + t] = f2bf(v);
            }
        }
    }
}

// ---------------- BN stats from bf16 [ch][b][t] ----------------
__global__ __launch_bounds__(256) void bn_stats(
    const unsigned short* __restrict__ x, const float* __restrict__ g,
    const float* __restrict__ bb, float* __restrict__ sc, float* __restrict__ sh,
    int n, int gmask)
{
    int ch = blockIdx.x;
    const unsigned short* xp = x + (size_t)ch * n;
    float s1 = 0.f, s2 = 0.f;
    for (int i = threadIdx.x*8; i < n; i += 2048) {
        uint4 raw = *(const uint4*)(xp + i);
        unsigned short us[8]; *(uint4*)us = raw;
#pragma unroll
        for (int j = 0; j < 8; j++) {
            float v = bf2f(us[j]);
            s1 += v; s2 += v*v;
        }
    }
    for (int o = 32; o > 0; o >>= 1) { s1 += __shfl_down(s1, o); s2 += __shfl_down(s2, o); }
    __shared__ float p1[4], p2[4];
    int wid = threadIdx.x >> 6;
    if ((threadIdx.x & 63) == 0) { p1[wid] = s1; p2[wid] = s2; }
    __syncthreads();
    if (threadIdx.x == 0) {
        s1 = p1[0] + p1[1] + p1[2] + p1[3];
        s2 = p2[0] + p2[1] + p2[2] + p2[3];
        float m = s1 / n;
        float var = s2 / n - m*m;
        float rstd = rsqrtf(var + 1e-5f);
        float scale = g[ch & gmask] * rstd;
        sc[ch] = scale;
        sh[ch] = fmaf(-m, scale, bb[ch & gmask]);
    }
}

// ---------------- s4c fused v2 (unchanged from v10) ----------
__global__ __launch_bounds__(64) void s4c_all(
    const unsigned short* __restrict__ u,
    const float* __restrict__ sc, const float* __restrict__ sh,
    const float* __restrict__ log_dt, const float* __restrict__ C2,
    const float* __restrict__ Dv, float* __restrict__ x3last)
{
    __shared__ float sE[64 * 68];              // 17408 B
    __shared__ float red[16 * 33];             // 2112 B
    __shared__ unsigned short sVA[4 * 64 * 32];// 16384 B
    __shared__ alignas(16) float sVrs[64];     // 256 B
    int h = blockIdx.x;
    int lane = threadIdx.x;
    int nl = lane & 15, g = lane >> 4;
    float scv = sc[h], shv = sh[h];
    float dt = expf(log_dt[h]);

    // build V rows + Vrs (prep_va math, LDS dest, chunk-swizzled)
    {
        int t = lane, n = t >> 1, ri = t & 1;
        float e = expf(-0.5f*dt);
        float s_, c_; sincosf(PI_F*dt*n, &s_, &c_);
        float wr = e*c_, wi = e*s_;
        float cr2 = 1.f, ci2 = 0.f;              // w^0 -> col 127
        int key = (t >> 1) & 3;
        for (int kb = 3; kb >= 0; kb--) {
            alignas(16) unsigned short buf[32];
            for (int kk = 31; kk >= 0; kk--) {
                buf[kk] = f2bf(ri ? ci2 : cr2);
                float nr = cr2*wr - ci2*wi;
                float ni = cr2*wi + ci2*wr;
                cr2 = nr; ci2 = ni;
            }
            uint4* dst = (uint4*)&sVA[(kb*64 + t)*32];
            uint4* src4 = (uint4*)buf;
#pragma unroll
            for (int cc = 0; cc < 4; cc++) dst[cc ^ key] = src4[cc];
        }
        if (ri == 0) {
            float e128 = expf(-64.f*dt);
            float s2, c2v; sincosf(PI_F*dt*n*128.f, &s2, &c2v);
            float pr = 1.f - e128*c2v, pim = -e128*s2;
            float dr = 1.f - wr, di = -wi;
            float dd = 1.f/(dr*dr + di*di);
            sVrs[2*n]   = (pr*dr + pim*di)*dd;
            sVrs[2*n+1] = (pim*dr - pr*di)*dd;
        }
    }
    __syncthreads();

    // phase 1: 4 col-groups x 16 MFMA = all 64 (b,c) columns for this h
    int rkey = (nl >> 1) & 3;
    for (int cg = 0; cg < 4; cg++) {
        int col = cg*16 + nl;
        int b = col >> 2, c = col & 3;
        const unsigned short* up = u + ((size_t)h*16 + b)*512 + c*128;
        f32x4 acc[4];
#pragma unroll
        for (int mt = 0; mt < 4; mt++) acc[mt] = (f32x4){0.f,0.f,0.f,0.f};
#pragma unroll
        for (int kb = 0; kb < 4; kb++) {
            short8 bf = *(const short8*)(up + kb*32 + g*8);
#pragma unroll
            for (int mt = 0; mt < 4; mt++) {
                short8 af = *(const short8*)&sVA[(kb*64 + mt*16 + nl)*32 + ((g ^ rkey) << 3)];
                acc[mt] = __builtin_amdgcn_mfma_f32_16x16x32_bf16(af, bf, acc[mt], 0, 0, 0);
            }
        }
#pragma unroll
        for (int mt = 0; mt < 4; mt++) {
            int j0 = mt*16 + g*4;
            float4 vr = *(const float4*)&sVrs[j0];
            sE[col*68 + j0 + 0] = fmaf(scv, acc[mt][0], shv*vr.x);
            sE[col*68 + j0 + 1] = fmaf(scv, acc[mt][1], shv*vr.y);
            sE[col*68 + j0 + 2] = fmaf(scv, acc[mt][2], shv*vr.z);
            sE[col*68 + j0 + 3] = fmaf(scv, acc[mt][3], shv*vr.w);
        }
    }
    __syncthreads();

    // phase 2+3 partials: lane = (n, bh); each handles 8 b's
    int n = lane >> 1, bh = lane & 1;
    float e = expf(-0.5f * dt);
    float s_, c_; sincosf(PI_F * dt * n, &s_, &c_);
    float wr = e*c_, wi = e*s_;
    float ar = -0.5f, ai = PI_F * n;
    float den = 1.f / (ar*ar + ai*ai);
    float tr = wr - 1.f, ti = wi;
    float qr = (tr*ar + ti*ai) * den;
    float qi = (ti*ar - tr*ai) * den;
    float c2r = C2[((size_t)h*32 + n)*2], c2i = C2[((size_t)h*32 + n)*2 + 1];
    float crv = c2r*qr - c2i*qi, civ = c2r*qi + c2i*qr;
    float Wr = wr, Wi = wi;
#pragma unroll
    for (int i = 0; i < 7; i++) { float r = Wr*Wr - Wi*Wi; float im = 2.f*Wr*Wi; Wr = r; Wi = im; }
#pragma unroll
    for (int b2 = 0; b2 < 8; b2++) {
        int b = bh*8 + b2;
        float Sr = 0.f, Si = 0.f;
#pragma unroll
        for (int c = 0; c < 4; c++) {
            int col = b*4 + c;
            float er = sE[col*68 + 2*n], ei = sE[col*68 + 2*n + 1];
            float r  = fmaf(Wr, Sr, fmaf(-Wi, Si, er));
            float im = fmaf(Wi, Sr, fmaf( Wr, Si, ei));
            Sr = r; Si = im;
        }
        red[b*33 + n] = crv*Sr - civ*Si;
    }
    __syncthreads();
    if (lane < 16) {
        int b = lane;
        float s = 0.f;
        for (int n2 = 0; n2 < 32; n2++) s += red[b*33 + n2];
        float uv = fmaf(scv, bf2f(u[((size_t)h*16 + b)*512 + 511]), shv);
        x3last[b*1024 + h] = 2.f*s + Dv[h]*uv;
    }
}

// ---------------- decoder head ----------------
__global__ __launch_bounds__(256) void dec_kernel(
    const float* __restrict__ x3last, const float* __restrict__ w1, const float* __restrict__ b1,
    const float* __restrict__ w2, const float* __restrict__ b2, float* __restrict__ out)
{
    __shared__ float xs[1024];
    int b = blockIdx.x, tid = threadIdx.x;
    for (int i = tid; i < 1024; i += 256) xs[i] = x3last[b*1024 + i];
    __syncthreads();
    float z = b1[tid];
    const float* wpt = w1 + (size_t)tid*1024;
    for (int i = 0; i < 1024; i += 4) {
        float4 wv = *(const float4*)(wpt + i);
        z = fmaf(wv.x, xs[i],   z);
        z = fmaf(wv.y, xs[i+1], z);
        z = fmaf(wv.z, xs[i+2], z);
        z = fmaf(wv.w, xs[i+3], z);
    }
    float v = w2[tid] * z;
    for (int o = 32; o > 0; o >>= 1) v += __shfl_down(v, o);
    __shared__ float ps[4];
    if ((tid & 63) == 0) ps[tid >> 6] = v;
    __syncthreads();
    if (tid == 0) out[b] = ps[0] + ps[1] + ps[2] + ps[3] + b2[0];
}

extern "C" void kernel_launch(void* const* d_in, const int* in_sizes, int n_in,
                              void* d_out, int out_size, void* d_ws, size_t ws_size,
                              hipStream_t stream)
{
    const float* x       = (const float*)d_in[0];
    const float* enc_w   = (const float*)d_in[1];
    const float* enc_b   = (const float*)d_in[2];
    const float* s4a_ldt = (const float*)d_in[3];
    const float* s4a_C   = (const float*)d_in[4];
    const float* s4a_D   = (const float*)d_in[5];
    const float* s4b_ldt = (const float*)d_in[6];
    const float* s4b_C   = (const float*)d_in[7];
    const float* s4b_D   = (const float*)d_in[8];
    const float* s4c_ldt = (const float*)d_in[9];
    const float* s4c_C   = (const float*)d_in[10];
    const float* s4c_D   = (const float*)d_in[11];
    const float* b1w[4] = {(const float*)d_in[12], (const float*)d_in[14], (const float*)d_in[16], (const float*)d_in[18]};
    const float* b1b[4] = {(const float*)d_in[13], (const float*)d_in[15], (const float*)d_in[17], (const float*)d_in[19]};
    const float* b2w[4] = {(const float*)d_in[20], (const float*)d_in[22], (const float*)d_in[24], (const float*)d_in[26]};
    const float* b2b[4] = {(const float*)d_in[21], (const float*)d_in[23], (const float*)d_in[25], (const float*)d_in[27]};
    const float* bn1_g  = (const float*)d_in[28];
    const float* bn1_b  = (const float*)d_in[29];
    const float* bn2_g  = (const float*)d_in[30];
    const float* bn2_b  = (const float*)d_in[31];
    const float* dec1_w = (const float*)d_in[32];
    const float* dec1_b = (const float*)d_in[33];
    const float* dec2_w = (const float*)d_in[34];
    const float* dec2_b = (const float*)d_in[35];
    float* out = (float*)d_out;

    char* ws = (char*)d_ws;
    unsigned short* u1    = (unsigned short*)(ws);              // 16.8 MB (also u3)
    unsigned short* u3    = u1;
    unsigned short* ya    = (unsigned short*)(ws + 16777216);   // 16.8 MB (also yb)
    unsigned short* yb    = ya;
    unsigned short* u2    = (unsigned short*)(ws + 33554432);   // 16.8 MB
    unsigned short* wprep = (unsigned short*)(ws + 88080384);   // 1.67 MB
    unsigned short* TA_a  = (unsigned short*)(ws + 89751552);   // 3.15 MB
    unsigned short* TA_b  = (unsigned short*)(ws + 92897280);   // 12.6 MB
    unsigned short* VA_a  = (unsigned short*)(ws + 105480192);  // 1.05 MB
    unsigned short* VA_b  = (unsigned short*)(ws + 106528768);  // 4.2 MB
    float*          rs_a  = (float*)(ws + 110723072);           // 32 KB
    float*          rs_b  = (float*)(ws + 110755840);           // 128 KB
    float*          Vrs_a = (float*)(ws + 110886912);           // 16 KB
    float*          Vrs_b = (float*)(ws + 110903296);           // 64 KB
    float*          smallp= (float*)(ws + 110968832);
    float* sc1 = smallp;         // 256
    float* sh1 = smallp + 256;   // 256
    float* sc2 = smallp + 512;   // 1024
    float* sh2 = smallp + 1536;  // 1024
    float* x3l = smallp + 2560;  // 16384

    // prep (independent of data path)
    prep_w<<<dim3(768, 8), 256, 0, stream>>>(b1w[0], b1w[1], b1w[2], b1w[3],
                                             b2w[0], b2w[1], b2w[2], b2w[3], wprep);
    prep_s4<<<64, 128, 0, stream>>>(s4a_ldt, s4a_C, s4a_D, TA_a, VA_a, rs_a, Vrs_a);
    prep_s4<<<256, 128, 0, stream>>>(s4b_ldt, s4b_C, s4b_D, TA_b, VA_b, rs_b, Vrs_b);

    // encoder -> u1 bf16
    enc_kernel<<<8192, 256, 0, stream>>>(x, enc_w, enc_b, u1);

    // s4a: H=64, NCH=64 (L=8192) -- single fused kernel (V-GEMM+scan+T/W-GEMM)
    s4_layer_fused<64,6><<<dim3(16, 64), 256, 0, stream>>>(
        u1, VA_a, Vrs_a, TA_a, rs_a, nullptr, nullptr, s4a_ldt, ya);

    // conv block1 (fused 4 dilations): ya [64][16][8192] -> u2 [256][16][2048]
    conv_mfma4<64,32><<<dim3(64, 16, 1), 256, 0, stream>>>(
        ya, wprep, b1b[0], b1b[1], b1b[2], b1b[3], u2, 8192, 2048);
    bn_stats<<<256, 256, 0, stream>>>(u2, bn1_g, bn1_b, sc1, sh1, 16*2048, 63);

    // s4b: H=256, NCH=16 (L=2048) -- single fused kernel
    s4_layer_fused<16,4><<<dim3(4, 256), 256, 0, stream>>>(
        u2, VA_b, Vrs_b, TA_b, rs_b, sc1, sh1, s4b_ldt, yb);

    // conv block2 (fused 4 dilations): yb [256][16][2048] -> u3 [1024][16][512]
    conv_mfma4<256,64><<<dim3(8, 16, 4), 256, 0, stream>>>(
        yb, wprep + 49152, b2b[0], b2b[1], b2b[2], b2b[3], u3, 2048, 512);
    bn_stats<<<1024, 256, 0, stream>>>(u3, bn2_g, bn2_b, sc2, sh2, 16*512, 255);

    // s4c fused v2: in-LDS V build + GEMM + scan + reduction
    s4c_all<<<1024, 64, 0, stream>>>(u3, sc2, sh2, s4c_ldt, s4c_C, s4c_D, x3l);

    // decoder head
    dec_kernel<<<16, 256, 0, stream>>>(x3l, dec1_w, dec1_b, dec2_w, dec2_b, out);
}

// Round 13
// 302.423 us; speedup vs baseline: 1.4900x; 1.0769x over previous
//
#include <hip/hip_runtime.h>
#include <math.h>

#define PI_F 3.14159265358979323846f

typedef __attribute__((ext_vector_type(8))) short short8;
typedef __attribute__((ext_vector_type(4))) float f32x4;

__device__ __forceinline__ unsigned short f2bf(float f) {
    unsigned int u = __float_as_uint(f);
    unsigned int r = (u + 0x7fffu + ((u >> 16) & 1u)) >> 16;
    return (unsigned short)r;
}
__device__ __forceinline__ float bf2f(unsigned short v) {
    return __uint_as_float((unsigned int)v << 16);
}

// ---------------- conv weight prep: fp32 [O][Cin][3] -> bf16 A-frag [kb][o][kk] ------
__global__ __launch_bounds__(256) void prep_w(
    const float* __restrict__ w0, const float* __restrict__ w1,
    const float* __restrict__ w2, const float* __restrict__ w3,
    const float* __restrict__ w4, const float* __restrict__ w5,
    const float* __restrict__ w6, const float* __restrict__ w7,
    unsigned short* __restrict__ wprep)
{
    int id = blockIdx.y;
    const float* src; int Cin; size_t doff;
    switch (id) {
        case 0: src = w0; Cin = 64;  doff = 0;      break;
        case 1: src = w1; Cin = 64;  doff = 12288;  break;
        case 2: src = w2; Cin = 64;  doff = 24576;  break;
        case 3: src = w3; Cin = 64;  doff = 36864;  break;
        case 4: src = w4; Cin = 256; doff = 49152;  break;
        case 5: src = w5; Cin = 256; doff = 245760; break;
        case 6: src = w6; Cin = 256; doff = 442368; break;
        default: src = w7; Cin = 256; doff = 638976; break;
    }
    int e = blockIdx.x * 256 + threadIdx.x;
    if (e >= Cin * Cin * 3) return;
    int kb  = e / (Cin * 32);
    int rem = e - kb * (Cin * 32);
    int o   = rem >> 5;
    int kk  = rem & 31;
    int cch = kb / 6, t6 = kb % 6, k = t6 >> 1, chalf = t6 & 1;
    int c = cch * 64 + chalf * 32 + kk;
    wprep[doff + e] = f2bf(src[((size_t)o * Cin + c) * 3 + k]);
}

// ---------------- S4 prep (both layers in one launch): per-h MFMA A-matrices --------
// blocks 0..63 -> layer a (h=bid), blocks 64..319 -> layer b (h=bid-64).
__global__ __launch_bounds__(128) void prep_s4_both(
    const float* __restrict__ ldt_a, const float* __restrict__ C2_a,
    const float* __restrict__ Dv_a,
    unsigned short* __restrict__ TA_a, unsigned short* __restrict__ VA_a,
    float* __restrict__ rs_a, float* __restrict__ Vrs_a,
    const float* __restrict__ ldt_b, const float* __restrict__ C2_b,
    const float* __restrict__ Dv_b,
    unsigned short* __restrict__ TA_b, unsigned short* __restrict__ VA_b,
    float* __restrict__ rs_b, float* __restrict__ Vrs_b)
{
    int bid = blockIdx.x, t = threadIdx.x;
    const float* log_dt; const float* C2; const float* Dv;
    unsigned short* TA; unsigned short* VA; float* rs; float* Vrs; int h;
    if (bid < 64) { h = bid;      log_dt = ldt_a; C2 = C2_a; Dv = Dv_a; TA = TA_a; VA = VA_a; rs = rs_a; Vrs = Vrs_a; }
    else          { h = bid - 64; log_dt = ldt_b; C2 = C2_b; Dv = Dv_b; TA = TA_b; VA = VA_b; rs = rs_b; Vrs = Vrs_b; }
    __shared__ float cn[64];
    __shared__ float sK[128];
    __shared__ unsigned short s_w[128 * 66];   // W staged [m][j], pad 66
    float dt = expf(log_dt[h]);
    if (t < 32) {
        int n = t;
        float e = expf(-0.5f*dt);
        float s_, c_; sincosf(PI_F*dt*n, &s_, &c_);
        float wr = e*c_, wi = e*s_;
        float ar = -0.5f, ai = PI_F*n;
        float den = 1.f/(ar*ar + ai*ai);
        float tr = wr - 1.f, ti = wi;
        float qr = (tr*ar + ti*ai)*den;
        float qi = (ti*ar - tr*ai)*den;
        float c2r = C2[((size_t)h*32+n)*2], c2i = C2[((size_t)h*32+n)*2+1];
        cn[2*n]   = 2.f*(c2r*qr - c2i*qi);
        cn[2*n+1] = 2.f*(c2r*qi + c2i*qr);
        // Vrs = sum_{j=0}^{127} w^j = (1 - w^128)/(1 - w)
        float e128 = expf(-64.f*dt);
        float s2, c2v; sincosf(PI_F*dt*n*128.f, &s2, &c2v);
        float pr = 1.f - e128*c2v, pim = -e128*s2;
        float dr = 1.f - wr, di = -wi;
        float dd = 1.f/(dr*dr + di*di);
        Vrs[(size_t)h*64 + 2*n]   = (pr*dr + pim*di)*dd;
        Vrs[(size_t)h*64 + 2*n+1] = (pim*dr - pr*di)*dd;
    }
    __syncthreads();
    // phase 1: K[t]
    {
        float em = expf(-0.5f*dt*t);
        float Kt = 0.f;
        for (int n = 0; n < 32; n++) {
            float s_, c_; sincosf(PI_F*dt*(float)(n*t), &s_, &c_);
            Kt += cn[2*n]*em*c_ - cn[2*n+1]*em*s_;
        }
        sK[t] = Kt + (t == 0 ? Dv[h] : 0.f);
    }
    // phase 2: wave0 builds W columns into LDS; wave1 builds V rows direct
    if (t < 64) {
        int n = t >> 1, ri = t & 1;
        float e = expf(-0.5f*dt);
        float s_, c_; sincosf(PI_F*dt*n, &s_, &c_);
        float wr = e*c_, wi = e*s_;
        float crn = cn[2*n], cin = cn[2*n+1];
        float pr = wr, pim = wi;                    // w^(m+1), m=0
        for (int m = 0; m < 128; m++) {
            float re = crn*pr - cin*pim;
            float im = crn*pim + cin*pr;
            s_w[m*66 + t] = f2bf(ri ? -im : re);
            float nr = pr*wr - pim*wi;
            float ni = pr*wi + pim*wr;
            pr = nr; pim = ni;
        }
    } else {
        int r = t - 64; int n = r >> 1, ri = r & 1;
        float e = expf(-0.5f*dt);
        float s_, c_; sincosf(PI_F*dt*n, &s_, &c_);
        float wr = e*c_, wi = e*s_;
        float cr2 = 1.f, ci2 = 0.f;                 // w^0
        for (int kb = 3; kb >= 0; kb--) {
            unsigned short buf[32];
            for (int kk = 31; kk >= 0; kk--) {
                buf[kk] = f2bf(ri ? ci2 : cr2);
                float nr = cr2*wr - ci2*wi;
                float ni = cr2*wi + ci2*wr;
                cr2 = nr; ci2 = ni;
            }
            uint4* dst = (uint4*)&VA[(((size_t)h*4 + kb)*64 + r)*32];
            uint4* src = (uint4*)buf;
            dst[0]=src[0]; dst[1]=src[1]; dst[2]=src[2]; dst[3]=src[3];
        }
    }
    __syncthreads();
    // prefix sum for BN shift
    {
        float acc = 0.f;
        for (int tau = 0; tau <= t; tau++) acc += sK[tau];
        rs[(size_t)h*128 + t] = acc;
    }
    // Toeplitz row t
    for (int kb = 0; kb < 4; kb++) {
        unsigned short tb[32];
#pragma unroll
        for (int kk = 0; kk < 32; kk++) {
            int col = kb*32 + kk;
            tb[kk] = f2bf((col <= t) ? sK[t - col] : 0.f);
        }
        uint4* dst = (uint4*)&TA[(((size_t)h*6 + kb)*128 + t)*32];
        uint4* src = (uint4*)tb;
        dst[0]=src[0]; dst[1]=src[1]; dst[2]=src[2]; dst[3]=src[3];
    }
    // W copy-out
    for (int i = t; i < 1024; i += 128) {
        int kb = i >> 9;
        int rem = i & 511;
        int m = rem >> 2, kkg = rem & 3;
        *(uint4*)&TA[(((size_t)h*6 + 4 + kb)*128 + m)*32 + kkg*8] =
            *(const uint4*)&s_w[m*66 + kb*32 + kkg*8];
    }
}

// ---------------- S4 layer fused: [enc] + V-GEMM + scan + T/W-GEMM ------------------
// ENC=true (layer a): stage u by applying the encoder affine to x inline
// (identical fmaf+f2bf -> bit-identical u values); u1 never exists in DRAM.
template<int NCH, int LOGNCH, bool ENC>
__global__ __launch_bounds__(256) void s4_layer_fused(
    const unsigned short* __restrict__ u, const float* __restrict__ xg,
    const float* __restrict__ ew, const float* __restrict__ ebv,
    const unsigned short* __restrict__ VA,
    const float* __restrict__ Vrs, const unsigned short* __restrict__ TA,
    const float* __restrict__ rs, const float* __restrict__ sc,
    const float* __restrict__ sh, const float* __restrict__ log_dt,
    unsigned short* __restrict__ yout)
{
    const int L = NCH * 128;
    __shared__ unsigned short s_u[64*200];   // 25600 B
    __shared__ unsigned short s_s[64*72];    // 9216 B
    __shared__ float sE[64*68];              // 17408 B  (total 52224 B)
    int h = blockIdx.y;
    int tid = threadIdx.x;
    int lane = tid & 63, wid = tid >> 6;
    int nl = lane & 15, g = lane >> 4;
    int col0 = blockIdx.x * 64;
    float scv = sc ? sc[h] : 1.f;
    float shv = sh ? sh[h] : 0.f;

    // stage u (once; serves V-GEMM and T-GEMM)
    if constexpr (ENC) {
        float w0e = ew[2*h], w1e = ew[2*h+1], bbe = ebv[h];
        for (int i = tid; i < 1024; i += 256) {
            int cl = i >> 4, o = i & 15;
            int col = col0 + cl; int b = col >> LOGNCH, c = col & (NCH - 1);
            const float* xp = xg + ((size_t)b*8192 + (size_t)(c*128 + o*8))*2;
            float4 a0 = *(const float4*)xp;
            float4 a1 = *(const float4*)(xp + 4);
            float4 a2 = *(const float4*)(xp + 8);
            float4 a3 = *(const float4*)(xp + 12);
            ushort4 q0, q1;
            q0.x = f2bf(fmaf(w0e, a0.x, fmaf(w1e, a0.y, bbe)));
            q0.y = f2bf(fmaf(w0e, a0.z, fmaf(w1e, a0.w, bbe)));
            q0.z = f2bf(fmaf(w0e, a1.x, fmaf(w1e, a1.y, bbe)));
            q0.w = f2bf(fmaf(w0e, a1.z, fmaf(w1e, a1.w, bbe)));
            q1.x = f2bf(fmaf(w0e, a2.x, fmaf(w1e, a2.y, bbe)));
            q1.y = f2bf(fmaf(w0e, a2.z, fmaf(w1e, a2.w, bbe)));
            q1.z = f2bf(fmaf(w0e, a3.x, fmaf(w1e, a3.y, bbe)));
            q1.w = f2bf(fmaf(w0e, a3.z, fmaf(w1e, a3.w, bbe)));
            *(ushort4*)&s_u[cl*200 + o*8]     = q0;
            *(ushort4*)&s_u[cl*200 + o*8 + 4] = q1;
        }
    } else {
        for (int i = tid; i < 1024; i += 256) {
            int cl = i >> 4, o = i & 15;
            int col = col0 + cl; int b = col >> LOGNCH, c = col & (NCH - 1);
            *(uint4*)&s_u[cl*200 + o*8] =
                *(const uint4*)&u[((size_t)h*16 + b)*L + c*128 + o*8];
        }
    }
    __syncthreads();

    // V-GEMM: wave wid computes E for cols cl = wid*16 + nl (gemm_a math)
    {
        int cl = wid*16 + nl;
        f32x4 acc[4];
#pragma unroll
        for (int mt = 0; mt < 4; mt++) acc[mt] = (f32x4){0.f,0.f,0.f,0.f};
#pragma unroll
        for (int kb = 0; kb < 4; kb++) {
            short8 bf = *(const short8*)&s_u[cl*200 + kb*32 + g*8];
#pragma unroll
            for (int mt = 0; mt < 4; mt++) {
                short8 af = *(const short8*)(VA + (((size_t)h*4 + kb)*64 + mt*16 + nl)*32 + g*8);
                acc[mt] = __builtin_amdgcn_mfma_f32_16x16x32_bf16(af, bf, acc[mt], 0, 0, 0);
            }
        }
#pragma unroll
        for (int mt = 0; mt < 4; mt++) {
            int j0 = mt*16 + g*4;
            float4 vr = *(const float4*)(Vrs + (size_t)h*64 + j0);
            sE[cl*68 + j0 + 0] = fmaf(scv, acc[mt][0], shv*vr.x);
            sE[cl*68 + j0 + 1] = fmaf(scv, acc[mt][1], shv*vr.y);
            sE[cl*68 + j0 + 2] = fmaf(scv, acc[mt][2], shv*vr.z);
            sE[cl*68 + j0 + 3] = fmaf(scv, acc[mt][3], shv*vr.w);
        }
    }
    __syncthreads();

    // chunk scan (mid math)
    constexpr int NB = 64 / NCH;   // 1 (layer a) or 4 (layer b)
    if (tid < NB * 32) {
        int bl = tid >> 5, n = tid & 31;
        float dt = expf(log_dt[h]);
        float e = expf(-0.5f * dt);
        float s_, c_; sincosf(PI_F * dt * n, &s_, &c_);
        float Wr = e*c_, Wi = e*s_;
#pragma unroll
        for (int i = 0; i < 7; i++) { float r = Wr*Wr - Wi*Wi; float im = 2.f*Wr*Wi; Wr = r; Wi = im; }
        float Sr = 0.f, Si = 0.f;
        for (int c2 = 0; c2 < NCH; c2++) {
            float* ep = &sE[(bl*NCH + c2)*68 + 2*n];
            float er = ep[0], ei = ep[1];
            ep[0] = Sr; ep[1] = Si;          // Sini = state BEFORE chunk c2
            float r  = fmaf(Wr, Sr, fmaf(-Wi, Si, er));
            float im = fmaf(Wi, Sr, fmaf( Wr, Si, ei));
            Sr = r; Si = im;
        }
    }
    __syncthreads();

    // convert Sini (fp32 in sE) -> bf16 s_s
    for (int i = tid*4; i < 4096; i += 1024) {
        int cl = i >> 6, j = i & 63;
        ushort4 q;
        q.x = f2bf(sE[cl*68 + j]);
        q.y = f2bf(sE[cl*68 + j+1]);
        q.z = f2bf(sE[cl*68 + j+2]);
        q.w = f2bf(sE[cl*68 + j+3]);
        *(ushort4*)&s_s[cl*72 + j] = q;
    }
    __syncthreads();

    // T-GEMM + W-GEMM + epilogue
    f32x4 accT[2][4], accW[2][4];
#pragma unroll
    for (int a = 0; a < 2; a++)
#pragma unroll
        for (int j = 0; j < 4; j++) { accT[a][j] = (f32x4){0,0,0,0}; accW[a][j] = (f32x4){0,0,0,0}; }
#pragma unroll
    for (int kb = 0; kb < 4; kb++) {
        short8 bfr[4];
#pragma unroll
        for (int j = 0; j < 4; j++)
            bfr[j] = *(const short8*)&s_u[(j*16 + nl)*200 + kb*32 + g*8];
#pragma unroll
        for (int mt2 = 0; mt2 < 2; mt2++) {
            int mtile = wid*2 + mt2;
            short8 af = *(const short8*)&TA[(((size_t)h*6 + kb)*128 + mtile*16 + nl)*32 + g*8];
#pragma unroll
            for (int j = 0; j < 4; j++)
                accT[mt2][j] = __builtin_amdgcn_mfma_f32_16x16x32_bf16(af, bfr[j], accT[mt2][j], 0, 0, 0);
        }
    }
#pragma unroll
    for (int kw = 0; kw < 2; kw++) {
        short8 bfr[4];
#pragma unroll
        for (int j = 0; j < 4; j++)
            bfr[j] = *(const short8*)&s_s[(j*16 + nl)*72 + kw*32 + g*8];
#pragma unroll
        for (int mt2 = 0; mt2 < 2; mt2++) {
            int mtile = wid*2 + mt2;
            short8 af = *(const short8*)&TA[(((size_t)h*6 + 4 + kw)*128 + mtile*16 + nl)*32 + g*8];
#pragma unroll
            for (int j = 0; j < 4; j++)
                accW[mt2][j] = __builtin_amdgcn_mfma_f32_16x16x32_bf16(af, bfr[j], accW[mt2][j], 0, 0, 0);
        }
    }
#pragma unroll
    for (int mt2 = 0; mt2 < 2; mt2++) {
        int m0 = (wid*2 + mt2)*16 + g*4;
        float4 rsv = *(const float4*)&rs[(size_t)h*128 + m0];
#pragma unroll
        for (int j = 0; j < 4; j++) {
            int col = col0 + j*16 + nl; int b = col >> LOGNCH, c = col & (NCH - 1);
            ushort4 q;
            q.x = f2bf(fmaf(scv, accT[mt2][j][0], shv*rsv.x) + accW[mt2][j][0]);
            q.y = f2bf(fmaf(scv, accT[mt2][j][1], shv*rsv.y) + accW[mt2][j][1]);
            q.z = f2bf(fmaf(scv, accT[mt2][j][2], shv*rsv.z) + accW[mt2][j][2]);
            q.w = f2bf(fmaf(scv, accT[mt2][j][3], shv*rsv.w) + accW[mt2][j][3]);
            *(ushort4*)&yout[((size_t)h*16 + b)*L + c*128 + m0] = q;
        }
    }
}

// ---------------- fused 4-dilation conv block via MFMA (v8, unchanged) ----------------
template<int CIN, int TBLK>
__global__ __launch_bounds__(256, 2) void conv_mfma4(
    const unsigned short* __restrict__ u, const unsigned short* __restrict__ wp,
    const float* __restrict__ bs0, const float* __restrict__ bs1,
    const float* __restrict__ bs2, const float* __restrict__ bs3,
    unsigned short* __restrict__ out, int Lin, int Lout)
{
    constexpr int F     = TBLK / 16;
    constexpr int NPOS  = TBLK * 4 + 16;
    constexpr int Q     = NPOS / 4;
    constexpr int NITEM = (NPOS / 8) * 64;
    constexpr int NLD   = (NITEM + 255) / 256;
    constexpr int NCC   = CIN / 64;
    constexpr int NBUF  = (NCC > 1) ? 2 : 1;
    constexpr int BUFSZ = 4 * Q * 64;
    __shared__ unsigned short s_in[NBUF * BUFSZ];

    int tid = threadIdx.x;
    int lane = tid & 63, wid = tid >> 6;      // wid == dilation index d
    int nl = lane & 15, g = lane >> 4;
    int t0 = blockIdx.x * TBLK;
    int b  = blockIdx.y;
    int og = blockIdx.z * 64;
    const int P0 = t0 * 4 - 8;
    const int DIL = 1 << wid;                 // wave-uniform

    f32x4 acc[4][F];
#pragma unroll
    for (int m = 0; m < 4; m++)
#pragma unroll
        for (int f = 0; f < F; f++) acc[m][f] = (f32x4){0.f,0.f,0.f,0.f};

    uint4 stg[NLD];

    auto stage_load = [&](int ccbase) {
#pragma unroll
        for (int j = 0; j < NLD; j++) {
            int i = tid + 256 * j;
            uint4 v; v.x = 0u; v.y = 0u; v.z = 0u; v.w = 0u;
            if (i < NITEM) {
                int ch = i & 63, po = i >> 6;
                int p = P0 + po * 8;
                const unsigned short* gp = u + ((size_t)(ccbase + ch)*16 + b)*Lin;
                if (p >= 0 && p + 8 <= Lin) {
                    v = *(const uint4*)(gp + p);
                } else {
                    alignas(16) unsigned short t8[8];
#pragma unroll
                    for (int j2 = 0; j2 < 8; j2++) {
                        int pj = p + j2;
                        t8[j2] = ((unsigned)pj < (unsigned)Lin) ? gp[pj] : (unsigned short)0;
                    }
                    v = *(const uint4*)t8;
                }
            }
            stg[j] = v;
        }
    };
    auto stage_write = [&](int bufidx) {
        unsigned short* sb = s_in + bufidx * BUFSZ;
#pragma unroll
        for (int j = 0; j < NLD; j++) {
            int i = tid + 256 * j;
            if (i < NITEM) {
                int ch = i & 63, po = i >> 6;
                alignas(16) unsigned short t8[8];
                *(uint4*)t8 = stg[j];
#pragma unroll
                for (int jj = 0; jj < 8; jj++) {
                    int pl = po * 8 + jj;
                    int row = (pl & 3) * Q + (pl >> 2);
                    sb[row * 64 + (ch ^ ((row & 7) << 3))] = t8[jj];
                }
            }
        }
    };

    stage_load(0);
    stage_write(0);
    __syncthreads();

#pragma unroll
    for (int cc = 0; cc < NCC; cc++) {
        if (cc + 1 < NCC) stage_load((cc + 1) * 64);
        const unsigned short* sb = s_in + (NBUF > 1 ? (cc & 1) * BUFSZ : 0);
#pragma unroll
        for (int k = 0; k < 3; ++k) {
            const int off = (k - 1) * DIL + 8;
            const int r = off & 3, s = off >> 2;
#pragma unroll
            for (int chalf = 0; chalf < 2; ++chalf) {
                int kb = cc * 6 + k * 2 + chalf;
                short8 bfr[F];
#pragma unroll
                for (int f = 0; f < F; ++f) {
                    int q = f*16 + nl + s;
                    int row = r * Q + q;
                    bfr[f] = *(const short8*)&sb[row * 64 +
                        ((((chalf << 2) | g) ^ (row & 7)) << 3)];
                }
#pragma unroll
                for (int m = 0; m < 4; ++m) {
                    short8 afrag = *(const short8*)&wp[(size_t)wid*(3*CIN*CIN) +
                        ((size_t)kb*CIN + og + m*16 + nl)*32 + g*8];
#pragma unroll
                    for (int f = 0; f < F; ++f)
                        acc[m][f] = __builtin_amdgcn_mfma_f32_16x16x32_bf16(afrag, bfr[f], acc[m][f], 0, 0, 0);
                }
            }
        }
        if (cc + 1 < NCC) {
            __syncthreads();
            stage_write((cc + 1) & 1);
            __syncthreads();
        }
    }

    const float* bp = (wid == 0) ? bs0 : (wid == 1) ? bs1 : (wid == 2) ? bs2 : bs3;
#pragma unroll
    for (int m = 0; m < 4; ++m) {
#pragma unroll
        for (int f = 0; f < F; ++f) {
            int t = t0 + f*16 + nl;
#pragma unroll
            for (int r2 = 0; r2 < 4; ++r2) {
                int o = og + m*16 + g*4 + r2;
                float v = acc[m][f][r2] + bp[o];
                if (wid) v = v >= 0.f ? v : 0.3f*v;
                out[((size_t)(wid*CIN + o)*16 + b)*Lout + t] = f2bf(v);
            }
        }
    }
}

// ---------------- BN stats from bf16 [ch][b][t] ----------------
__global__ __launch_bounds__(256) void bn_stats(
    const unsigned short* __restrict__ x, const float* __restrict__ g,
    const float* __restrict__ bb, float* __restrict__ sc, float* __restrict__ sh,
    int n, int gmask)
{
    int ch = blockIdx.x;
    const unsigned short* xp = x + (size_t)ch * n;
    float s1 = 0.f, s2 = 0.f;
    for (int i = threadIdx.x*8; i < n; i += 2048) {
        uint4 raw = *(const uint4*)(xp + i);
        unsigned short us[8]; *(uint4*)us = raw;
#pragma unroll
        for (int j = 0; j < 8; j++) {
            float v = bf2f(us[j]);
            s1 += v; s2 += v*v;
        }
    }
    for (int o = 32; o > 0; o >>= 1) { s1 += __shfl_down(s1, o); s2 += __shfl_down(s2, o); }
    __shared__ float p1[4], p2[4];
    int wid = threadIdx.x >> 6;
    if ((threadIdx.x & 63) == 0) { p1[wid] = s1; p2[wid] = s2; }
    __syncthreads();
    if (threadIdx.x == 0) {
        s1 = p1[0] + p1[1] + p1[2] + p1[3];
        s2 = p2[0] + p2[1] + p2[2] + p2[3];
        float m = s1 / n;
        float var = s2 / n - m*m;
        float rstd = rsqrtf(var + 1e-5f);
        float scale = g[ch & gmask] * rstd;
        sc[ch] = scale;
        sh[ch] = fmaf(-m, scale, bb[ch & gmask]);
    }
}

// ---------------- s4c fused v3: 256 threads; parallel V build over kb --------------
// V[t][col] = w^(127-col): thread (t, kb) starts at w^(96-32*kb) (computed directly
// via expf/sincosf -- analytically identical to the sequential start) and runs the
// same 32-step recurrence. Phase 1 runs its 4 col-groups on 4 waves in parallel.
__global__ __launch_bounds__(256) void s4c_all(
    const unsigned short* __restrict__ u,
    const float* __restrict__ sc, const float* __restrict__ sh,
    const float* __restrict__ log_dt, const float* __restrict__ C2,
    const float* __restrict__ Dv, float* __restrict__ x3last)
{
    __shared__ float sE[64 * 68];              // 17408 B
    __shared__ float red[16 * 33];             // 2112 B
    __shared__ unsigned short sVA[4 * 64 * 32];// 16384 B
    __shared__ alignas(16) float sVrs[64];     // 256 B
    int h = blockIdx.x;
    int tid = threadIdx.x;
    int lane = tid & 63, wid = tid >> 6;
    int nl = lane & 15, g = lane >> 4;
    float scv = sc[h], shv = sh[h];
    float dt = expf(log_dt[h]);

    // build V rows + Vrs: thread (t=lane, kb=wid) builds 32 cols (chunk-swizzled)
    {
        int t = lane, n = t >> 1, ri = t & 1;
        int kb = wid;
        float e = expf(-0.5f*dt);
        float s_, c_; sincosf(PI_F*dt*n, &s_, &c_);
        float wr = e*c_, wi = e*s_;
        int e0 = 96 - kb*32;                     // exponent at (kb, kk=31)
        float em0 = expf(-0.5f*dt*(float)e0);
        float s0, c0; sincosf(PI_F*dt*(float)n*(float)e0, &s0, &c0);
        float cr2 = em0*c0, ci2 = em0*s0;        // w^e0 (e0=0 -> 1,0)
        alignas(16) unsigned short buf[32];
        for (int kk = 31; kk >= 0; kk--) {
            buf[kk] = f2bf(ri ? ci2 : cr2);
            float nr = cr2*wr - ci2*wi;
            float ni = cr2*wi + ci2*wr;
            cr2 = nr; ci2 = ni;
        }
        int key = (t >> 1) & 3;
        uint4* dst = (uint4*)&sVA[(kb*64 + t)*32];
        uint4* src4 = (uint4*)buf;
#pragma unroll
        for (int cc = 0; cc < 4; cc++) dst[cc ^ key] = src4[cc];
        if (wid == 0 && ri == 0) {
            float e128 = expf(-64.f*dt);
            float s2, c2v; sincosf(PI_F*dt*n*128.f, &s2, &c2v);
            float pr = 1.f - e128*c2v, pim = -e128*s2;
            float dr = 1.f - wr, di = -wi;
            float dd = 1.f/(dr*dr + di*di);
            sVrs[2*n]   = (pr*dr + pim*di)*dd;
            sVrs[2*n+1] = (pim*dr - pr*di)*dd;
        }
    }
    __syncthreads();

    // phase 1: wave wid handles col-group cg=wid (16 cols); all 4 in parallel
    int rkey = (nl >> 1) & 3;
    {
        int col = wid*16 + nl;
        int b = col >> 2, c = col & 3;
        const unsigned short* up = u + ((size_t)h*16 + b)*512 + c*128;
        f32x4 acc[4];
#pragma unroll
        for (int mt = 0; mt < 4; mt++) acc[mt] = (f32x4){0.f,0.f,0.f,0.f};
#pragma unroll
        for (int kb = 0; kb < 4; kb++) {
            short8 bf = *(const short8*)(up + kb*32 + g*8);
#pragma unroll
            for (int mt = 0; mt < 4; mt++) {
                short8 af = *(const short8*)&sVA[(kb*64 + mt*16 + nl)*32 + ((g ^ rkey) << 3)];
                acc[mt] = __builtin_amdgcn_mfma_f32_16x16x32_bf16(af, bf, acc[mt], 0, 0, 0);
            }
        }
#pragma unroll
        for (int mt = 0; mt < 4; mt++) {
            int j0 = mt*16 + g*4;
            float4 vr = *(const float4*)&sVrs[j0];
            sE[col*68 + j0 + 0] = fmaf(scv, acc[mt][0], shv*vr.x);
            sE[col*68 + j0 + 1] = fmaf(scv, acc[mt][1], shv*vr.y);
            sE[col*68 + j0 + 2] = fmaf(scv, acc[mt][2], shv*vr.z);
            sE[col*68 + j0 + 3] = fmaf(scv, acc[mt][3], shv*vr.w);
        }
    }
    __syncthreads();

    // phase 2+3 partials on wave 0: lane = (n, bh); each handles 8 b's
    if (tid < 64) {
        int n = lane >> 1, bh = lane & 1;
        float e = expf(-0.5f * dt);
        float s_, c_; sincosf(PI_F * dt * n, &s_, &c_);
        float wr = e*c_, wi = e*s_;
        float ar = -0.5f, ai = PI_F * n;
        float den = 1.f / (ar*ar + ai*ai);
        float tr = wr - 1.f, ti = wi;
        float qr = (tr*ar + ti*ai) * den;
        float qi = (ti*ar - tr*ai) * den;
        float c2r = C2[((size_t)h*32 + n)*2], c2i = C2[((size_t)h*32 + n)*2 + 1];
        float crv = c2r*qr - c2i*qi, civ = c2r*qi + c2i*qr;
        float Wr = wr, Wi = wi;
#pragma unroll
        for (int i = 0; i < 7; i++) { float r = Wr*Wr - Wi*Wi; float im = 2.f*Wr*Wi; Wr = r; Wi = im; }
#pragma unroll
        for (int b2 = 0; b2 < 8; b2++) {
            int b = bh*8 + b2;
            float Sr = 0.f, Si = 0.f;
#pragma unroll
            for (int c = 0; c < 4; c++) {
                int col = b*4 + c;
                float er = sE[col*68 + 2*n], ei = sE[col*68 + 2*n + 1];
                float r  = fmaf(Wr, Sr, fmaf(-Wi, Si, er));
                float im = fmaf(Wi, Sr, fmaf( Wr, Si, ei));
                Sr = r; Si = im;
            }
            red[b*33 + n] = crv*Sr - civ*Si;
        }
    }
    __syncthreads();
    if (tid < 16) {
        int b = tid;
        float s = 0.f;
        for (int n2 = 0; n2 < 32; n2++) s += red[b*33 + n2];
        float uv = fmaf(scv, bf2f(u[((size_t)h*16 + b)*512 + 511]), shv);
        x3last[b*1024 + h] = 2.f*s + Dv[h]*uv;
    }
}

// ---------------- decoder head ----------------
__global__ __launch_bounds__(256) void dec_kernel(
    const float* __restrict__ x3last, const float* __restrict__ w1, const float* __restrict__ b1,
    const float* __restrict__ w2, const float* __restrict__ b2, float* __restrict__ out)
{
    __shared__ float xs[1024];
    int b = blockIdx.x, tid = threadIdx.x;
    for (int i = tid; i < 1024; i += 256) xs[i] = x3last[b*1024 + i];
    __syncthreads();
    float z = b1[tid];
    const float* wpt = w1 + (size_t)tid*1024;
    for (int i = 0; i < 1024; i += 4) {
        float4 wv = *(const float4*)(wpt + i);
        z = fmaf(wv.x, xs[i],   z);
        z = fmaf(wv.y, xs[i+1], z);
        z = fmaf(wv.z, xs[i+2], z);
        z = fmaf(wv.w, xs[i+3], z);
    }
    float v = w2[tid] * z;
    for (int o = 32; o > 0; o >>= 1) v += __shfl_down(v, o);
    __shared__ float ps[4];
    if ((tid & 63) == 0) ps[tid >> 6] = v;
    __syncthreads();
    if (tid == 0) out[b] = ps[0] + ps[1] + ps[2] + ps[3] + b2[0];
}

extern "C" void kernel_launch(void* const* d_in, const int* in_sizes, int n_in,
                              void* d_out, int out_size, void* d_ws, size_t ws_size,
                              hipStream_t stream)
{
    const float* x       = (const float*)d_in[0];
    const float* enc_w   = (const float*)d_in[1];
    const float* enc_b   = (const float*)d_in[2];
    const float* s4a_ldt = (const float*)d_in[3];
    const float* s4a_C   = (const float*)d_in[4];
    const float* s4a_D   = (const float*)d_in[5];
    const float* s4b_ldt = (const float*)d_in[6];
    const float* s4b_C   = (const float*)d_in[7];
    const float* s4b_D   = (const float*)d_in[8];
    const float* s4c_ldt = (const float*)d_in[9];
    const float* s4c_C   = (const float*)d_in[10];
    const float* s4c_D   = (const float*)d_in[11];
    const float* b1w[4] = {(const float*)d_in[12], (const float*)d_in[14], (const float*)d_in[16], (const float*)d_in[18]};
    const float* b1b[4] = {(const float*)d_in[13], (const float*)d_in[15], (const float*)d_in[17], (const float*)d_in[19]};
    const float* b2w[4] = {(const float*)d_in[20], (const float*)d_in[22], (const float*)d_in[24], (const float*)d_in[26]};
    const float* b2b[4] = {(const float*)d_in[21], (const float*)d_in[23], (const float*)d_in[25], (const float*)d_in[27]};
    const float* bn1_g  = (const float*)d_in[28];
    const float* bn1_b  = (const float*)d_in[29];
    const float* bn2_g  = (const float*)d_in[30];
    const float* bn2_b  = (const float*)d_in[31];
    const float* dec1_w = (const float*)d_in[32];
    const float* dec1_b = (const float*)d_in[33];
    const float* dec2_w = (const float*)d_in[34];
    const float* dec2_b = (const float*)d_in[35];
    float* out = (float*)d_out;

    char* ws = (char*)d_ws;
    unsigned short* u3    = (unsigned short*)(ws);              // 16.8 MB
    unsigned short* ya    = (unsigned short*)(ws + 16777216);   // 16.8 MB (also yb)
    unsigned short* yb    = ya;
    unsigned short* u2    = (unsigned short*)(ws + 33554432);   // 16.8 MB
    unsigned short* wprep = (unsigned short*)(ws + 88080384);   // 1.67 MB
    unsigned short* TA_a  = (unsigned short*)(ws + 89751552);   // 3.15 MB
    unsigned short* TA_b  = (unsigned short*)(ws + 92897280);   // 12.6 MB
    unsigned short* VA_a  = (unsigned short*)(ws + 105480192);  // 1.05 MB
    unsigned short* VA_b  = (unsigned short*)(ws + 106528768);  // 4.2 MB
    float*          rs_a  = (float*)(ws + 110723072);           // 32 KB
    float*          rs_b  = (float*)(ws + 110755840);           // 128 KB
    float*          Vrs_a = (float*)(ws + 110886912);           // 16 KB
    float*          Vrs_b = (float*)(ws + 110903296);           // 64 KB
    float*          smallp= (float*)(ws + 110968832);
    float* sc1 = smallp;         // 256
    float* sh1 = smallp + 256;   // 256
    float* sc2 = smallp + 512;   // 1024
    float* sh2 = smallp + 1536;  // 1024
    float* x3l = smallp + 2560;  // 16384

    // prep (independent of data path)
    prep_w<<<dim3(768, 8), 256, 0, stream>>>(b1w[0], b1w[1], b1w[2], b1w[3],
                                             b2w[0], b2w[1], b2w[2], b2w[3], wprep);
    prep_s4_both<<<320, 128, 0, stream>>>(
        s4a_ldt, s4a_C, s4a_D, TA_a, VA_a, rs_a, Vrs_a,
        s4b_ldt, s4b_C, s4b_D, TA_b, VA_b, rs_b, Vrs_b);

    // s4a: H=64, NCH=64 (L=8192) -- fused kernel with inline encoder (u1 eliminated)
    s4_layer_fused<64,6,true><<<dim3(16, 64), 256, 0, stream>>>(
        nullptr, x, enc_w, enc_b, VA_a, Vrs_a, TA_a, rs_a, nullptr, nullptr, s4a_ldt, ya);

    // conv block1 (fused 4 dilations): ya [64][16][8192] -> u2 [256][16][2048]
    conv_mfma4<64,32><<<dim3(64, 16, 1), 256, 0, stream>>>(
        ya, wprep, b1b[0], b1b[1], b1b[2], b1b[3], u2, 8192, 2048);
    bn_stats<<<256, 256, 0, stream>>>(u2, bn1_g, bn1_b, sc1, sh1, 16*2048, 63);

    // s4b: H=256, NCH=16 (L=2048) -- single fused kernel
    s4_layer_fused<16,4,false><<<dim3(4, 256), 256, 0, stream>>>(
        u2, nullptr, nullptr, nullptr, VA_b, Vrs_b, TA_b, rs_b, sc1, sh1, s4b_ldt, yb);

    // conv block2 (fused 4 dilations): yb [256][16][2048] -> u3 [1024][16][512]
    conv_mfma4<256,64><<<dim3(8, 16, 4), 256, 0, stream>>>(
        yb, wprep + 49152, b2b[0], b2b[1], b2b[2], b2b[3], u3, 2048, 512);
    bn_stats<<<1024, 256, 0, stream>>>(u3, bn2_g, bn2_b, sc2, sh2, 16*512, 255);

    // s4c fused v3: 256-thread in-LDS V build + GEMM + scan + reduction
    s4c_all<<<1024, 256, 0, stream>>>(u3, sc2, sh2, s4c_ldt, s4c_C, s4c_D, x3l);

    // decoder head
    dec_kernel<<<16, 256, 0, stream>>>(x3l, dec1_w, dec1_b, dec2_w, dec2_b, out);
}